// Round 1
// 952.599 us; speedup vs baseline: 1.1262x; 1.1262x over previous
//
#include <hip/hip_runtime.h>
#include <hip/hip_bf16.h>

// ---------------------------------------------------------------------------
// Problem constants
// ---------------------------------------------------------------------------
#define N0 100000
#define E0C 1600000
#define N1 100000
#define E1C 1600000
#define GCONST 512
#define F0C 93
#define F1C 43
#define OC0 (F0C * 10)   // 930
#define OC1 (F1C * 10)   // 430
#define BN_EPS 1e-5f
#define NBKT 391         // ceil(100000 / 256) buckets for CSR fill

typedef __attribute__((ext_vector_type(8))) short short8;
typedef __attribute__((ext_vector_type(4))) float floatx4;

static __device__ __forceinline__ unsigned short f2bf(float f) {
    unsigned u = __float_as_uint(f);
    unsigned r = (u + 0x7FFF + ((u >> 16) & 1)) >> 16;   // RNE
    return (unsigned short)r;
}
static __device__ __forceinline__ float bf2f(unsigned short u) {
    return __uint_as_float(((unsigned)u) << 16);
}

// ---------------------------------------------------------------------------
// zero ints
// ---------------------------------------------------------------------------
__global__ __launch_bounds__(256) void zero_int_kernel(int* __restrict__ p, int n) {
    int i = blockIdx.x * 256 + threadIdx.x;
    if (i < n) p[i] = 0;
}

// ---------------------------------------------------------------------------
// graph boundary search (both branches in one launch; blockIdx.y = branch)
// ---------------------------------------------------------------------------
__global__ __launch_bounds__(256) void find_starts2_kernel(const int* __restrict__ bat0,
                                                           const int* __restrict__ bat1,
                                                           int N, int G,
                                                           int* __restrict__ st0,
                                                           int* __restrict__ st1) {
    const int* batch = blockIdx.y ? bat1 : bat0;
    int* starts = blockIdx.y ? st1 : st0;
    int g = blockIdx.x * 256 + threadIdx.x;
    if (g > G) return;
    if (g == G) { starts[G] = N; return; }
    int lo = 0, hi = N;
    while (lo < hi) {
        int mid = (lo + hi) >> 1;
        if (batch[mid] < g) lo = mid + 1; else hi = mid;
    }
    starts[g] = lo;
}

// ---------------------------------------------------------------------------
// CSR build: histogram, 3-phase multi-block scan, two-phase bucketed fill.
// ---------------------------------------------------------------------------
__global__ __launch_bounds__(256) void hist_kernel(const int* __restrict__ ei,
                                                   int E, int* __restrict__ deg) {
    int e = blockIdx.x * 256 + threadIdx.x;
    if (e >= E) return;
    atomicAdd(&deg[ei[E + e]], 1);
}

__global__ __launch_bounds__(256) void scan_phase1_kernel(const int* __restrict__ deg,
                                                          int N,
                                                          int* __restrict__ rowptr,
                                                          int* __restrict__ bsum) {
    __shared__ int sh[256];
    int t = threadIdx.x;
    int i = blockIdx.x * 256 + t;
    int v = (i < N) ? deg[i] : 0;
    sh[t] = v;
    __syncthreads();
    for (int offd = 1; offd < 256; offd <<= 1) {
        int add = (t >= offd) ? sh[t - offd] : 0;
        __syncthreads();
        sh[t] += add;
        __syncthreads();
    }
    if (i < N) rowptr[i] = sh[t] - v;   // exclusive
    if (t == 255) bsum[blockIdx.x] = sh[255];
}

__global__ __launch_bounds__(1024) void scan_phase2_kernel(int* __restrict__ bsum, int NB) {
    __shared__ int sh[1024];
    int t = threadIdx.x;
    int v = (t < NB) ? bsum[t] : 0;
    sh[t] = v;
    __syncthreads();
    for (int offd = 1; offd < 1024; offd <<= 1) {
        int add = (t >= offd) ? sh[t - offd] : 0;
        __syncthreads();
        sh[t] += add;
        __syncthreads();
    }
    if (t < NB) bsum[t] = sh[t] - v;    // exclusive
}

__global__ __launch_bounds__(256) void scan_phase3_kernel(int* __restrict__ rowptr,
                                                          int* __restrict__ bcur,
                                                          const int* __restrict__ bsum,
                                                          int N, int E) {
    int i = blockIdx.x * 256 + threadIdx.x;
    if (i < N) {
        int r = rowptr[i] + bsum[blockIdx.x];
        rowptr[i] = r;
        if ((i & 255) == 0) bcur[i >> 8] = r;
    }
    if (blockIdx.x == 0 && threadIdx.x == 0) rowptr[N] = E;
}

__global__ __launch_bounds__(256) void edge_bucket_kernel(const int* __restrict__ ei,
                                                          int E,
                                                          int* __restrict__ bcur,
                                                          int2* __restrict__ staging) {
    __shared__ int hist[NBKT];
    __shared__ int gbase[NBKT];
    int t = threadIdx.x;
    for (int i = t; i < NBKT; i += 256) hist[i] = 0;
    __syncthreads();
    int base = blockIdx.x * 2048;
    int srcv[8], dstv[8];
#pragma unroll
    for (int i = 0; i < 8; ++i) {
        int e = base + i * 256 + t;
        if (e < E) { srcv[i] = ei[e]; dstv[i] = ei[E + e]; }
        else dstv[i] = -1;
    }
#pragma unroll
    for (int i = 0; i < 8; ++i)
        if (dstv[i] >= 0) atomicAdd(&hist[dstv[i] >> 8], 1);
    __syncthreads();
    for (int i = t; i < NBKT; i += 256) {
        int c = hist[i];
        gbase[i] = c ? atomicAdd(&bcur[i], c) : 0;
        hist[i] = 0;   // reuse as local cursor
    }
    __syncthreads();
#pragma unroll
    for (int i = 0; i < 8; ++i) {
        if (dstv[i] >= 0) {
            int b = dstv[i] >> 8;
            int lofs = atomicAdd(&hist[b], 1);
            staging[gbase[b] + lofs] = make_int2(srcv[i], dstv[i]);
        }
    }
}

__global__ __launch_bounds__(256) void csr_fill_kernel(const int2* __restrict__ staging,
                                                       const int* __restrict__ rowptr,
                                                       int N, int E,
                                                       int* __restrict__ col) {
    __shared__ int lcur[256];
    int b = blockIdx.x;
    int n0 = b << 8;
    int t = threadIdx.x;
    int node = n0 + t;
    lcur[t] = (node < N) ? rowptr[node] : 0;
    __syncthreads();
    int estart = rowptr[n0];
    int nend = (n0 + 256 < N) ? n0 + 256 : N;
    int eend = rowptr[nend];
    for (int e = estart + t; e < eend; e += 256) {
        int2 ed = staging[e];
        int pos = atomicAdd(&lcur[ed.y - n0], 1);
        col[pos] = ed.x;
    }
}

// ---------------------------------------------------------------------------
// all 4 weight transposes in one launch: Wt[c][k] (bf16, [rows][KP], 0-padded)
// ---------------------------------------------------------------------------
__global__ __launch_bounds__(128) void wt_prep4_kernel(const float* __restrict__ W0,
                                                       const float* __restrict__ W1,
                                                       const float* __restrict__ W2,
                                                       const float* __restrict__ W3,
                                                       unsigned short* __restrict__ T0,
                                                       unsigned short* __restrict__ T1,
                                                       unsigned short* __restrict__ T2,
                                                       unsigned short* __restrict__ T3) {
    const float* W; unsigned short* T; int OCr, Fr, KP, RB;
    switch (blockIdx.y) {
        case 0:  W = W0; T = T0; OCr = 93;  Fr = 93; KP = 96; RB = 96;   break;
        case 1:  W = W1; T = T1; OCr = 930; Fr = 93; KP = 96; RB = 1024; break;
        case 2:  W = W2; T = T2; OCr = 43;  Fr = 43; KP = 64; RB = 48;   break;
        default: W = W3; T = T3; OCr = 430; Fr = 43; KP = 64; RB = 512;  break;
    }
    int c = blockIdx.x, k = threadIdx.x;
    if (c >= RB || k >= KP) return;
    unsigned short v = 0;
    if (c < OCr && k < Fr) v = f2bf(W[(size_t)k * OCr + c]);
    T[(size_t)c * KP + k] = v;
}

// ---------------------------------------------------------------------------
// fp32 [N][F] -> bf16 [N][KP] (zero-padded) streaming convert
// ---------------------------------------------------------------------------
template<int F, int KP>
__global__ __launch_bounds__(256) void tobf16_kernel(unsigned short* __restrict__ t,
                                                     const float* __restrict__ x, int N) {
    int node = blockIdx.x * blockDim.y + threadIdx.y;
    int f = threadIdx.x;
    if (node >= N) return;
    t[(size_t)node * KP + f] = (f < F) ? f2bf(x[(size_t)node * F + f]) : (unsigned short)0;
}

// ---------------------------------------------------------------------------
// gather-aggregate v2: one wave per node, 16B vector loads.
//   Lanes split into GR groups of CH lanes (CH = KP/8 chunks of 8 bf16).
//   Group g handles edges j = s-1+g, s-1+g+GR, ... (j == s-1 is the self row).
//   One wave vmem inst moves up to GR*CH*16B (= 960B for KP=96) from GR rows,
//   vs 128B/inst in the old per-feature-thread layout -> ~7.5x more bytes in
//   flight per wave; next col[j] prefetched one iteration ahead.
// ---------------------------------------------------------------------------
template<int KP, int CH, int GR>
__global__ __launch_bounds__(256) void gather_wave_kernel(unsigned short* __restrict__ t,
                                                          const unsigned short* __restrict__ x,
                                                          const int* __restrict__ rowptr,
                                                          const int* __restrict__ col,
                                                          int N) {
    int wave = threadIdx.x >> 6, lane = threadIdx.x & 63;
    int node = blockIdx.x * 4 + wave;
    if (node >= N) return;
    int g = lane / CH;
    int c = lane - g * CH;
    bool act = (g < GR);
    int s = rowptr[node], e = rowptr[node + 1];
    float acc[8] = {0.f, 0.f, 0.f, 0.f, 0.f, 0.f, 0.f, 0.f};
    int j = act ? (s - 1 + g) : e;
    int src = node;
    if (j >= s && j < e) src = col[j];
    while (j < e) {
        int jn = j + GR;
        int srcn = (jn < e) ? col[jn] : 0;          // prefetch next index
        short8 v = *(const short8*)(x + (size_t)src * KP + c * 8);
#pragma unroll
        for (int i = 0; i < 8; ++i) acc[i] += bf2f((unsigned short)v[i]);
        j = jn; src = srcn;
    }
    // reduce across groups
    if (GR == 8) {
#pragma unroll
        for (int i = 0; i < 8; ++i) {
            float v = acc[i];
            v += __shfl_xor(v, 8);
            v += __shfl_xor(v, 16);
            v += __shfl_xor(v, 32);
            acc[i] = v;
        }
    } else {
#pragma unroll
        for (int i = 0; i < 8; ++i) {
            float v = acc[i];
            float v1 = __shfl(v, lane + CH);
            float v2 = __shfl(v, lane + 2 * CH);
            float v3 = __shfl(v, lane + 3 * CH);
            float v4 = __shfl(v, lane + 4 * CH);
            acc[i] = v + v1 + v2 + v3 + v4;
        }
    }
    if (lane < CH) {
        short8 o;
#pragma unroll
        for (int i = 0; i < 8; ++i) o[i] = (short)f2bf(acc[i]);
        *(short8*)(t + (size_t)node * KP + lane * 8) = o;
    }
}

// ---------------------------------------------------------------------------
// conv1 via MFMA 16x16x32 bf16: y = relu(t @ W + b), y stored bf16 [N][KP]
// ---------------------------------------------------------------------------
template<int KP, int KS, int NT>
__global__ __launch_bounds__(256) void conv1_mfma_kernel(const unsigned short* __restrict__ t,
                                                         const unsigned short* __restrict__ Wt,
                                                         const float* __restrict__ bias,
                                                         unsigned short* __restrict__ y,
                                                         int NC, int N) {
    int wave = threadIdx.x >> 6, lane = threadIdx.x & 63;
    int quad = lane >> 4, l15 = lane & 15;
    int r0 = (blockIdx.x * 4 + wave) * 16;
    const short8 z8 = {0, 0, 0, 0, 0, 0, 0, 0};
    short8 a[KS];
    int arow = r0 + l15;
#pragma unroll
    for (int ks = 0; ks < KS; ++ks)
        a[ks] = (arow < N) ? *(const short8*)(t + (size_t)arow * KP + ks * 32 + quad * 8) : z8;
#pragma unroll
    for (int nt = 0; nt < NT; ++nt) {
        int colb = nt * 16 + l15;
        floatx4 c = {0.f, 0.f, 0.f, 0.f};
#pragma unroll
        for (int ks = 0; ks < KS; ++ks) {
            short8 b = *(const short8*)(Wt + (size_t)colb * KP + ks * 32 + quad * 8);
            c = __builtin_amdgcn_mfma_f32_16x16x32_bf16(a[ks], b, c, 0, 0, 0);
        }
        float bc = (colb < NC) ? bias[colb] : 0.f;
#pragma unroll
        for (int r = 0; r < 4; ++r) {
            int row = r0 + quad * 4 + r;
            if (row < N) {
                float o = fmaxf(c[r] + bc, 0.f);
                y[(size_t)row * KP + colb] = f2bf(o);
            }
        }
    }
}

// ---------------------------------------------------------------------------
// conv2 + relu + mean/max pool via MFMA, fused per graph. No LDS.
// ---------------------------------------------------------------------------
template<int KP, int KS>
__global__ __launch_bounds__(256) void conv2_pool_mfma_kernel(const unsigned short* __restrict__ t,
                                                              const unsigned short* __restrict__ Wt,
                                                              const float* __restrict__ bias,
                                                              const int* __restrict__ starts,
                                                              float* __restrict__ pooled,
                                                              int OC) {
    int wave = threadIdx.x >> 6, lane = threadIdx.x & 63;
    int quad = lane >> 4, l15 = lane & 15;
    int g = blockIdx.y;
    int cw0 = blockIdx.x * 256 + wave * 64;
    short8 bfr[4][KS];
    float bs[4];
#pragma unroll
    for (int ti = 0; ti < 4; ++ti) {
        int colb = cw0 + ti * 16 + l15;
#pragma unroll
        for (int ks = 0; ks < KS; ++ks)
            bfr[ti][ks] = *(const short8*)(Wt + (size_t)colb * KP + ks * 32 + quad * 8);
        bs[ti] = (colb < OC) ? bias[colb] : 0.f;
    }
    int s = starts[g], e = starts[g + 1];
    float sum[4] = {0.f, 0.f, 0.f, 0.f};
    float mx[4]  = {0.f, 0.f, 0.f, 0.f};
    const short8 z8 = {0, 0, 0, 0, 0, 0, 0, 0};
    for (int ns = s; ns < e; ns += 16) {
        short8 a[KS];
        int arow = ns + l15;
        bool av = arow < e;
#pragma unroll
        for (int ks = 0; ks < KS; ++ks)
            a[ks] = av ? *(const short8*)(t + (size_t)arow * KP + ks * 32 + quad * 8) : z8;
        int rbase = ns + quad * 4;
#pragma unroll
        for (int ti = 0; ti < 4; ++ti) {
            floatx4 c = {0.f, 0.f, 0.f, 0.f};
#pragma unroll
            for (int ks = 0; ks < KS; ++ks)
                c = __builtin_amdgcn_mfma_f32_16x16x32_bf16(a[ks], bfr[ti][ks], c, 0, 0, 0);
#pragma unroll
            for (int r = 0; r < 4; ++r) {
                float o = fmaxf(c[r] + bs[ti], 0.f);
                if (rbase + r < e) {
                    sum[ti] += o;
                    mx[ti] = fmaxf(mx[ti], o);
                }
            }
        }
    }
    int cnt = e - s;
    float rc = 1.f / (float)(cnt > 0 ? cnt : 1);
#pragma unroll
    for (int ti = 0; ti < 4; ++ti) {
        float sv = sum[ti], mv = mx[ti];
        sv += __shfl_down(sv, 32);
        mv = fmaxf(mv, __shfl_down(mv, 32));
        sv += __shfl_down(sv, 16);
        mv = fmaxf(mv, __shfl_down(mv, 16));
        if (lane < 16) {
            int colb = cw0 + ti * 16 + l15;
            if (colb < OC) {
                size_t base = (size_t)g * (size_t)(2 * OC);
                pooled[base + colb] = sv * rc;
                pooled[base + OC + colb] = mv;
            }
        }
    }
}

// ---------------------------------------------------------------------------
// split-K fp32 GEMM + reduce epilogue (MLP/head1)
// ---------------------------------------------------------------------------
__global__ __launch_bounds__(256) void gemm_splitk_kernel(const float* __restrict__ A,
                                                          const float* __restrict__ B,
                                                          float* __restrict__ Cpart,
                                                          int M, int N, int K, int KC) {
    __shared__ float As[16][68];
    __shared__ float Bs[16][64];
    int tid = threadIdx.x;
    int tx = tid & 15, ty = tid >> 4;
    int m0 = blockIdx.y * 64, n0 = blockIdx.x * 64;
    int ks = blockIdx.z * KC;
    int ke = ks + KC < K ? ks + KC : K;
    float acc[4][4] = {};
    for (int k0 = ks; k0 < ke; k0 += 16) {
#pragma unroll
        for (int i = 0; i < 4; ++i) {
            int lin = tid + i * 256;
            int m = lin >> 4, k = lin & 15;
            int gm = m0 + m, gk = k0 + k;
            As[k][m] = (gm < M && gk < ke) ? A[(size_t)gm * K + gk] : 0.f;
        }
#pragma unroll
        for (int i = 0; i < 4; ++i) {
            int lin = tid + i * 256;
            int n = lin & 63, k = lin >> 6;
            int gn = n0 + n, gk = k0 + k;
            Bs[k][n] = (gk < ke && gn < N) ? B[(size_t)gk * N + gn] : 0.f;
        }
        __syncthreads();
#pragma unroll
        for (int k = 0; k < 16; ++k) {
            float a[4], b[4];
#pragma unroll
            for (int i = 0; i < 4; ++i) a[i] = As[k][ty * 4 + i];
#pragma unroll
            for (int j = 0; j < 4; ++j) b[j] = Bs[k][tx * 4 + j];
#pragma unroll
            for (int i = 0; i < 4; ++i)
#pragma unroll
                for (int j = 0; j < 4; ++j)
                    acc[i][j] = fmaf(a[i], b[j], acc[i][j]);
        }
        __syncthreads();
    }
    size_t base = (size_t)blockIdx.z * M * N;
#pragma unroll
    for (int i = 0; i < 4; ++i) {
        int gm = m0 + ty * 4 + i;
        if (gm >= M) continue;
#pragma unroll
        for (int j = 0; j < 4; ++j) {
            int gn = n0 + tx * 4 + j;
            if (gn >= N) continue;
            Cpart[base + (size_t)gm * N + gn] = acc[i][j];
        }
    }
}

__global__ __launch_bounds__(256) void reduce_bias_kernel(const float* __restrict__ Cpart,
                                                          const float* __restrict__ bias,
                                                          float* __restrict__ C,
                                                          int MN, int Nmask, int S, int relu) {
    int i = blockIdx.x * 256 + threadIdx.x;
    if (i >= MN) return;
    float s = 0.f;
    for (int z = 0; z < S; ++z) s += Cpart[(size_t)z * MN + i];
    s += bias[i & Nmask];
    if (relu) s = fmaxf(s, 0.f);
    C[i] = s;
}

// ---------------------------------------------------------------------------
// head2: z[row][0..1] = h[row][0..255] @ w2[256][2] + b2. Wave per row.
// ---------------------------------------------------------------------------
__global__ __launch_bounds__(256) void head2_kernel(const float* __restrict__ h,
                                                    const float* __restrict__ w2,
                                                    const float* __restrict__ b2,
                                                    float* __restrict__ z, int M) {
    int wave = threadIdx.x >> 6, lane = threadIdx.x & 63;
    int row = blockIdx.x * 4 + wave;
    if (row >= M) return;
    float4 hv = *(const float4*)(h + (size_t)row * 256 + lane * 4);
    const float* wp = w2 + lane * 8;
    float s0 = hv.x * wp[0] + hv.y * wp[2] + hv.z * wp[4] + hv.w * wp[6];
    float s1 = hv.x * wp[1] + hv.y * wp[3] + hv.z * wp[5] + hv.w * wp[7];
#pragma unroll
    for (int offd = 32; offd >= 1; offd >>= 1) {
        s0 += __shfl_down(s0, offd);
        s1 += __shfl_down(s1, offd);
    }
    if (lane == 0) {
        z[(size_t)row * 2 + 0] = s0 + b2[0];
        z[(size_t)row * 2 + 1] = s1 + b2[1];
    }
}

// ---------------------------------------------------------------------------
// batchnorm stats + apply
// ---------------------------------------------------------------------------
__global__ __launch_bounds__(256) void bn_stats_kernel(const float* __restrict__ p,
                                                       int rows, int cols,
                                                       float* __restrict__ mean,
                                                       float* __restrict__ inv) {
    int c = blockIdx.x;
    float s = 0.f, s2 = 0.f;
    for (int r = threadIdx.x; r < rows; r += 256) {
        float v = p[(size_t)r * cols + c];
        s += v;
        s2 += v * v;
    }
    __shared__ float ls[256], ls2[256];
    ls[threadIdx.x] = s;
    ls2[threadIdx.x] = s2;
    __syncthreads();
    for (int st = 128; st > 0; st >>= 1) {
        if (threadIdx.x < st) {
            ls[threadIdx.x] += ls[threadIdx.x + st];
            ls2[threadIdx.x] += ls2[threadIdx.x + st];
        }
        __syncthreads();
    }
    if (threadIdx.x == 0) {
        float m = ls[0] / (float)rows;
        float var = ls2[0] / (float)rows - m * m;
        mean[c] = m;
        inv[c] = 1.f / sqrtf(var + BN_EPS);
    }
}

__global__ __launch_bounds__(256) void bn_apply_kernel(const float* __restrict__ p,
                                                       const float* __restrict__ gamma,
                                                       const float* __restrict__ beta,
                                                       const float* __restrict__ mean,
                                                       const float* __restrict__ inv,
                                                       float* __restrict__ outp,
                                                       int total, int cols) {
    int i = blockIdx.x * 256 + threadIdx.x;
    if (i >= total) return;
    int c = i & (cols - 1);
    outp[i] = gamma[c] * (p[i] - mean[c]) * inv[c] + beta[c];
}

// ---------------------------------------------------------------------------
// launch
// ---------------------------------------------------------------------------
static inline int ceildiv(int a, int b) { return (a + b - 1) / b; }

extern "C" void kernel_launch(void* const* d_in, const int* in_sizes, int n_in,
                              void* d_out, int out_size, void* d_ws, size_t ws_size,
                              hipStream_t stream) {
    const float* x0   = (const float*)d_in[0];
    const float* x1   = (const float*)d_in[1];
    const int*   ei0  = (const int*)d_in[2];
    const int*   ei1  = (const int*)d_in[3];
    const int*   bat0 = (const int*)d_in[4];
    const int*   bat1 = (const int*)d_in[5];
    const float* w_c1 = (const float*)d_in[6];
    const float* b_c1 = (const float*)d_in[7];
    const float* w_c2 = (const float*)d_in[8];
    const float* b_c2 = (const float*)d_in[9];
    const float* w_c3 = (const float*)d_in[10];
    const float* b_c3 = (const float*)d_in[11];
    const float* w_c4 = (const float*)d_in[12];
    const float* b_c4 = (const float*)d_in[13];
    const float* g0_w1 = (const float*)d_in[14];
    const float* g0_b1 = (const float*)d_in[15];
    const float* g0_w2 = (const float*)d_in[16];
    const float* g0_b2 = (const float*)d_in[17];
    const float* g0_bn_g = (const float*)d_in[18];
    const float* g0_bn_b = (const float*)d_in[19];
    const float* g1_w1 = (const float*)d_in[20];
    const float* g1_b1 = (const float*)d_in[21];
    const float* g1_w2 = (const float*)d_in[22];
    const float* g1_b2 = (const float*)d_in[23];
    const float* g1_bn_g = (const float*)d_in[24];
    const float* g1_bn_b = (const float*)d_in[25];
    const float* f0_w1 = (const float*)d_in[26];
    const float* f0_b1 = (const float*)d_in[27];
    const float* f0_w2 = (const float*)d_in[28];
    const float* f0_b2 = (const float*)d_in[29];
    const float* f1_w1 = (const float*)d_in[30];
    const float* f1_b1 = (const float*)d_in[31];
    const float* f1_w2 = (const float*)d_in[32];
    const float* f1_b2 = (const float*)d_in[33];

    float* out = (float*)d_out;
    float* out_z   = out;
    float* out_xg0 = out + 1024;
    float* out_xg1 = out + 1024 + 262144;
    float* out_z1  = out + 1024 + 262144 + 262144;

    // workspace carve (floats; all offsets multiples of 4 -> 16B aligned)
    float* ws = (float*)d_ws;
    size_t off = 0;
    auto alloc = [&](size_t n) { float* p = ws + off; off += n; return p; };
    unsigned short* t_bf = (unsigned short*)alloc((size_t)N0 * 96 / 2);  // bf16 [N][96]
    unsigned short* y_bf = (unsigned short*)alloc((size_t)N0 * 96 / 2);  // bf16 [N][96] (also x-bf16 staging)
    unsigned short* wt_a0 = (unsigned short*)alloc(96 * 96 / 2);         // branch0 conv1 Wt
    unsigned short* wt_b0 = (unsigned short*)alloc(1024 * 96 / 2);       // branch0 conv2 Wt
    unsigned short* wt_a1 = (unsigned short*)alloc(48 * 64 / 2);         // branch1 conv1 Wt
    unsigned short* wt_b1 = (unsigned short*)alloc(512 * 64 / 2);        // branch1 conv2 Wt
    float* cpart = alloc((size_t)8 * 512 * 1024);                        // split-K partials
    int*   bsum  = (int*)alloc(512);                                     // scan block sums
    int*   bcur  = (int*)alloc(512);                                     // bucket cursors
    // Union region C: CSR (graph phase) aliases MLP temps (dense phase).
    size_t csr_floats = (size_t)N0 + (N0 + 4) + E0C + 2 * (size_t)E0C;   // deg|rowptr|col|staging
    size_t mlp_floats = (size_t)GCONST * 2 * OC0 + (size_t)GCONST * 2 * OC1 +
                        (size_t)GCONST * 1024 + (size_t)GCONST * 512 +
                        (size_t)GCONST * 256;
    float* regionC = alloc(csr_floats > mlp_floats ? csr_floats : mlp_floats);
    int* deg     = (int*)regionC;
    int* rowptr  = deg + N0;
    int* colb    = rowptr + (N0 + 4);
    int2* staging = (int2*)(colb + E0C);
    float* pooled0 = regionC;
    float* pooled1 = pooled0 + (size_t)GCONST * 2 * OC0;
    float* m1      = pooled1 + (size_t)GCONST * 2 * OC1;
    float* pbn     = m1 + (size_t)GCONST * 1024;
    float* hbuf    = pbn + (size_t)GCONST * 512;
    float* meanb   = alloc(512);
    float* invb    = alloc(512);
    int*   starts0 = (int*)alloc(520);
    int*   starts1 = (int*)alloc(520);

    const int G = GCONST;
    const int NBS = ceildiv(N0, 256);   // 391 scan blocks == NBKT buckets

    // ------------------- shared prologue (both branches) -------------------
    find_starts2_kernel<<<dim3(3, 2), 256, 0, stream>>>(bat0, bat1, N0, G, starts0, starts1);
    wt_prep4_kernel<<<dim3(1024, 4), 128, 0, stream>>>(w_c1, w_c2, w_c3, w_c4,
                                                       wt_a0, wt_b0, wt_a1, wt_b1);

    // =========================== branch 0 (F=93, KP=96) ===========================
    {
        const int N = N0, E = E0C, OC = OC0;
        zero_int_kernel<<<ceildiv(N, 256), 256, 0, stream>>>(deg, N);
        hist_kernel<<<ceildiv(E, 256), 256, 0, stream>>>(ei0, E, deg);
        scan_phase1_kernel<<<NBS, 256, 0, stream>>>(deg, N, rowptr, bsum);
        scan_phase2_kernel<<<1, 1024, 0, stream>>>(bsum, NBS);
        scan_phase3_kernel<<<NBS, 256, 0, stream>>>(rowptr, bcur, bsum, N, E);
        edge_bucket_kernel<<<ceildiv(E, 2048), 256, 0, stream>>>(ei0, E, bcur, staging);
        csr_fill_kernel<<<NBKT, 256, 0, stream>>>(staging, rowptr, N, E, colb);
        tobf16_kernel<93, 96><<<ceildiv(N, 2), dim3(96, 2), 0, stream>>>(y_bf, x0, N);
        gather_wave_kernel<96, 12, 5><<<ceildiv(N, 4), 256, 0, stream>>>(
            t_bf, y_bf, rowptr, colb, N);
        conv1_mfma_kernel<96, 3, 6><<<ceildiv(N, 64), 256, 0, stream>>>(
            t_bf, wt_a0, b_c1, y_bf, 93, N);
        gather_wave_kernel<96, 12, 5><<<ceildiv(N, 4), 256, 0, stream>>>(
            t_bf, y_bf, rowptr, colb, N);
        conv2_pool_mfma_kernel<96, 3><<<dim3(4, G), 256, 0, stream>>>(
            t_bf, wt_b0, b_c2, starts0, pooled0, OC);
        // MLP (fp32, split-K)
        gemm_splitk_kernel<<<dim3(16, 8, 8), 256, 0, stream>>>(
            pooled0, g0_w1, cpart, G, 1024, 2 * OC, 240);
        reduce_bias_kernel<<<ceildiv(G * 1024, 256), 256, 0, stream>>>(
            cpart, g0_b1, m1, G * 1024, 1023, 8, 1);
        gemm_splitk_kernel<<<dim3(8, 8, 8), 256, 0, stream>>>(
            m1, g0_w2, cpart, G, 512, 1024, 128);
        reduce_bias_kernel<<<ceildiv(G * 512, 256), 256, 0, stream>>>(
            cpart, g0_b2, pbn, G * 512, 511, 8, 0);
        bn_stats_kernel<<<512, 256, 0, stream>>>(pbn, G, 512, meanb, invb);
        bn_apply_kernel<<<ceildiv(G * 512, 256), 256, 0, stream>>>(
            pbn, g0_bn_g, g0_bn_b, meanb, invb, out_xg0, G * 512, 512);
        // head
        gemm_splitk_kernel<<<dim3(4, 8, 8), 256, 0, stream>>>(
            out_xg0, f0_w1, cpart, G, 256, 512, 64);
        reduce_bias_kernel<<<ceildiv(G * 256, 256), 256, 0, stream>>>(
            cpart, f0_b1, hbuf, G * 256, 255, 8, 1);
        head2_kernel<<<G / 4, 256, 0, stream>>>(hbuf, f0_w2, f0_b2, out_z, G);
    }

    // =========================== branch 1 (F=43, KP=64) ===========================
    {
        const int N = N1, E = E1C, OC = OC1;
        zero_int_kernel<<<ceildiv(N, 256), 256, 0, stream>>>(deg, N);
        hist_kernel<<<ceildiv(E, 256), 256, 0, stream>>>(ei1, E, deg);
        scan_phase1_kernel<<<NBS, 256, 0, stream>>>(deg, N, rowptr, bsum);
        scan_phase2_kernel<<<1, 1024, 0, stream>>>(bsum, NBS);
        scan_phase3_kernel<<<NBS, 256, 0, stream>>>(rowptr, bcur, bsum, N, E);
        edge_bucket_kernel<<<ceildiv(E, 2048), 256, 0, stream>>>(ei1, E, bcur, staging);
        csr_fill_kernel<<<NBKT, 256, 0, stream>>>(staging, rowptr, N, E, colb);
        tobf16_kernel<43, 64><<<ceildiv(N, 4), dim3(64, 4), 0, stream>>>(y_bf, x1, N);
        gather_wave_kernel<64, 8, 8><<<ceildiv(N, 4), 256, 0, stream>>>(
            t_bf, y_bf, rowptr, colb, N);
        conv1_mfma_kernel<64, 2, 3><<<ceildiv(N, 64), 256, 0, stream>>>(
            t_bf, wt_a1, b_c3, y_bf, 43, N);
        gather_wave_kernel<64, 8, 8><<<ceildiv(N, 4), 256, 0, stream>>>(
            t_bf, y_bf, rowptr, colb, N);
        conv2_pool_mfma_kernel<64, 2><<<dim3(2, G), 256, 0, stream>>>(
            t_bf, wt_b1, b_c4, starts1, pooled1, OC);
        gemm_splitk_kernel<<<dim3(16, 8, 8), 256, 0, stream>>>(
            pooled1, g1_w1, cpart, G, 1024, 2 * OC, 112);
        reduce_bias_kernel<<<ceildiv(G * 1024, 256), 256, 0, stream>>>(
            cpart, g1_b1, m1, G * 1024, 1023, 8, 1);
        gemm_splitk_kernel<<<dim3(8, 8, 8), 256, 0, stream>>>(
            m1, g1_w2, cpart, G, 512, 1024, 128);
        reduce_bias_kernel<<<ceildiv(G * 512, 256), 256, 0, stream>>>(
            cpart, g1_b2, pbn, G * 512, 511, 8, 0);
        bn_stats_kernel<<<512, 256, 0, stream>>>(pbn, G, 512, meanb, invb);
        bn_apply_kernel<<<ceildiv(G * 512, 256), 256, 0, stream>>>(
            pbn, g1_bn_g, g1_bn_b, meanb, invb, out_xg1, G * 512, 512);
        gemm_splitk_kernel<<<dim3(4, 8, 8), 256, 0, stream>>>(
            out_xg1, f1_w1, cpart, G, 256, 512, 64);
        reduce_bias_kernel<<<ceildiv(G * 256, 256), 256, 0, stream>>>(
            cpart, f1_b1, hbuf, G * 256, 255, 8, 1);
        head2_kernel<<<G / 4, 256, 0, stream>>>(hbuf, f1_w2, f1_b2, out_z1, G);
    }
}

// Round 2
// 909.580 us; speedup vs baseline: 1.1794x; 1.0473x over previous
//
#include <hip/hip_runtime.h>
#include <hip/hip_bf16.h>

// ---------------------------------------------------------------------------
// Problem constants
// ---------------------------------------------------------------------------
#define N0 100000
#define E0C 1600000
#define N1 100000
#define E1C 1600000
#define GCONST 512
#define F0C 93
#define F1C 43
#define OC0 (F0C * 10)   // 930
#define OC1 (F1C * 10)   // 430
#define BN_EPS 1e-5f
#define NBKT 391         // ceil(100000 / 256) buckets for CSR fill

typedef __attribute__((ext_vector_type(8))) short short8;
typedef __attribute__((ext_vector_type(4))) float floatx4;

static __device__ __forceinline__ unsigned short f2bf(float f) {
    unsigned u = __float_as_uint(f);
    unsigned r = (u + 0x7FFF + ((u >> 16) & 1)) >> 16;   // RNE
    return (unsigned short)r;
}
static __device__ __forceinline__ float bf2f(unsigned short u) {
    return __uint_as_float(((unsigned)u) << 16);
}
static __device__ __forceinline__ void split_bf(float v, unsigned short& h, unsigned short& l) {
    h = f2bf(v);
    l = f2bf(v - bf2f(h));
}

// ---------------------------------------------------------------------------
// zero ints
// ---------------------------------------------------------------------------
__global__ __launch_bounds__(256) void zero_int_kernel(int* __restrict__ p, int n) {
    int i = blockIdx.x * 256 + threadIdx.x;
    if (i < n) p[i] = 0;
}

// ---------------------------------------------------------------------------
// graph boundary search (both branches in one launch; blockIdx.y = branch)
// ---------------------------------------------------------------------------
__global__ __launch_bounds__(256) void find_starts2_kernel(const int* __restrict__ bat0,
                                                           const int* __restrict__ bat1,
                                                           int N, int G,
                                                           int* __restrict__ st0,
                                                           int* __restrict__ st1) {
    const int* batch = blockIdx.y ? bat1 : bat0;
    int* starts = blockIdx.y ? st1 : st0;
    int g = blockIdx.x * 256 + threadIdx.x;
    if (g > G) return;
    if (g == G) { starts[G] = N; return; }
    int lo = 0, hi = N;
    while (lo < hi) {
        int mid = (lo + hi) >> 1;
        if (batch[mid] < g) lo = mid + 1; else hi = mid;
    }
    starts[g] = lo;
}

// ---------------------------------------------------------------------------
// CSR build: histogram, 3-phase multi-block scan, two-phase bucketed fill.
// ---------------------------------------------------------------------------
__global__ __launch_bounds__(256) void hist_kernel(const int* __restrict__ ei,
                                                   int E, int* __restrict__ deg) {
    int e = blockIdx.x * 256 + threadIdx.x;
    if (e >= E) return;
    atomicAdd(&deg[ei[E + e]], 1);
}

__global__ __launch_bounds__(256) void scan_phase1_kernel(const int* __restrict__ deg,
                                                          int N,
                                                          int* __restrict__ rowptr,
                                                          int* __restrict__ bsum) {
    __shared__ int sh[256];
    int t = threadIdx.x;
    int i = blockIdx.x * 256 + t;
    int v = (i < N) ? deg[i] : 0;
    sh[t] = v;
    __syncthreads();
    for (int offd = 1; offd < 256; offd <<= 1) {
        int add = (t >= offd) ? sh[t - offd] : 0;
        __syncthreads();
        sh[t] += add;
        __syncthreads();
    }
    if (i < N) rowptr[i] = sh[t] - v;   // exclusive
    if (t == 255) bsum[blockIdx.x] = sh[255];
}

__global__ __launch_bounds__(1024) void scan_phase2_kernel(int* __restrict__ bsum, int NB) {
    __shared__ int sh[1024];
    int t = threadIdx.x;
    int v = (t < NB) ? bsum[t] : 0;
    sh[t] = v;
    __syncthreads();
    for (int offd = 1; offd < 1024; offd <<= 1) {
        int add = (t >= offd) ? sh[t - offd] : 0;
        __syncthreads();
        sh[t] += add;
        __syncthreads();
    }
    if (t < NB) bsum[t] = sh[t] - v;    // exclusive
}

__global__ __launch_bounds__(256) void scan_phase3_kernel(int* __restrict__ rowptr,
                                                          int* __restrict__ bcur,
                                                          const int* __restrict__ bsum,
                                                          int N, int E) {
    int i = blockIdx.x * 256 + threadIdx.x;
    if (i < N) {
        int r = rowptr[i] + bsum[blockIdx.x];
        rowptr[i] = r;
        if ((i & 255) == 0) bcur[i >> 8] = r;
    }
    if (blockIdx.x == 0 && threadIdx.x == 0) rowptr[N] = E;
}

__global__ __launch_bounds__(256) void edge_bucket_kernel(const int* __restrict__ ei,
                                                          int E,
                                                          int* __restrict__ bcur,
                                                          int2* __restrict__ staging) {
    __shared__ int hist[NBKT];
    __shared__ int gbase[NBKT];
    int t = threadIdx.x;
    for (int i = t; i < NBKT; i += 256) hist[i] = 0;
    __syncthreads();
    int base = blockIdx.x * 2048;
    int srcv[8], dstv[8];
#pragma unroll
    for (int i = 0; i < 8; ++i) {
        int e = base + i * 256 + t;
        if (e < E) { srcv[i] = ei[e]; dstv[i] = ei[E + e]; }
        else dstv[i] = -1;
    }
#pragma unroll
    for (int i = 0; i < 8; ++i)
        if (dstv[i] >= 0) atomicAdd(&hist[dstv[i] >> 8], 1);
    __syncthreads();
    for (int i = t; i < NBKT; i += 256) {
        int c = hist[i];
        gbase[i] = c ? atomicAdd(&bcur[i], c) : 0;
        hist[i] = 0;   // reuse as local cursor
    }
    __syncthreads();
#pragma unroll
    for (int i = 0; i < 8; ++i) {
        if (dstv[i] >= 0) {
            int b = dstv[i] >> 8;
            int lofs = atomicAdd(&hist[b], 1);
            staging[gbase[b] + lofs] = make_int2(srcv[i], dstv[i]);
        }
    }
}

__global__ __launch_bounds__(256) void csr_fill_kernel(const int2* __restrict__ staging,
                                                       const int* __restrict__ rowptr,
                                                       int N, int E,
                                                       int* __restrict__ col) {
    __shared__ int lcur[256];
    int b = blockIdx.x;
    int n0 = b << 8;
    int t = threadIdx.x;
    int node = n0 + t;
    lcur[t] = (node < N) ? rowptr[node] : 0;
    __syncthreads();
    int estart = rowptr[n0];
    int nend = (n0 + 256 < N) ? n0 + 256 : N;
    int eend = rowptr[nend];
    for (int e = estart + t; e < eend; e += 256) {
        int2 ed = staging[e];
        int pos = atomicAdd(&lcur[ed.y - n0], 1);
        col[pos] = ed.x;
    }
}

// ---------------------------------------------------------------------------
// all 4 conv weight transposes in one launch: Wt[c][k] (bf16, [rows][KP], 0-pad)
// ---------------------------------------------------------------------------
__global__ __launch_bounds__(128) void wt_prep4_kernel(const float* __restrict__ W0,
                                                       const float* __restrict__ W1,
                                                       const float* __restrict__ W2,
                                                       const float* __restrict__ W3,
                                                       unsigned short* __restrict__ T0,
                                                       unsigned short* __restrict__ T1,
                                                       unsigned short* __restrict__ T2,
                                                       unsigned short* __restrict__ T3) {
    const float* W; unsigned short* T; int OCr, Fr, KP, RB;
    switch (blockIdx.y) {
        case 0:  W = W0; T = T0; OCr = 93;  Fr = 93; KP = 96; RB = 96;   break;
        case 1:  W = W1; T = T1; OCr = 930; Fr = 93; KP = 96; RB = 1024; break;
        case 2:  W = W2; T = T2; OCr = 43;  Fr = 43; KP = 64; RB = 48;   break;
        default: W = W3; T = T3; OCr = 430; Fr = 43; KP = 64; RB = 512;  break;
    }
    int c = blockIdx.x, k = threadIdx.x;
    if (c >= RB || k >= KP) return;
    unsigned short v = 0;
    if (c < OCr && k < Fr) v = f2bf(W[(size_t)k * OCr + c]);
    T[(size_t)c * KP + k] = v;
}

// ---------------------------------------------------------------------------
// MLP weight transpose + hi/lo bf16 split: W[K][N] -> Th/Tl[N][KP] (0-padded)
// ---------------------------------------------------------------------------
__global__ __launch_bounds__(256) void wsplit_t_kernel(const float* __restrict__ W,
                                                       unsigned short* __restrict__ Th,
                                                       unsigned short* __restrict__ Tl,
                                                       int K, int N, int KP) {
    __shared__ float tile[32][33];
    int tx = threadIdx.x & 31, ty = threadIdx.x >> 5;   // 32 x 8
    int k0 = blockIdx.x * 32, c0 = blockIdx.y * 32;
    for (int r = ty; r < 32; r += 8) {
        int k = k0 + r;
        tile[r][tx] = (k < K) ? W[(size_t)k * N + c0 + tx] : 0.f;
    }
    __syncthreads();
    for (int r = ty; r < 32; r += 8) {
        int c = c0 + r;
        float v = tile[tx][r];
        unsigned short h, l;
        split_bf(v, h, l);
        Th[(size_t)c * KP + k0 + tx] = h;
        Tl[(size_t)c * KP + k0 + tx] = l;
    }
}

// zero pad columns [from, KP) of the 512-row hi/lo pooled buffers
__global__ __launch_bounds__(256) void zero_pad_kernel(unsigned short* __restrict__ ph,
                                                       unsigned short* __restrict__ pl,
                                                       int KP, int from) {
    int padw = KP - from;
    int total = GCONST * padw;
    int i = blockIdx.x * 256 + threadIdx.x;
    if (i >= total) return;
    int g = i / padw, c = from + (i - g * padw);
    ph[(size_t)g * KP + c] = 0;
    pl[(size_t)g * KP + c] = 0;
}

// ---------------------------------------------------------------------------
// fp32 [N][F] -> bf16 [N][KP] (zero-padded) streaming convert
// ---------------------------------------------------------------------------
template<int F, int KP>
__global__ __launch_bounds__(256) void tobf16_kernel(unsigned short* __restrict__ t,
                                                     const float* __restrict__ x, int N) {
    int node = blockIdx.x * blockDim.y + threadIdx.y;
    int f = threadIdx.x;
    if (node >= N) return;
    t[(size_t)node * KP + f] = (f < F) ? f2bf(x[(size_t)node * F + f]) : (unsigned short)0;
}

// ---------------------------------------------------------------------------
// gather-aggregate: one wave per node, 16B vector loads, index prefetch.
// ---------------------------------------------------------------------------
template<int KP, int CH, int GR>
__global__ __launch_bounds__(256) void gather_wave_kernel(unsigned short* __restrict__ t,
                                                          const unsigned short* __restrict__ x,
                                                          const int* __restrict__ rowptr,
                                                          const int* __restrict__ col,
                                                          int N) {
    int wave = threadIdx.x >> 6, lane = threadIdx.x & 63;
    int node = blockIdx.x * 4 + wave;
    if (node >= N) return;
    int g = lane / CH;
    int c = lane - g * CH;
    bool act = (g < GR);
    int s = rowptr[node], e = rowptr[node + 1];
    float acc[8] = {0.f, 0.f, 0.f, 0.f, 0.f, 0.f, 0.f, 0.f};
    int j = act ? (s - 1 + g) : e;
    int src = node;
    if (j >= s && j < e) src = col[j];
    while (j < e) {
        int jn = j + GR;
        int srcn = (jn < e) ? col[jn] : 0;          // prefetch next index
        short8 v = *(const short8*)(x + (size_t)src * KP + c * 8);
#pragma unroll
        for (int i = 0; i < 8; ++i) acc[i] += bf2f((unsigned short)v[i]);
        j = jn; src = srcn;
    }
    if (GR == 8) {
#pragma unroll
        for (int i = 0; i < 8; ++i) {
            float v = acc[i];
            v += __shfl_xor(v, 8);
            v += __shfl_xor(v, 16);
            v += __shfl_xor(v, 32);
            acc[i] = v;
        }
    } else {
#pragma unroll
        for (int i = 0; i < 8; ++i) {
            float v = acc[i];
            float v1 = __shfl(v, lane + CH);
            float v2 = __shfl(v, lane + 2 * CH);
            float v3 = __shfl(v, lane + 3 * CH);
            float v4 = __shfl(v, lane + 4 * CH);
            acc[i] = v + v1 + v2 + v3 + v4;
        }
    }
    if (lane < CH) {
        short8 o;
#pragma unroll
        for (int i = 0; i < 8; ++i) o[i] = (short)f2bf(acc[i]);
        *(short8*)(t + (size_t)node * KP + lane * 8) = o;
    }
}

// ---------------------------------------------------------------------------
// conv1 via MFMA 16x16x32 bf16: y = relu(t @ W + b), y stored bf16 [N][KP]
// ---------------------------------------------------------------------------
template<int KP, int KS, int NT>
__global__ __launch_bounds__(256) void conv1_mfma_kernel(const unsigned short* __restrict__ t,
                                                         const unsigned short* __restrict__ Wt,
                                                         const float* __restrict__ bias,
                                                         unsigned short* __restrict__ y,
                                                         int NC, int N) {
    int wave = threadIdx.x >> 6, lane = threadIdx.x & 63;
    int quad = lane >> 4, l15 = lane & 15;
    int r0 = (blockIdx.x * 4 + wave) * 16;
    const short8 z8 = {0, 0, 0, 0, 0, 0, 0, 0};
    short8 a[KS];
    int arow = r0 + l15;
#pragma unroll
    for (int ks = 0; ks < KS; ++ks)
        a[ks] = (arow < N) ? *(const short8*)(t + (size_t)arow * KP + ks * 32 + quad * 8) : z8;
#pragma unroll
    for (int nt = 0; nt < NT; ++nt) {
        int colb = nt * 16 + l15;
        floatx4 c = {0.f, 0.f, 0.f, 0.f};
#pragma unroll
        for (int ks = 0; ks < KS; ++ks) {
            short8 b = *(const short8*)(Wt + (size_t)colb * KP + ks * 32 + quad * 8);
            c = __builtin_amdgcn_mfma_f32_16x16x32_bf16(a[ks], b, c, 0, 0, 0);
        }
        float bc = (colb < NC) ? bias[colb] : 0.f;
#pragma unroll
        for (int r = 0; r < 4; ++r) {
            int row = r0 + quad * 4 + r;
            if (row < N) {
                float o = fmaxf(c[r] + bc, 0.f);
                y[(size_t)row * KP + colb] = f2bf(o);
            }
        }
    }
}

// ---------------------------------------------------------------------------
// conv2 + relu + mean/max pool via MFMA, fused per graph.
// Epilogue emits pooled rows as hi/lo bf16 split: row = [mean(OC)|max(OC)|pad]
// ---------------------------------------------------------------------------
template<int KP, int KS>
__global__ __launch_bounds__(256) void conv2_pool_mfma_kernel(const unsigned short* __restrict__ t,
                                                              const unsigned short* __restrict__ Wt,
                                                              const float* __restrict__ bias,
                                                              const int* __restrict__ starts,
                                                              unsigned short* __restrict__ ph,
                                                              unsigned short* __restrict__ pl,
                                                              int OC, int KPad) {
    int wave = threadIdx.x >> 6, lane = threadIdx.x & 63;
    int quad = lane >> 4, l15 = lane & 15;
    int g = blockIdx.y;
    int cw0 = blockIdx.x * 256 + wave * 64;
    short8 bfr[4][KS];
    float bs[4];
#pragma unroll
    for (int ti = 0; ti < 4; ++ti) {
        int colb = cw0 + ti * 16 + l15;
#pragma unroll
        for (int ks = 0; ks < KS; ++ks)
            bfr[ti][ks] = *(const short8*)(Wt + (size_t)colb * KP + ks * 32 + quad * 8);
        bs[ti] = (colb < OC) ? bias[colb] : 0.f;
    }
    int s = starts[g], e = starts[g + 1];
    float sum[4] = {0.f, 0.f, 0.f, 0.f};
    float mx[4]  = {0.f, 0.f, 0.f, 0.f};
    const short8 z8 = {0, 0, 0, 0, 0, 0, 0, 0};
    for (int ns = s; ns < e; ns += 16) {
        short8 a[KS];
        int arow = ns + l15;
        bool av = arow < e;
#pragma unroll
        for (int ks = 0; ks < KS; ++ks)
            a[ks] = av ? *(const short8*)(t + (size_t)arow * KP + ks * 32 + quad * 8) : z8;
        int rbase = ns + quad * 4;
#pragma unroll
        for (int ti = 0; ti < 4; ++ti) {
            floatx4 c = {0.f, 0.f, 0.f, 0.f};
#pragma unroll
            for (int ks = 0; ks < KS; ++ks)
                c = __builtin_amdgcn_mfma_f32_16x16x32_bf16(a[ks], bfr[ti][ks], c, 0, 0, 0);
#pragma unroll
            for (int r = 0; r < 4; ++r) {
                float o = fmaxf(c[r] + bs[ti], 0.f);
                if (rbase + r < e) {
                    sum[ti] += o;
                    mx[ti] = fmaxf(mx[ti], o);
                }
            }
        }
    }
    int cnt = e - s;
    float rc = 1.f / (float)(cnt > 0 ? cnt : 1);
#pragma unroll
    for (int ti = 0; ti < 4; ++ti) {
        float sv = sum[ti], mv = mx[ti];
        sv += __shfl_down(sv, 32);
        mv = fmaxf(mv, __shfl_down(mv, 32));
        sv += __shfl_down(sv, 16);
        mv = fmaxf(mv, __shfl_down(mv, 16));
        if (lane < 16) {
            int colb = cw0 + ti * 16 + l15;
            if (colb < OC) {
                size_t base = (size_t)g * (size_t)KPad;
                unsigned short h, l;
                split_bf(sv * rc, h, l);
                ph[base + colb] = h; pl[base + colb] = l;
                split_bf(mv, h, l);
                ph[base + OC + colb] = h; pl[base + OC + colb] = l;
            }
        }
    }
}

// ---------------------------------------------------------------------------
// split-bf16 ("bf16x3") MFMA GEMM: C = A @ B^T(+bias), fp32-equivalent.
//   A given as hi/lo bf16 [M][KP]; B given transposed hi/lo [N][KP].
//   acc += Ah*Bh + Al*Bh + Ah*Bl  (Al*Bl ~2^-18, omitted)
//   Block: 256 thr = 4 waves; tile 32 rows x 64 cols; grid (N/64, M/32).
//   MODE 0: relu, write hi/lo bf16.  MODE 1: fp32.  MODE 2: relu, fp32.
// ---------------------------------------------------------------------------
template<int MODE>
__global__ __launch_bounds__(256) void gemm3x_kernel(const unsigned short* __restrict__ Ah,
                                                     const unsigned short* __restrict__ Al,
                                                     const unsigned short* __restrict__ Bh,
                                                     const unsigned short* __restrict__ Bl,
                                                     const float* __restrict__ bias,
                                                     float* __restrict__ Cf,
                                                     unsigned short* __restrict__ Ch,
                                                     unsigned short* __restrict__ Cl,
                                                     int KP) {
    int wave = threadIdx.x >> 6, lane = threadIdx.x & 63;
    int quad = lane >> 4, l15 = lane & 15;
    int r0 = blockIdx.y * 32 + (wave & 1) * 16;
    int c0 = blockIdx.x * 64 + (wave >> 1) * 32;
    int Ncols = gridDim.x * 64;
    floatx4 acc0 = {0.f, 0.f, 0.f, 0.f};
    floatx4 acc1 = {0.f, 0.f, 0.f, 0.f};
    const unsigned short* arh = Ah + (size_t)(r0 + l15) * KP;
    const unsigned short* arl = Al + (size_t)(r0 + l15) * KP;
    const unsigned short* b0h = Bh + (size_t)(c0 + l15) * KP;
    const unsigned short* b0l = Bl + (size_t)(c0 + l15) * KP;
    const unsigned short* b1h = Bh + (size_t)(c0 + 16 + l15) * KP;
    const unsigned short* b1l = Bl + (size_t)(c0 + 16 + l15) * KP;
    for (int k0 = 0; k0 < KP; k0 += 128) {
        short8 ah[4], al[4];
#pragma unroll
        for (int q = 0; q < 4; ++q) {
            ah[q] = *(const short8*)(arh + k0 + q * 32 + quad * 8);
            al[q] = *(const short8*)(arl + k0 + q * 32 + quad * 8);
        }
#pragma unroll
        for (int q = 0; q < 4; ++q) {
            short8 bh = *(const short8*)(b0h + k0 + q * 32 + quad * 8);
            short8 bl = *(const short8*)(b0l + k0 + q * 32 + quad * 8);
            acc0 = __builtin_amdgcn_mfma_f32_16x16x32_bf16(ah[q], bh, acc0, 0, 0, 0);
            acc0 = __builtin_amdgcn_mfma_f32_16x16x32_bf16(al[q], bh, acc0, 0, 0, 0);
            acc0 = __builtin_amdgcn_mfma_f32_16x16x32_bf16(ah[q], bl, acc0, 0, 0, 0);
            bh = *(const short8*)(b1h + k0 + q * 32 + quad * 8);
            bl = *(const short8*)(b1l + k0 + q * 32 + quad * 8);
            acc1 = __builtin_amdgcn_mfma_f32_16x16x32_bf16(ah[q], bh, acc1, 0, 0, 0);
            acc1 = __builtin_amdgcn_mfma_f32_16x16x32_bf16(al[q], bh, acc1, 0, 0, 0);
            acc1 = __builtin_amdgcn_mfma_f32_16x16x32_bf16(ah[q], bl, acc1, 0, 0, 0);
        }
    }
    int col0 = c0 + l15, col1 = c0 + 16 + l15;
    float bc0 = bias[col0], bc1 = bias[col1];
#pragma unroll
    for (int r = 0; r < 4; ++r) {
        int row = r0 + quad * 4 + r;
        float v0 = acc0[r] + bc0;
        float v1 = acc1[r] + bc1;
        if (MODE != 1) { v0 = fmaxf(v0, 0.f); v1 = fmaxf(v1, 0.f); }
        if (MODE == 0) {
            unsigned short h, l;
            split_bf(v0, h, l);
            Ch[(size_t)row * Ncols + col0] = h; Cl[(size_t)row * Ncols + col0] = l;
            split_bf(v1, h, l);
            Ch[(size_t)row * Ncols + col1] = h; Cl[(size_t)row * Ncols + col1] = l;
        } else {
            Cf[(size_t)row * Ncols + col0] = v0;
            Cf[(size_t)row * Ncols + col1] = v1;
        }
    }
}

// ---------------------------------------------------------------------------
// head2: z[row][0..1] = h[row][0..255] @ w2[256][2] + b2. Wave per row.
// ---------------------------------------------------------------------------
__global__ __launch_bounds__(256) void head2_kernel(const float* __restrict__ h,
                                                    const float* __restrict__ w2,
                                                    const float* __restrict__ b2,
                                                    float* __restrict__ z, int M) {
    int wave = threadIdx.x >> 6, lane = threadIdx.x & 63;
    int row = blockIdx.x * 4 + wave;
    if (row >= M) return;
    float4 hv = *(const float4*)(h + (size_t)row * 256 + lane * 4);
    const float* wp = w2 + lane * 8;
    float s0 = hv.x * wp[0] + hv.y * wp[2] + hv.z * wp[4] + hv.w * wp[6];
    float s1 = hv.x * wp[1] + hv.y * wp[3] + hv.z * wp[5] + hv.w * wp[7];
#pragma unroll
    for (int offd = 32; offd >= 1; offd >>= 1) {
        s0 += __shfl_down(s0, offd);
        s1 += __shfl_down(s1, offd);
    }
    if (lane == 0) {
        z[(size_t)row * 2 + 0] = s0 + b2[0];
        z[(size_t)row * 2 + 1] = s1 + b2[1];
    }
}

// ---------------------------------------------------------------------------
// batchnorm stats + apply (apply also emits hi/lo bf16 for the head GEMM)
// ---------------------------------------------------------------------------
__global__ __launch_bounds__(256) void bn_stats_kernel(const float* __restrict__ p,
                                                       int rows, int cols,
                                                       float* __restrict__ mean,
                                                       float* __restrict__ inv) {
    int c = blockIdx.x;
    float s = 0.f, s2 = 0.f;
    for (int r = threadIdx.x; r < rows; r += 256) {
        float v = p[(size_t)r * cols + c];
        s += v;
        s2 += v * v;
    }
    __shared__ float ls[256], ls2[256];
    ls[threadIdx.x] = s;
    ls2[threadIdx.x] = s2;
    __syncthreads();
    for (int st = 128; st > 0; st >>= 1) {
        if (threadIdx.x < st) {
            ls[threadIdx.x] += ls[threadIdx.x + st];
            ls2[threadIdx.x] += ls2[threadIdx.x + st];
        }
        __syncthreads();
    }
    if (threadIdx.x == 0) {
        float m = ls[0] / (float)rows;
        float var = ls2[0] / (float)rows - m * m;
        mean[c] = m;
        inv[c] = 1.f / sqrtf(var + BN_EPS);
    }
}

__global__ __launch_bounds__(256) void bn_apply_kernel(const float* __restrict__ p,
                                                       const float* __restrict__ gamma,
                                                       const float* __restrict__ beta,
                                                       const float* __restrict__ mean,
                                                       const float* __restrict__ inv,
                                                       float* __restrict__ outp,
                                                       unsigned short* __restrict__ oh,
                                                       unsigned short* __restrict__ ol,
                                                       int total, int cols) {
    int i = blockIdx.x * 256 + threadIdx.x;
    if (i >= total) return;
    int c = i & (cols - 1);
    float v = gamma[c] * (p[i] - mean[c]) * inv[c] + beta[c];
    outp[i] = v;
    unsigned short h, l;
    split_bf(v, h, l);
    oh[i] = h;
    ol[i] = l;
}

// ---------------------------------------------------------------------------
// launch
// ---------------------------------------------------------------------------
static inline int ceildiv(int a, int b) { return (a + b - 1) / b; }

extern "C" void kernel_launch(void* const* d_in, const int* in_sizes, int n_in,
                              void* d_out, int out_size, void* d_ws, size_t ws_size,
                              hipStream_t stream) {
    const float* x0   = (const float*)d_in[0];
    const float* x1   = (const float*)d_in[1];
    const int*   ei0  = (const int*)d_in[2];
    const int*   ei1  = (const int*)d_in[3];
    const int*   bat0 = (const int*)d_in[4];
    const int*   bat1 = (const int*)d_in[5];
    const float* w_c1 = (const float*)d_in[6];
    const float* b_c1 = (const float*)d_in[7];
    const float* w_c2 = (const float*)d_in[8];
    const float* b_c2 = (const float*)d_in[9];
    const float* w_c3 = (const float*)d_in[10];
    const float* b_c3 = (const float*)d_in[11];
    const float* w_c4 = (const float*)d_in[12];
    const float* b_c4 = (const float*)d_in[13];
    const float* g0_w1 = (const float*)d_in[14];
    const float* g0_b1 = (const float*)d_in[15];
    const float* g0_w2 = (const float*)d_in[16];
    const float* g0_b2 = (const float*)d_in[17];
    const float* g0_bn_g = (const float*)d_in[18];
    const float* g0_bn_b = (const float*)d_in[19];
    const float* g1_w1 = (const float*)d_in[20];
    const float* g1_b1 = (const float*)d_in[21];
    const float* g1_w2 = (const float*)d_in[22];
    const float* g1_b2 = (const float*)d_in[23];
    const float* g1_bn_g = (const float*)d_in[24];
    const float* g1_bn_b = (const float*)d_in[25];
    const float* f0_w1 = (const float*)d_in[26];
    const float* f0_b1 = (const float*)d_in[27];
    const float* f0_w2 = (const float*)d_in[28];
    const float* f0_b2 = (const float*)d_in[29];
    const float* f1_w1 = (const float*)d_in[30];
    const float* f1_b1 = (const float*)d_in[31];
    const float* f1_w2 = (const float*)d_in[32];
    const float* f1_b2 = (const float*)d_in[33];

    float* out = (float*)d_out;
    float* out_z   = out;
    float* out_xg0 = out + 1024;
    float* out_xg1 = out + 1024 + 262144;
    float* out_z1  = out + 1024 + 262144 + 262144;

    // workspace carve (floats; all offsets multiples of 4 -> 16B aligned)
    float* ws = (float*)d_ws;
    size_t off = 0;
    auto alloc = [&](size_t n) { float* p = ws + off; off += n; return p; };
    unsigned short* t_bf = (unsigned short*)alloc((size_t)N0 * 96 / 2);  // bf16 [N][96]
    unsigned short* y_bf = (unsigned short*)alloc((size_t)N0 * 96 / 2);  // bf16 [N][96] (also x-bf16 staging)
    unsigned short* wt_a0 = (unsigned short*)alloc(96 * 96 / 2);         // branch0 conv1 Wt
    unsigned short* wt_b0 = (unsigned short*)alloc(1024 * 96 / 2);       // branch0 conv2 Wt
    unsigned short* wt_a1 = (unsigned short*)alloc(48 * 64 / 2);         // branch1 conv1 Wt
    unsigned short* wt_b1 = (unsigned short*)alloc(512 * 64 / 2);        // branch1 conv2 Wt
    // MLP hi/lo weight buffers (aliased across branches; sized for branch0)
    unsigned short* bt1h = (unsigned short*)alloc((size_t)1024 * 1920 / 2);
    unsigned short* bt1l = (unsigned short*)alloc((size_t)1024 * 1920 / 2);
    unsigned short* bt2h = (unsigned short*)alloc((size_t)512 * 1024 / 2);
    unsigned short* bt2l = (unsigned short*)alloc((size_t)512 * 1024 / 2);
    unsigned short* bt3h = (unsigned short*)alloc((size_t)256 * 512 / 2);
    unsigned short* bt3l = (unsigned short*)alloc((size_t)256 * 512 / 2);
    unsigned short* m1h  = (unsigned short*)alloc((size_t)512 * 1024 / 2);
    unsigned short* m1l  = (unsigned short*)alloc((size_t)512 * 1024 / 2);
    unsigned short* xgh  = (unsigned short*)alloc((size_t)512 * 512 / 2);
    unsigned short* xgl  = (unsigned short*)alloc((size_t)512 * 512 / 2);
    int*   bsum  = (int*)alloc(512);                                     // scan block sums
    int*   bcur  = (int*)alloc(512);                                     // bucket cursors
    // Union region C: CSR (graph phase) aliases pooled-hi/lo + MLP fp32 temps.
    size_t csr_floats = (size_t)N0 + (N0 + 4) + E0C + 2 * (size_t)E0C;   // deg|rowptr|col|staging
    float* regionC = alloc(csr_floats);
    int* deg     = (int*)regionC;
    int* rowptr  = deg + N0;
    int* colb    = rowptr + (N0 + 4);
    int2* staging = (int2*)(colb + E0C);
    float* meanb   = alloc(512);
    float* invb    = alloc(512);
    int*   starts0 = (int*)alloc(520);
    int*   starts1 = (int*)alloc(520);

    const int G = GCONST;
    const int NBS = ceildiv(N0, 256);   // 391 scan blocks == NBKT buckets

    // ------------------- shared prologue (both branches) -------------------
    find_starts2_kernel<<<dim3(3, 2), 256, 0, stream>>>(bat0, bat1, N0, G, starts0, starts1);
    wt_prep4_kernel<<<dim3(1024, 4), 128, 0, stream>>>(w_c1, w_c2, w_c3, w_c4,
                                                       wt_a0, wt_b0, wt_a1, wt_b1);

    // =========================== branch 0 (F=93, KP=96) ===========================
    {
        const int N = N0, E = E0C, OC = OC0;
        const int KP1 = 1920;   // 2*OC=1860 padded to x128
        unsigned short* p_hi = (unsigned short*)regionC;   // CSR dead by conv2_pool time
        unsigned short* p_lo = p_hi + (size_t)G * KP1;
        float* pbn  = (float*)(p_hi + (size_t)G * KP1 * 2);
        float* hbuf = pbn + (size_t)G * 512;
        zero_int_kernel<<<ceildiv(N, 256), 256, 0, stream>>>(deg, N);
        hist_kernel<<<ceildiv(E, 256), 256, 0, stream>>>(ei0, E, deg);
        scan_phase1_kernel<<<NBS, 256, 0, stream>>>(deg, N, rowptr, bsum);
        scan_phase2_kernel<<<1, 1024, 0, stream>>>(bsum, NBS);
        scan_phase3_kernel<<<NBS, 256, 0, stream>>>(rowptr, bcur, bsum, N, E);
        edge_bucket_kernel<<<ceildiv(E, 2048), 256, 0, stream>>>(ei0, E, bcur, staging);
        csr_fill_kernel<<<NBKT, 256, 0, stream>>>(staging, rowptr, N, E, colb);
        tobf16_kernel<93, 96><<<ceildiv(N, 2), dim3(96, 2), 0, stream>>>(y_bf, x0, N);
        gather_wave_kernel<96, 12, 5><<<ceildiv(N, 4), 256, 0, stream>>>(
            t_bf, y_bf, rowptr, colb, N);
        conv1_mfma_kernel<96, 3, 6><<<ceildiv(N, 64), 256, 0, stream>>>(
            t_bf, wt_a0, b_c1, y_bf, 93, N);
        gather_wave_kernel<96, 12, 5><<<ceildiv(N, 4), 256, 0, stream>>>(
            t_bf, y_bf, rowptr, colb, N);
        conv2_pool_mfma_kernel<96, 3><<<dim3(4, G), 256, 0, stream>>>(
            t_bf, wt_b0, b_c2, starts0, p_hi, p_lo, OC, KP1);
        zero_pad_kernel<<<ceildiv(G * (KP1 - 2 * OC), 256), 256, 0, stream>>>(
            p_hi, p_lo, KP1, 2 * OC);
        // MLP weight splits
        wsplit_t_kernel<<<dim3(KP1 / 32, 1024 / 32), 256, 0, stream>>>(g0_w1, bt1h, bt1l, 2 * OC, 1024, KP1);
        wsplit_t_kernel<<<dim3(1024 / 32, 512 / 32), 256, 0, stream>>>(g0_w2, bt2h, bt2l, 1024, 512, 1024);
        wsplit_t_kernel<<<dim3(512 / 32, 256 / 32), 256, 0, stream>>>(f0_w1, bt3h, bt3l, 512, 256, 512);
        // MLP (bf16x3 MFMA)
        gemm3x_kernel<0><<<dim3(16, 16), 256, 0, stream>>>(
            p_hi, p_lo, bt1h, bt1l, g0_b1, nullptr, m1h, m1l, KP1);
        gemm3x_kernel<1><<<dim3(8, 16), 256, 0, stream>>>(
            m1h, m1l, bt2h, bt2l, g0_b2, pbn, nullptr, nullptr, 1024);
        bn_stats_kernel<<<512, 256, 0, stream>>>(pbn, G, 512, meanb, invb);
        bn_apply_kernel<<<ceildiv(G * 512, 256), 256, 0, stream>>>(
            pbn, g0_bn_g, g0_bn_b, meanb, invb, out_xg0, xgh, xgl, G * 512, 512);
        // head
        gemm3x_kernel<2><<<dim3(4, 16), 256, 0, stream>>>(
            xgh, xgl, bt3h, bt3l, f0_b1, hbuf, nullptr, nullptr, 512);
        head2_kernel<<<G / 4, 256, 0, stream>>>(hbuf, f0_w2, f0_b2, out_z, G);
    }

    // =========================== branch 1 (F=43, KP=64) ===========================
    {
        const int N = N1, E = E1C, OC = OC1;
        const int KP1 = 896;    // 2*OC=860 padded to x128
        unsigned short* p_hi = (unsigned short*)regionC;
        unsigned short* p_lo = p_hi + (size_t)G * KP1;
        float* pbn  = (float*)(p_hi + (size_t)G * KP1 * 2);
        float* hbuf = pbn + (size_t)G * 512;
        zero_int_kernel<<<ceildiv(N, 256), 256, 0, stream>>>(deg, N);
        hist_kernel<<<ceildiv(E, 256), 256, 0, stream>>>(ei1, E, deg);
        scan_phase1_kernel<<<NBS, 256, 0, stream>>>(deg, N, rowptr, bsum);
        scan_phase2_kernel<<<1, 1024, 0, stream>>>(bsum, NBS);
        scan_phase3_kernel<<<NBS, 256, 0, stream>>>(rowptr, bcur, bsum, N, E);
        edge_bucket_kernel<<<ceildiv(E, 2048), 256, 0, stream>>>(ei1, E, bcur, staging);
        csr_fill_kernel<<<NBKT, 256, 0, stream>>>(staging, rowptr, N, E, colb);
        tobf16_kernel<43, 64><<<ceildiv(N, 4), dim3(64, 4), 0, stream>>>(y_bf, x1, N);
        gather_wave_kernel<64, 8, 8><<<ceildiv(N, 4), 256, 0, stream>>>(
            t_bf, y_bf, rowptr, colb, N);
        conv1_mfma_kernel<64, 2, 3><<<ceildiv(N, 64), 256, 0, stream>>>(
            t_bf, wt_a1, b_c3, y_bf, 43, N);
        gather_wave_kernel<64, 8, 8><<<ceildiv(N, 4), 256, 0, stream>>>(
            t_bf, y_bf, rowptr, colb, N);
        conv2_pool_mfma_kernel<64, 2><<<dim3(2, G), 256, 0, stream>>>(
            t_bf, wt_b1, b_c4, starts1, p_hi, p_lo, OC, KP1);
        zero_pad_kernel<<<ceildiv(G * (KP1 - 2 * OC), 256), 256, 0, stream>>>(
            p_hi, p_lo, KP1, 2 * OC);
        wsplit_t_kernel<<<dim3(KP1 / 32, 1024 / 32), 256, 0, stream>>>(g1_w1, bt1h, bt1l, 2 * OC, 1024, KP1);
        wsplit_t_kernel<<<dim3(1024 / 32, 512 / 32), 256, 0, stream>>>(g1_w2, bt2h, bt2l, 1024, 512, 1024);
        wsplit_t_kernel<<<dim3(512 / 32, 256 / 32), 256, 0, stream>>>(f1_w1, bt3h, bt3l, 512, 256, 512);
        gemm3x_kernel<0><<<dim3(16, 16), 256, 0, stream>>>(
            p_hi, p_lo, bt1h, bt1l, g1_b1, nullptr, m1h, m1l, KP1);
        gemm3x_kernel<1><<<dim3(8, 16), 256, 0, stream>>>(
            m1h, m1l, bt2h, bt2l, g1_b2, pbn, nullptr, nullptr, 1024);
        bn_stats_kernel<<<512, 256, 0, stream>>>(pbn, G, 512, meanb, invb);
        bn_apply_kernel<<<ceildiv(G * 512, 256), 256, 0, stream>>>(
            pbn, g1_bn_g, g1_bn_b, meanb, invb, out_xg1, xgh, xgl, G * 512, 512);
        gemm3x_kernel<2><<<dim3(4, 16), 256, 0, stream>>>(
            xgh, xgl, bt3h, bt3l, f1_b1, hbuf, nullptr, nullptr, 512);
        head2_kernel<<<G / 4, 256, 0, stream>>>(hbuf, f1_w2, f1_b2, out_z1, G);
    }
}

// Round 3
// 813.049 us; speedup vs baseline: 1.3195x; 1.1187x over previous
//
#include <hip/hip_runtime.h>
#include <hip/hip_bf16.h>

// ---------------------------------------------------------------------------
// Problem constants
// ---------------------------------------------------------------------------
#define N0 100000
#define E0C 1600000
#define N1 100000
#define E1C 1600000
#define GCONST 512
#define F0C 93
#define F1C 43
#define OC0 (F0C * 10)   // 930
#define OC1 (F1C * 10)   // 430
#define BN_EPS 1e-5f
#define NBKT 391         // ceil(100000 / 256) buckets for CSR fill

typedef __attribute__((ext_vector_type(8))) short short8;
typedef __attribute__((ext_vector_type(4))) float floatx4;

static __device__ __forceinline__ unsigned short f2bf(float f) {
    unsigned u = __float_as_uint(f);
    unsigned r = (u + 0x7FFF + ((u >> 16) & 1)) >> 16;   // RNE
    return (unsigned short)r;
}
static __device__ __forceinline__ float bf2f(unsigned short u) {
    return __uint_as_float(((unsigned)u) << 16);
}
static __device__ __forceinline__ void split_bf(float v, unsigned short& h, unsigned short& l) {
    h = f2bf(v);
    l = f2bf(v - bf2f(h));
}

// ---------------------------------------------------------------------------
// zero ints
// ---------------------------------------------------------------------------
__global__ __launch_bounds__(256) void zero_int_kernel(int* __restrict__ p, int n) {
    int i = blockIdx.x * 256 + threadIdx.x;
    if (i < n) p[i] = 0;
}

// ---------------------------------------------------------------------------
// graph boundary search (both branches in one launch; blockIdx.y = branch)
// ---------------------------------------------------------------------------
__global__ __launch_bounds__(256) void find_starts2_kernel(const int* __restrict__ bat0,
                                                           const int* __restrict__ bat1,
                                                           int N, int G,
                                                           int* __restrict__ st0,
                                                           int* __restrict__ st1) {
    const int* batch = blockIdx.y ? bat1 : bat0;
    int* starts = blockIdx.y ? st1 : st0;
    int g = blockIdx.x * 256 + threadIdx.x;
    if (g > G) return;
    if (g == G) { starts[G] = N; return; }
    int lo = 0, hi = N;
    while (lo < hi) {
        int mid = (lo + hi) >> 1;
        if (batch[mid] < g) lo = mid + 1; else hi = mid;
    }
    starts[g] = lo;
}

// ---------------------------------------------------------------------------
// CSR build v2: bucket-grain histogram (LDS + ~300K dense global atomics),
// 391-entry scan, bucketed staging fill, then per-bucket fused
// {256-entry LDS histogram -> LDS scan -> rowptr write -> col scatter}.
// Replaces the old node-grain hist_kernel whose 1.6M device-scope atomics
// cost 66us and 50MB of line write-backs.
// ---------------------------------------------------------------------------
__global__ __launch_bounds__(256) void bucket_count_kernel(const int* __restrict__ ei,
                                                           int E, int* __restrict__ btot) {
    __shared__ int h[NBKT];
    int t = threadIdx.x;
    for (int i = t; i < NBKT; i += 256) h[i] = 0;
    __syncthreads();
    int base = blockIdx.x * 2048;
#pragma unroll
    for (int i = 0; i < 8; ++i) {
        int e = base + i * 256 + t;
        if (e < E) atomicAdd(&h[ei[E + e] >> 8], 1);
    }
    __syncthreads();
    for (int i = t; i < NBKT; i += 256) {
        int c = h[i];
        if (c) atomicAdd(&btot[i], c);
    }
}

__global__ __launch_bounds__(512) void bucket_scan_kernel(const int* __restrict__ btot,
                                                          int* __restrict__ bbase,
                                                          int* __restrict__ bcur) {
    __shared__ int sh[512];
    int t = threadIdx.x;
    int v = (t < NBKT) ? btot[t] : 0;
    sh[t] = v;
    __syncthreads();
    for (int o = 1; o < 512; o <<= 1) {
        int add = (t >= o) ? sh[t - o] : 0;
        __syncthreads();
        sh[t] += add;
        __syncthreads();
    }
    if (t < NBKT) {
        int ex = sh[t] - v;
        bbase[t] = ex;
        bcur[t] = ex;
    }
    if (t == NBKT) bbase[t] = sh[NBKT - 1];   // total == E
}

__global__ __launch_bounds__(256) void edge_bucket_kernel(const int* __restrict__ ei,
                                                          int E,
                                                          int* __restrict__ bcur,
                                                          int2* __restrict__ staging) {
    __shared__ int hist[NBKT];
    __shared__ int gbase[NBKT];
    int t = threadIdx.x;
    for (int i = t; i < NBKT; i += 256) hist[i] = 0;
    __syncthreads();
    int base = blockIdx.x * 2048;
    int srcv[8], dstv[8];
#pragma unroll
    for (int i = 0; i < 8; ++i) {
        int e = base + i * 256 + t;
        if (e < E) { srcv[i] = ei[e]; dstv[i] = ei[E + e]; }
        else dstv[i] = -1;
    }
#pragma unroll
    for (int i = 0; i < 8; ++i)
        if (dstv[i] >= 0) atomicAdd(&hist[dstv[i] >> 8], 1);
    __syncthreads();
    for (int i = t; i < NBKT; i += 256) {
        int c = hist[i];
        gbase[i] = c ? atomicAdd(&bcur[i], c) : 0;
        hist[i] = 0;   // reuse as local cursor
    }
    __syncthreads();
#pragma unroll
    for (int i = 0; i < 8; ++i) {
        if (dstv[i] >= 0) {
            int b = dstv[i] >> 8;
            int lofs = atomicAdd(&hist[b], 1);
            staging[gbase[b] + lofs] = make_int2(srcv[i], dstv[i]);
        }
    }
}

// block b: slice [bbase[b], bbase[b+1]) of staging (all dst in [256b, 256b+256)).
// LDS histogram of dst&255 -> exclusive scan -> rowptr for these 256 nodes
// (thread with node==N writes rowptr[N]=E) -> scatter col via LDS cursors.
__global__ __launch_bounds__(256) void csr_build_kernel(const int2* __restrict__ staging,
                                                        const int* __restrict__ bbase,
                                                        int N,
                                                        int* __restrict__ rowptr,
                                                        int* __restrict__ col) {
    __shared__ int h[256];
    __shared__ int sc[256];
    int b = blockIdx.x;
    int t = threadIdx.x;
    int s = bbase[b], e = bbase[b + 1];
    h[t] = 0;
    __syncthreads();
    for (int i = s + t; i < e; i += 256)
        atomicAdd(&h[staging[i].y & 255], 1);
    __syncthreads();
    int v = h[t];
    sc[t] = v;
    __syncthreads();
    for (int o = 1; o < 256; o <<= 1) {
        int add = (t >= o) ? sc[t - o] : 0;
        __syncthreads();
        sc[t] += add;
        __syncthreads();
    }
    int ex = s + (sc[t] - v);
    int node = (b << 8) + t;
    if (node <= N) rowptr[node] = ex;   // node==N: ex == E (trailing counts are 0)
    __syncthreads();
    sc[t] = ex;                          // reuse as cursor
    __syncthreads();
    for (int i = s + t; i < e; i += 256) {
        int2 ed = staging[i];
        int pos = atomicAdd(&sc[ed.y & 255], 1);
        col[pos] = ed.x;
    }
}

// ---------------------------------------------------------------------------
// all 4 conv weight transposes in one launch: Wt[c][k] (bf16, [rows][KP], 0-pad)
// ---------------------------------------------------------------------------
__global__ __launch_bounds__(128) void wt_prep4_kernel(const float* __restrict__ W0,
                                                       const float* __restrict__ W1,
                                                       const float* __restrict__ W2,
                                                       const float* __restrict__ W3,
                                                       unsigned short* __restrict__ T0,
                                                       unsigned short* __restrict__ T1,
                                                       unsigned short* __restrict__ T2,
                                                       unsigned short* __restrict__ T3) {
    const float* W; unsigned short* T; int OCr, Fr, KP, RB;
    switch (blockIdx.y) {
        case 0:  W = W0; T = T0; OCr = 93;  Fr = 93; KP = 96; RB = 96;   break;
        case 1:  W = W1; T = T1; OCr = 930; Fr = 93; KP = 96; RB = 1024; break;
        case 2:  W = W2; T = T2; OCr = 43;  Fr = 43; KP = 64; RB = 48;   break;
        default: W = W3; T = T3; OCr = 430; Fr = 43; KP = 64; RB = 512;  break;
    }
    int c = blockIdx.x, k = threadIdx.x;
    if (c >= RB || k >= KP) return;
    unsigned short v = 0;
    if (c < OCr && k < Fr) v = f2bf(W[(size_t)k * OCr + c]);
    T[(size_t)c * KP + k] = v;
}

// ---------------------------------------------------------------------------
// MLP weight transpose + hi/lo bf16 split: W[K][N] -> Th/Tl[N][KP] (0-padded)
// ---------------------------------------------------------------------------
__global__ __launch_bounds__(256) void wsplit_t_kernel(const float* __restrict__ W,
                                                       unsigned short* __restrict__ Th,
                                                       unsigned short* __restrict__ Tl,
                                                       int K, int N, int KP) {
    __shared__ float tile[32][33];
    int tx = threadIdx.x & 31, ty = threadIdx.x >> 5;   // 32 x 8
    int k0 = blockIdx.x * 32, c0 = blockIdx.y * 32;
    for (int r = ty; r < 32; r += 8) {
        int k = k0 + r;
        tile[r][tx] = (k < K) ? W[(size_t)k * N + c0 + tx] : 0.f;
    }
    __syncthreads();
    for (int r = ty; r < 32; r += 8) {
        int c = c0 + r;
        float v = tile[tx][r];
        unsigned short h, l;
        split_bf(v, h, l);
        Th[(size_t)c * KP + k0 + tx] = h;
        Tl[(size_t)c * KP + k0 + tx] = l;
    }
}

// zero pad columns [from, KP) of the 512-row hi/lo pooled buffers
__global__ __launch_bounds__(256) void zero_pad_kernel(unsigned short* __restrict__ ph,
                                                       unsigned short* __restrict__ pl,
                                                       int KP, int from) {
    int padw = KP - from;
    int total = GCONST * padw;
    int i = blockIdx.x * 256 + threadIdx.x;
    if (i >= total) return;
    int g = i / padw, c = from + (i - g * padw);
    ph[(size_t)g * KP + c] = 0;
    pl[(size_t)g * KP + c] = 0;
}

// ---------------------------------------------------------------------------
// fp32 [N][F] -> bf16 [N][KP] (zero-padded) streaming convert
// ---------------------------------------------------------------------------
template<int F, int KP>
__global__ __launch_bounds__(256) void tobf16_kernel(unsigned short* __restrict__ t,
                                                     const float* __restrict__ x, int N) {
    int node = blockIdx.x * blockDim.y + threadIdx.y;
    int f = threadIdx.x;
    if (node >= N) return;
    t[(size_t)node * KP + f] = (f < F) ? f2bf(x[(size_t)node * F + f]) : (unsigned short)0;
}

// ---------------------------------------------------------------------------
// gather-aggregate: one wave per node, 16B vector loads, index prefetch.
// ---------------------------------------------------------------------------
template<int KP, int CH, int GR>
__global__ __launch_bounds__(256) void gather_wave_kernel(unsigned short* __restrict__ t,
                                                          const unsigned short* __restrict__ x,
                                                          const int* __restrict__ rowptr,
                                                          const int* __restrict__ col,
                                                          int N) {
    int wave = threadIdx.x >> 6, lane = threadIdx.x & 63;
    int node = blockIdx.x * 4 + wave;
    if (node >= N) return;
    int g = lane / CH;
    int c = lane - g * CH;
    bool act = (g < GR);
    int s = rowptr[node], e = rowptr[node + 1];
    float acc[8] = {0.f, 0.f, 0.f, 0.f, 0.f, 0.f, 0.f, 0.f};
    int j = act ? (s - 1 + g) : e;
    int src = node;
    if (j >= s && j < e) src = col[j];
    while (j < e) {
        int jn = j + GR;
        int srcn = (jn < e) ? col[jn] : 0;          // prefetch next index
        short8 v = *(const short8*)(x + (size_t)src * KP + c * 8);
#pragma unroll
        for (int i = 0; i < 8; ++i) acc[i] += bf2f((unsigned short)v[i]);
        j = jn; src = srcn;
    }
    if (GR == 8) {
#pragma unroll
        for (int i = 0; i < 8; ++i) {
            float v = acc[i];
            v += __shfl_xor(v, 8);
            v += __shfl_xor(v, 16);
            v += __shfl_xor(v, 32);
            acc[i] = v;
        }
    } else {
#pragma unroll
        for (int i = 0; i < 8; ++i) {
            float v = acc[i];
            float v1 = __shfl(v, lane + CH);
            float v2 = __shfl(v, lane + 2 * CH);
            float v3 = __shfl(v, lane + 3 * CH);
            float v4 = __shfl(v, lane + 4 * CH);
            acc[i] = v + v1 + v2 + v3 + v4;
        }
    }
    if (lane < CH) {
        short8 o;
#pragma unroll
        for (int i = 0; i < 8; ++i) o[i] = (short)f2bf(acc[i]);
        *(short8*)(t + (size_t)node * KP + lane * 8) = o;
    }
}

// ---------------------------------------------------------------------------
// conv1 via MFMA 16x16x32 bf16: y = relu(t @ W + b), y stored bf16 [N][KP]
// ---------------------------------------------------------------------------
template<int KP, int KS, int NT>
__global__ __launch_bounds__(256) void conv1_mfma_kernel(const unsigned short* __restrict__ t,
                                                         const unsigned short* __restrict__ Wt,
                                                         const float* __restrict__ bias,
                                                         unsigned short* __restrict__ y,
                                                         int NC, int N) {
    int wave = threadIdx.x >> 6, lane = threadIdx.x & 63;
    int quad = lane >> 4, l15 = lane & 15;
    int r0 = (blockIdx.x * 4 + wave) * 16;
    const short8 z8 = {0, 0, 0, 0, 0, 0, 0, 0};
    short8 a[KS];
    int arow = r0 + l15;
#pragma unroll
    for (int ks = 0; ks < KS; ++ks)
        a[ks] = (arow < N) ? *(const short8*)(t + (size_t)arow * KP + ks * 32 + quad * 8) : z8;
#pragma unroll
    for (int nt = 0; nt < NT; ++nt) {
        int colb = nt * 16 + l15;
        floatx4 c = {0.f, 0.f, 0.f, 0.f};
#pragma unroll
        for (int ks = 0; ks < KS; ++ks) {
            short8 b = *(const short8*)(Wt + (size_t)colb * KP + ks * 32 + quad * 8);
            c = __builtin_amdgcn_mfma_f32_16x16x32_bf16(a[ks], b, c, 0, 0, 0);
        }
        float bc = (colb < NC) ? bias[colb] : 0.f;
#pragma unroll
        for (int r = 0; r < 4; ++r) {
            int row = r0 + quad * 4 + r;
            if (row < N) {
                float o = fmaxf(c[r] + bc, 0.f);
                y[(size_t)row * KP + colb] = f2bf(o);
            }
        }
    }
}

// ---------------------------------------------------------------------------
// conv2 + relu + mean/max pool via MFMA, fused per graph.
// Epilogue emits pooled rows as hi/lo bf16 split: row = [mean(OC)|max(OC)|pad]
// ---------------------------------------------------------------------------
template<int KP, int KS>
__global__ __launch_bounds__(256) void conv2_pool_mfma_kernel(const unsigned short* __restrict__ t,
                                                              const unsigned short* __restrict__ Wt,
                                                              const float* __restrict__ bias,
                                                              const int* __restrict__ starts,
                                                              unsigned short* __restrict__ ph,
                                                              unsigned short* __restrict__ pl,
                                                              int OC, int KPad) {
    int wave = threadIdx.x >> 6, lane = threadIdx.x & 63;
    int quad = lane >> 4, l15 = lane & 15;
    int g = blockIdx.y;
    int cw0 = blockIdx.x * 256 + wave * 64;
    short8 bfr[4][KS];
    float bs[4];
#pragma unroll
    for (int ti = 0; ti < 4; ++ti) {
        int colb = cw0 + ti * 16 + l15;
#pragma unroll
        for (int ks = 0; ks < KS; ++ks)
            bfr[ti][ks] = *(const short8*)(Wt + (size_t)colb * KP + ks * 32 + quad * 8);
        bs[ti] = (colb < OC) ? bias[colb] : 0.f;
    }
    int s = starts[g], e = starts[g + 1];
    float sum[4] = {0.f, 0.f, 0.f, 0.f};
    float mx[4]  = {0.f, 0.f, 0.f, 0.f};
    const short8 z8 = {0, 0, 0, 0, 0, 0, 0, 0};
    for (int ns = s; ns < e; ns += 16) {
        short8 a[KS];
        int arow = ns + l15;
        bool av = arow < e;
#pragma unroll
        for (int ks = 0; ks < KS; ++ks)
            a[ks] = av ? *(const short8*)(t + (size_t)arow * KP + ks * 32 + quad * 8) : z8;
        int rbase = ns + quad * 4;
#pragma unroll
        for (int ti = 0; ti < 4; ++ti) {
            floatx4 c = {0.f, 0.f, 0.f, 0.f};
#pragma unroll
            for (int ks = 0; ks < KS; ++ks)
                c = __builtin_amdgcn_mfma_f32_16x16x32_bf16(a[ks], bfr[ti][ks], c, 0, 0, 0);
#pragma unroll
            for (int r = 0; r < 4; ++r) {
                float o = fmaxf(c[r] + bs[ti], 0.f);
                if (rbase + r < e) {
                    sum[ti] += o;
                    mx[ti] = fmaxf(mx[ti], o);
                }
            }
        }
    }
    int cnt = e - s;
    float rc = 1.f / (float)(cnt > 0 ? cnt : 1);
#pragma unroll
    for (int ti = 0; ti < 4; ++ti) {
        float sv = sum[ti], mv = mx[ti];
        sv += __shfl_down(sv, 32);
        mv = fmaxf(mv, __shfl_down(mv, 32));
        sv += __shfl_down(sv, 16);
        mv = fmaxf(mv, __shfl_down(mv, 16));
        if (lane < 16) {
            int colb = cw0 + ti * 16 + l15;
            if (colb < OC) {
                size_t base = (size_t)g * (size_t)KPad;
                unsigned short h, l;
                split_bf(sv * rc, h, l);
                ph[base + colb] = h; pl[base + colb] = l;
                split_bf(mv, h, l);
                ph[base + OC + colb] = h; pl[base + OC + colb] = l;
            }
        }
    }
}

// ---------------------------------------------------------------------------
// split-bf16 ("bf16x3") MFMA GEMM: C = A @ B^T(+bias), fp32-equivalent.
//   acc += Ah*Bh + Al*Bh + Ah*Bl  (Al*Bl ~2^-18, omitted)
//   MODE 0: relu, write hi/lo bf16.  MODE 1: fp32.  MODE 2: relu, fp32.
// ---------------------------------------------------------------------------
template<int MODE>
__global__ __launch_bounds__(256) void gemm3x_kernel(const unsigned short* __restrict__ Ah,
                                                     const unsigned short* __restrict__ Al,
                                                     const unsigned short* __restrict__ Bh,
                                                     const unsigned short* __restrict__ Bl,
                                                     const float* __restrict__ bias,
                                                     float* __restrict__ Cf,
                                                     unsigned short* __restrict__ Ch,
                                                     unsigned short* __restrict__ Cl,
                                                     int KP) {
    int wave = threadIdx.x >> 6, lane = threadIdx.x & 63;
    int quad = lane >> 4, l15 = lane & 15;
    int r0 = blockIdx.y * 32 + (wave & 1) * 16;
    int c0 = blockIdx.x * 64 + (wave >> 1) * 32;
    int Ncols = gridDim.x * 64;
    floatx4 acc0 = {0.f, 0.f, 0.f, 0.f};
    floatx4 acc1 = {0.f, 0.f, 0.f, 0.f};
    const unsigned short* arh = Ah + (size_t)(r0 + l15) * KP;
    const unsigned short* arl = Al + (size_t)(r0 + l15) * KP;
    const unsigned short* b0h = Bh + (size_t)(c0 + l15) * KP;
    const unsigned short* b0l = Bl + (size_t)(c0 + l15) * KP;
    const unsigned short* b1h = Bh + (size_t)(c0 + 16 + l15) * KP;
    const unsigned short* b1l = Bl + (size_t)(c0 + 16 + l15) * KP;
    for (int k0 = 0; k0 < KP; k0 += 128) {
        short8 ah[4], al[4];
#pragma unroll
        for (int q = 0; q < 4; ++q) {
            ah[q] = *(const short8*)(arh + k0 + q * 32 + quad * 8);
            al[q] = *(const short8*)(arl + k0 + q * 32 + quad * 8);
        }
#pragma unroll
        for (int q = 0; q < 4; ++q) {
            short8 bh = *(const short8*)(b0h + k0 + q * 32 + quad * 8);
            short8 bl = *(const short8*)(b0l + k0 + q * 32 + quad * 8);
            acc0 = __builtin_amdgcn_mfma_f32_16x16x32_bf16(ah[q], bh, acc0, 0, 0, 0);
            acc0 = __builtin_amdgcn_mfma_f32_16x16x32_bf16(al[q], bh, acc0, 0, 0, 0);
            acc0 = __builtin_amdgcn_mfma_f32_16x16x32_bf16(ah[q], bl, acc0, 0, 0, 0);
            bh = *(const short8*)(b1h + k0 + q * 32 + quad * 8);
            bl = *(const short8*)(b1l + k0 + q * 32 + quad * 8);
            acc1 = __builtin_amdgcn_mfma_f32_16x16x32_bf16(ah[q], bh, acc1, 0, 0, 0);
            acc1 = __builtin_amdgcn_mfma_f32_16x16x32_bf16(al[q], bh, acc1, 0, 0, 0);
            acc1 = __builtin_amdgcn_mfma_f32_16x16x32_bf16(ah[q], bl, acc1, 0, 0, 0);
        }
    }
    int col0 = c0 + l15, col1 = c0 + 16 + l15;
    float bc0 = bias[col0], bc1 = bias[col1];
#pragma unroll
    for (int r = 0; r < 4; ++r) {
        int row = r0 + quad * 4 + r;
        float v0 = acc0[r] + bc0;
        float v1 = acc1[r] + bc1;
        if (MODE != 1) { v0 = fmaxf(v0, 0.f); v1 = fmaxf(v1, 0.f); }
        if (MODE == 0) {
            unsigned short h, l;
            split_bf(v0, h, l);
            Ch[(size_t)row * Ncols + col0] = h; Cl[(size_t)row * Ncols + col0] = l;
            split_bf(v1, h, l);
            Ch[(size_t)row * Ncols + col1] = h; Cl[(size_t)row * Ncols + col1] = l;
        } else {
            Cf[(size_t)row * Ncols + col0] = v0;
            Cf[(size_t)row * Ncols + col1] = v1;
        }
    }
}

// ---------------------------------------------------------------------------
// head2: z[row][0..1] = h[row][0..255] @ w2[256][2] + b2. Wave per row.
// ---------------------------------------------------------------------------
__global__ __launch_bounds__(256) void head2_kernel(const float* __restrict__ h,
                                                    const float* __restrict__ w2,
                                                    const float* __restrict__ b2,
                                                    float* __restrict__ z, int M) {
    int wave = threadIdx.x >> 6, lane = threadIdx.x & 63;
    int row = blockIdx.x * 4 + wave;
    if (row >= M) return;
    float4 hv = *(const float4*)(h + (size_t)row * 256 + lane * 4);
    const float* wp = w2 + lane * 8;
    float s0 = hv.x * wp[0] + hv.y * wp[2] + hv.z * wp[4] + hv.w * wp[6];
    float s1 = hv.x * wp[1] + hv.y * wp[3] + hv.z * wp[5] + hv.w * wp[7];
#pragma unroll
    for (int offd = 32; offd >= 1; offd >>= 1) {
        s0 += __shfl_down(s0, offd);
        s1 += __shfl_down(s1, offd);
    }
    if (lane == 0) {
        z[(size_t)row * 2 + 0] = s0 + b2[0];
        z[(size_t)row * 2 + 1] = s1 + b2[1];
    }
}

// ---------------------------------------------------------------------------
// batchnorm stats + apply (apply also emits hi/lo bf16 for the head GEMM)
// ---------------------------------------------------------------------------
__global__ __launch_bounds__(256) void bn_stats_kernel(const float* __restrict__ p,
                                                       int rows, int cols,
                                                       float* __restrict__ mean,
                                                       float* __restrict__ inv) {
    int c = blockIdx.x;
    float s = 0.f, s2 = 0.f;
    for (int r = threadIdx.x; r < rows; r += 256) {
        float v = p[(size_t)r * cols + c];
        s += v;
        s2 += v * v;
    }
    __shared__ float ls[256], ls2[256];
    ls[threadIdx.x] = s;
    ls2[threadIdx.x] = s2;
    __syncthreads();
    for (int st = 128; st > 0; st >>= 1) {
        if (threadIdx.x < st) {
            ls[threadIdx.x] += ls[threadIdx.x + st];
            ls2[threadIdx.x] += ls2[threadIdx.x + st];
        }
        __syncthreads();
    }
    if (threadIdx.x == 0) {
        float m = ls[0] / (float)rows;
        float var = ls2[0] / (float)rows - m * m;
        mean[c] = m;
        inv[c] = 1.f / sqrtf(var + BN_EPS);
    }
}

__global__ __launch_bounds__(256) void bn_apply_kernel(const float* __restrict__ p,
                                                       const float* __restrict__ gamma,
                                                       const float* __restrict__ beta,
                                                       const float* __restrict__ mean,
                                                       const float* __restrict__ inv,
                                                       float* __restrict__ outp,
                                                       unsigned short* __restrict__ oh,
                                                       unsigned short* __restrict__ ol,
                                                       int total, int cols) {
    int i = blockIdx.x * 256 + threadIdx.x;
    if (i >= total) return;
    int c = i & (cols - 1);
    float v = gamma[c] * (p[i] - mean[c]) * inv[c] + beta[c];
    outp[i] = v;
    unsigned short h, l;
    split_bf(v, h, l);
    oh[i] = h;
    ol[i] = l;
}

// ---------------------------------------------------------------------------
// launch
// ---------------------------------------------------------------------------
static inline int ceildiv(int a, int b) { return (a + b - 1) / b; }

extern "C" void kernel_launch(void* const* d_in, const int* in_sizes, int n_in,
                              void* d_out, int out_size, void* d_ws, size_t ws_size,
                              hipStream_t stream) {
    const float* x0   = (const float*)d_in[0];
    const float* x1   = (const float*)d_in[1];
    const int*   ei0  = (const int*)d_in[2];
    const int*   ei1  = (const int*)d_in[3];
    const int*   bat0 = (const int*)d_in[4];
    const int*   bat1 = (const int*)d_in[5];
    const float* w_c1 = (const float*)d_in[6];
    const float* b_c1 = (const float*)d_in[7];
    const float* w_c2 = (const float*)d_in[8];
    const float* b_c2 = (const float*)d_in[9];
    const float* w_c3 = (const float*)d_in[10];
    const float* b_c3 = (const float*)d_in[11];
    const float* w_c4 = (const float*)d_in[12];
    const float* b_c4 = (const float*)d_in[13];
    const float* g0_w1 = (const float*)d_in[14];
    const float* g0_b1 = (const float*)d_in[15];
    const float* g0_w2 = (const float*)d_in[16];
    const float* g0_b2 = (const float*)d_in[17];
    const float* g0_bn_g = (const float*)d_in[18];
    const float* g0_bn_b = (const float*)d_in[19];
    const float* g1_w1 = (const float*)d_in[20];
    const float* g1_b1 = (const float*)d_in[21];
    const float* g1_w2 = (const float*)d_in[22];
    const float* g1_b2 = (const float*)d_in[23];
    const float* g1_bn_g = (const float*)d_in[24];
    const float* g1_bn_b = (const float*)d_in[25];
    const float* f0_w1 = (const float*)d_in[26];
    const float* f0_b1 = (const float*)d_in[27];
    const float* f0_w2 = (const float*)d_in[28];
    const float* f0_b2 = (const float*)d_in[29];
    const float* f1_w1 = (const float*)d_in[30];
    const float* f1_b1 = (const float*)d_in[31];
    const float* f1_w2 = (const float*)d_in[32];
    const float* f1_b2 = (const float*)d_in[33];

    float* out = (float*)d_out;
    float* out_z   = out;
    float* out_xg0 = out + 1024;
    float* out_xg1 = out + 1024 + 262144;
    float* out_z1  = out + 1024 + 262144 + 262144;

    // workspace carve (floats; all offsets multiples of 4 -> 16B aligned)
    float* ws = (float*)d_ws;
    size_t off = 0;
    auto alloc = [&](size_t n) { float* p = ws + off; off += n; return p; };
    unsigned short* t_bf = (unsigned short*)alloc((size_t)N0 * 96 / 2);  // bf16 [N][96]
    unsigned short* y_bf = (unsigned short*)alloc((size_t)N0 * 96 / 2);  // bf16 [N][96] (also x-bf16 staging)
    unsigned short* wt_a0 = (unsigned short*)alloc(96 * 96 / 2);         // branch0 conv1 Wt
    unsigned short* wt_b0 = (unsigned short*)alloc(1024 * 96 / 2);       // branch0 conv2 Wt
    unsigned short* wt_a1 = (unsigned short*)alloc(48 * 64 / 2);         // branch1 conv1 Wt
    unsigned short* wt_b1 = (unsigned short*)alloc(512 * 64 / 2);        // branch1 conv2 Wt
    // MLP hi/lo weight buffers (aliased across branches; sized for branch0)
    unsigned short* bt1h = (unsigned short*)alloc((size_t)1024 * 1920 / 2);
    unsigned short* bt1l = (unsigned short*)alloc((size_t)1024 * 1920 / 2);
    unsigned short* bt2h = (unsigned short*)alloc((size_t)512 * 1024 / 2);
    unsigned short* bt2l = (unsigned short*)alloc((size_t)512 * 1024 / 2);
    unsigned short* bt3h = (unsigned short*)alloc((size_t)256 * 512 / 2);
    unsigned short* bt3l = (unsigned short*)alloc((size_t)256 * 512 / 2);
    unsigned short* m1h  = (unsigned short*)alloc((size_t)512 * 1024 / 2);
    unsigned short* m1l  = (unsigned short*)alloc((size_t)512 * 1024 / 2);
    unsigned short* xgh  = (unsigned short*)alloc((size_t)512 * 512 / 2);
    unsigned short* xgl  = (unsigned short*)alloc((size_t)512 * 512 / 2);
    int*   btot  = (int*)alloc(512);                                     // bucket totals
    int*   bbase = (int*)alloc(512);                                     // bucket base offsets
    int*   bcur  = (int*)alloc(512);                                     // bucket cursors
    // Union region C: CSR (graph phase) aliases pooled-hi/lo + MLP fp32 temps.
    size_t csr_floats = (size_t)(N0 + 4) + E0C + 2 * (size_t)E0C;        // rowptr|col|staging
    float* regionC = alloc(csr_floats);
    int* rowptr  = (int*)regionC;
    int* colb    = rowptr + (N0 + 4);
    int2* staging = (int2*)(colb + E0C);
    float* meanb   = alloc(512);
    float* invb    = alloc(512);
    int*   starts0 = (int*)alloc(520);
    int*   starts1 = (int*)alloc(520);

    const int G = GCONST;

    // ------------------- shared prologue (both branches) -------------------
    find_starts2_kernel<<<dim3(3, 2), 256, 0, stream>>>(bat0, bat1, N0, G, starts0, starts1);
    wt_prep4_kernel<<<dim3(1024, 4), 128, 0, stream>>>(w_c1, w_c2, w_c3, w_c4,
                                                       wt_a0, wt_b0, wt_a1, wt_b1);

    // =========================== branch 0 (F=93, KP=96) ===========================
    {
        const int N = N0, E = E0C, OC = OC0;
        const int KP1 = 1920;   // 2*OC=1860 padded to x128
        unsigned short* p_hi = (unsigned short*)regionC;   // CSR dead by conv2_pool time
        unsigned short* p_lo = p_hi + (size_t)G * KP1;
        float* pbn  = (float*)(p_hi + (size_t)G * KP1 * 2);
        float* hbuf = pbn + (size_t)G * 512;
        zero_int_kernel<<<2, 256, 0, stream>>>(btot, NBKT);
        bucket_count_kernel<<<ceildiv(E, 2048), 256, 0, stream>>>(ei0, E, btot);
        bucket_scan_kernel<<<1, 512, 0, stream>>>(btot, bbase, bcur);
        edge_bucket_kernel<<<ceildiv(E, 2048), 256, 0, stream>>>(ei0, E, bcur, staging);
        csr_build_kernel<<<NBKT, 256, 0, stream>>>(staging, bbase, N, rowptr, colb);
        tobf16_kernel<93, 96><<<ceildiv(N, 2), dim3(96, 2), 0, stream>>>(y_bf, x0, N);
        gather_wave_kernel<96, 12, 5><<<ceildiv(N, 4), 256, 0, stream>>>(
            t_bf, y_bf, rowptr, colb, N);
        conv1_mfma_kernel<96, 3, 6><<<ceildiv(N, 64), 256, 0, stream>>>(
            t_bf, wt_a0, b_c1, y_bf, 93, N);
        gather_wave_kernel<96, 12, 5><<<ceildiv(N, 4), 256, 0, stream>>>(
            t_bf, y_bf, rowptr, colb, N);
        conv2_pool_mfma_kernel<96, 3><<<dim3(4, G), 256, 0, stream>>>(
            t_bf, wt_b0, b_c2, starts0, p_hi, p_lo, OC, KP1);
        zero_pad_kernel<<<ceildiv(G * (KP1 - 2 * OC), 256), 256, 0, stream>>>(
            p_hi, p_lo, KP1, 2 * OC);
        // MLP weight splits
        wsplit_t_kernel<<<dim3(KP1 / 32, 1024 / 32), 256, 0, stream>>>(g0_w1, bt1h, bt1l, 2 * OC, 1024, KP1);
        wsplit_t_kernel<<<dim3(1024 / 32, 512 / 32), 256, 0, stream>>>(g0_w2, bt2h, bt2l, 1024, 512, 1024);
        wsplit_t_kernel<<<dim3(512 / 32, 256 / 32), 256, 0, stream>>>(f0_w1, bt3h, bt3l, 512, 256, 512);
        // MLP (bf16x3 MFMA)
        gemm3x_kernel<0><<<dim3(16, 16), 256, 0, stream>>>(
            p_hi, p_lo, bt1h, bt1l, g0_b1, nullptr, m1h, m1l, KP1);
        gemm3x_kernel<1><<<dim3(8, 16), 256, 0, stream>>>(
            m1h, m1l, bt2h, bt2l, g0_b2, pbn, nullptr, nullptr, 1024);
        bn_stats_kernel<<<512, 256, 0, stream>>>(pbn, G, 512, meanb, invb);
        bn_apply_kernel<<<ceildiv(G * 512, 256), 256, 0, stream>>>(
            pbn, g0_bn_g, g0_bn_b, meanb, invb, out_xg0, xgh, xgl, G * 512, 512);
        // head
        gemm3x_kernel<2><<<dim3(4, 16), 256, 0, stream>>>(
            xgh, xgl, bt3h, bt3l, f0_b1, hbuf, nullptr, nullptr, 512);
        head2_kernel<<<G / 4, 256, 0, stream>>>(hbuf, f0_w2, f0_b2, out_z, G);
    }

    // =========================== branch 1 (F=43, KP=64) ===========================
    {
        const int N = N1, E = E1C, OC = OC1;
        const int KP1 = 896;    // 2*OC=860 padded to x128
        unsigned short* p_hi = (unsigned short*)regionC;
        unsigned short* p_lo = p_hi + (size_t)G * KP1;
        float* pbn  = (float*)(p_hi + (size_t)G * KP1 * 2);
        float* hbuf = pbn + (size_t)G * 512;
        zero_int_kernel<<<2, 256, 0, stream>>>(btot, NBKT);
        bucket_count_kernel<<<ceildiv(E, 2048), 256, 0, stream>>>(ei1, E, btot);
        bucket_scan_kernel<<<1, 512, 0, stream>>>(btot, bbase, bcur);
        edge_bucket_kernel<<<ceildiv(E, 2048), 256, 0, stream>>>(ei1, E, bcur, staging);
        csr_build_kernel<<<NBKT, 256, 0, stream>>>(staging, bbase, N, rowptr, colb);
        tobf16_kernel<43, 64><<<ceildiv(N, 4), dim3(64, 4), 0, stream>>>(y_bf, x1, N);
        gather_wave_kernel<64, 8, 8><<<ceildiv(N, 4), 256, 0, stream>>>(
            t_bf, y_bf, rowptr, colb, N);
        conv1_mfma_kernel<64, 2, 3><<<ceildiv(N, 64), 256, 0, stream>>>(
            t_bf, wt_a1, b_c3, y_bf, 43, N);
        gather_wave_kernel<64, 8, 8><<<ceildiv(N, 4), 256, 0, stream>>>(
            t_bf, y_bf, rowptr, colb, N);
        conv2_pool_mfma_kernel<64, 2><<<dim3(2, G), 256, 0, stream>>>(
            t_bf, wt_b1, b_c4, starts1, p_hi, p_lo, OC, KP1);
        zero_pad_kernel<<<ceildiv(G * (KP1 - 2 * OC), 256), 256, 0, stream>>>(
            p_hi, p_lo, KP1, 2 * OC);
        wsplit_t_kernel<<<dim3(KP1 / 32, 1024 / 32), 256, 0, stream>>>(g1_w1, bt1h, bt1l, 2 * OC, 1024, KP1);
        wsplit_t_kernel<<<dim3(1024 / 32, 512 / 32), 256, 0, stream>>>(g1_w2, bt2h, bt2l, 1024, 512, 1024);
        wsplit_t_kernel<<<dim3(512 / 32, 256 / 32), 256, 0, stream>>>(f1_w1, bt3h, bt3l, 512, 256, 512);
        gemm3x_kernel<0><<<dim3(16, 16), 256, 0, stream>>>(
            p_hi, p_lo, bt1h, bt1l, g1_b1, nullptr, m1h, m1l, KP1);
        gemm3x_kernel<1><<<dim3(8, 16), 256, 0, stream>>>(
            m1h, m1l, bt2h, bt2l, g1_b2, pbn, nullptr, nullptr, 1024);
        bn_stats_kernel<<<512, 256, 0, stream>>>(pbn, G, 512, meanb, invb);
        bn_apply_kernel<<<ceildiv(G * 512, 256), 256, 0, stream>>>(
            pbn, g1_bn_g, g1_bn_b, meanb, invb, out_xg1, xgh, xgl, G * 512, 512);
        gemm3x_kernel<2><<<dim3(4, 16), 256, 0, stream>>>(
            xgh, xgl, bt3h, bt3l, f1_b1, hbuf, nullptr, nullptr, 512);
        head2_kernel<<<G / 4, 256, 0, stream>>>(hbuf, f1_w2, f1_b2, out_z1, G);
    }
}

// Round 4
// 738.590 us; speedup vs baseline: 1.4525x; 1.1008x over previous
//
#include <hip/hip_runtime.h>
#include <hip/hip_bf16.h>

// ---------------------------------------------------------------------------
// Problem constants
// ---------------------------------------------------------------------------
#define N0 100000
#define E0C 1600000
#define N1 100000
#define E1C 1600000
#define GCONST 512
#define F0C 93
#define F1C 43
#define OC0 (F0C * 10)   // 930
#define OC1 (F1C * 10)   // 430
#define BN_EPS 1e-5f
#define NBKT 391         // ceil(100000 / 256) buckets for CSR fill

typedef __attribute__((ext_vector_type(8))) short short8;
typedef __attribute__((ext_vector_type(4))) float floatx4;

static __device__ __forceinline__ unsigned short f2bf(float f) {
    unsigned u = __float_as_uint(f);
    unsigned r = (u + 0x7FFF + ((u >> 16) & 1)) >> 16;   // RNE
    return (unsigned short)r;
}
static __device__ __forceinline__ float bf2f(unsigned short u) {
    return __uint_as_float(((unsigned)u) << 16);
}
static __device__ __forceinline__ void split_bf(float v, unsigned short& h, unsigned short& l) {
    h = f2bf(v);
    l = f2bf(v - bf2f(h));
}

// ---------------------------------------------------------------------------
// small utility kernels
// ---------------------------------------------------------------------------
__global__ __launch_bounds__(256) void zero_int_kernel(int* __restrict__ p, int n) {
    int i = blockIdx.x * 256 + threadIdx.x;
    if (i < n) p[i] = 0;
}

__global__ __launch_bounds__(256) void find_starts2_kernel(const int* __restrict__ bat0,
                                                           const int* __restrict__ bat1,
                                                           int N, int G,
                                                           int* __restrict__ st0,
                                                           int* __restrict__ st1) {
    const int* batch = blockIdx.y ? bat1 : bat0;
    int* starts = blockIdx.y ? st1 : st0;
    int g = blockIdx.x * 256 + threadIdx.x;
    if (g > G) return;
    if (g == G) { starts[G] = N; return; }
    int lo = 0, hi = N;
    while (lo < hi) {
        int mid = (lo + hi) >> 1;
        if (batch[mid] < g) lo = mid + 1; else hi = mid;
    }
    starts[g] = lo;
}

// zero pad columns [from, KP) of the 512-row hi/lo pooled buffers
__global__ __launch_bounds__(256) void zero_pad_kernel(unsigned short* __restrict__ ph,
                                                       unsigned short* __restrict__ pl,
                                                       int KP, int from) {
    int padw = KP - from;
    int total = GCONST * padw;
    int i = blockIdx.x * 256 + threadIdx.x;
    if (i >= total) return;
    int g = i / padw, c = from + (i - g * padw);
    ph[(size_t)g * KP + c] = 0;
    pl[(size_t)g * KP + c] = 0;
}

// ---------------------------------------------------------------------------
// CSR build (both branches in one launch via blockIdx.y)
// ---------------------------------------------------------------------------
__global__ __launch_bounds__(256) void bucket_count2_kernel(const int* __restrict__ ei0,
                                                            const int* __restrict__ ei1,
                                                            int E, int* __restrict__ btot2) {
    const int* ei = blockIdx.y ? ei1 : ei0;
    int* btot = btot2 + blockIdx.y * 512;
    __shared__ int h[NBKT];
    int t = threadIdx.x;
    for (int i = t; i < NBKT; i += 256) h[i] = 0;
    __syncthreads();
    int base = blockIdx.x * 2048;
#pragma unroll
    for (int i = 0; i < 8; ++i) {
        int e = base + i * 256 + t;
        if (e < E) atomicAdd(&h[ei[E + e] >> 8], 1);
    }
    __syncthreads();
    for (int i = t; i < NBKT; i += 256) {
        int c = h[i];
        if (c) atomicAdd(&btot[i], c);
    }
}

__global__ __launch_bounds__(512) void bucket_scan2_kernel(const int* __restrict__ btot2,
                                                           int* __restrict__ bbase2,
                                                           int* __restrict__ bcur2) {
    const int* btot = btot2 + blockIdx.x * 512;
    int* bbase = bbase2 + blockIdx.x * 512;
    int* bcur  = bcur2 + blockIdx.x * 512;
    __shared__ int sh[512];
    int t = threadIdx.x;
    int v = (t < NBKT) ? btot[t] : 0;
    sh[t] = v;
    __syncthreads();
    for (int o = 1; o < 512; o <<= 1) {
        int add = (t >= o) ? sh[t - o] : 0;
        __syncthreads();
        sh[t] += add;
        __syncthreads();
    }
    if (t < NBKT) {
        int ex = sh[t] - v;
        bbase[t] = ex;
        bcur[t] = ex;
    }
    if (t == NBKT) bbase[t] = sh[NBKT - 1];   // total == E
}

__global__ __launch_bounds__(256) void edge_bucket2_kernel(const int* __restrict__ ei0,
                                                           const int* __restrict__ ei1,
                                                           int E, int* __restrict__ bcur2,
                                                           int2* __restrict__ st0,
                                                           int2* __restrict__ st1) {
    const int* ei = blockIdx.y ? ei1 : ei0;
    int* bcur = bcur2 + blockIdx.y * 512;
    int2* staging = blockIdx.y ? st1 : st0;
    __shared__ int hist[NBKT];
    __shared__ int gbase[NBKT];
    int t = threadIdx.x;
    for (int i = t; i < NBKT; i += 256) hist[i] = 0;
    __syncthreads();
    int base = blockIdx.x * 2048;
    int srcv[8], dstv[8];
#pragma unroll
    for (int i = 0; i < 8; ++i) {
        int e = base + i * 256 + t;
        if (e < E) { srcv[i] = ei[e]; dstv[i] = ei[E + e]; }
        else dstv[i] = -1;
    }
#pragma unroll
    for (int i = 0; i < 8; ++i)
        if (dstv[i] >= 0) atomicAdd(&hist[dstv[i] >> 8], 1);
    __syncthreads();
    for (int i = t; i < NBKT; i += 256) {
        int c = hist[i];
        gbase[i] = c ? atomicAdd(&bcur[i], c) : 0;
        hist[i] = 0;   // reuse as local cursor
    }
    __syncthreads();
#pragma unroll
    for (int i = 0; i < 8; ++i) {
        if (dstv[i] >= 0) {
            int b = dstv[i] >> 8;
            int lofs = atomicAdd(&hist[b], 1);
            staging[gbase[b] + lofs] = make_int2(srcv[i], dstv[i]);
        }
    }
}

__global__ __launch_bounds__(256) void csr_build2_kernel(const int2* __restrict__ st0,
                                                         const int2* __restrict__ st1,
                                                         const int* __restrict__ bbase2,
                                                         int N,
                                                         int* __restrict__ rp0,
                                                         int* __restrict__ rp1,
                                                         int* __restrict__ c0,
                                                         int* __restrict__ c1) {
    const int2* staging = blockIdx.y ? st1 : st0;
    const int* bbase = bbase2 + blockIdx.y * 512;
    int* rowptr = blockIdx.y ? rp1 : rp0;
    int* col = blockIdx.y ? c1 : c0;
    __shared__ int h[256];
    __shared__ int sc[256];
    int b = blockIdx.x;
    int t = threadIdx.x;
    int s = bbase[b], e = bbase[b + 1];
    h[t] = 0;
    __syncthreads();
    for (int i = s + t; i < e; i += 256)
        atomicAdd(&h[staging[i].y & 255], 1);
    __syncthreads();
    int v = h[t];
    sc[t] = v;
    __syncthreads();
    for (int o = 1; o < 256; o <<= 1) {
        int add = (t >= o) ? sc[t - o] : 0;
        __syncthreads();
        sc[t] += add;
        __syncthreads();
    }
    int ex = s + (sc[t] - v);
    int node = (b << 8) + t;
    if (node <= N) rowptr[node] = ex;
    __syncthreads();
    sc[t] = ex;                          // reuse as cursor
    __syncthreads();
    for (int i = s + t; i < e; i += 256) {
        int2 ed = staging[i];
        int pos = atomicAdd(&sc[ed.y & 255], 1);
        col[pos] = ed.x;
    }
}

// ---------------------------------------------------------------------------
// conv weight transposes: Wt[c][k] (bf16, [rows][KP], 0-pad)
// ---------------------------------------------------------------------------
__global__ __launch_bounds__(128) void wt_prep4_kernel(const float* __restrict__ W0,
                                                       const float* __restrict__ W1,
                                                       const float* __restrict__ W2,
                                                       const float* __restrict__ W3,
                                                       unsigned short* __restrict__ T0,
                                                       unsigned short* __restrict__ T1,
                                                       unsigned short* __restrict__ T2,
                                                       unsigned short* __restrict__ T3) {
    const float* W; unsigned short* T; int OCr, Fr, KP, RB;
    switch (blockIdx.y) {
        case 0:  W = W0; T = T0; OCr = 93;  Fr = 93; KP = 96; RB = 96;   break;
        case 1:  W = W1; T = T1; OCr = 930; Fr = 93; KP = 96; RB = 1024; break;
        case 2:  W = W2; T = T2; OCr = 43;  Fr = 43; KP = 64; RB = 48;   break;
        default: W = W3; T = T3; OCr = 430; Fr = 43; KP = 64; RB = 512;  break;
    }
    int c = blockIdx.x, k = threadIdx.x;
    if (c >= RB || k >= KP) return;
    unsigned short v = 0;
    if (c < OCr && k < Fr) v = f2bf(W[(size_t)k * OCr + c]);
    T[(size_t)c * KP + k] = v;
}

// ---------------------------------------------------------------------------
// all 6 MLP weight transpose+splits in one launch (blockIdx.z selects)
// ---------------------------------------------------------------------------
struct WsArgs {
    const float* W[6];
    unsigned short* H[6];
    unsigned short* L[6];
    int K[6];
    int N[6];
    int KP[6];
};

__global__ __launch_bounds__(256) void wsplit_all_kernel(WsArgs a) {
    int z = blockIdx.z;
    int K = a.K[z], N = a.N[z], KP = a.KP[z];
    int k0 = blockIdx.x * 32, c0 = blockIdx.y * 32;
    if (k0 >= KP || c0 >= N) return;
    const float* W = a.W[z];
    unsigned short* Th = a.H[z];
    unsigned short* Tl = a.L[z];
    __shared__ float tile[32][33];
    int tx = threadIdx.x & 31, ty = threadIdx.x >> 5;
    for (int r = ty; r < 32; r += 8) {
        int k = k0 + r;
        tile[r][tx] = (k < K) ? W[(size_t)k * N + c0 + tx] : 0.f;
    }
    __syncthreads();
    for (int r = ty; r < 32; r += 8) {
        int c = c0 + r;
        float v = tile[tx][r];
        unsigned short h, l;
        split_bf(v, h, l);
        Th[(size_t)c * KP + k0 + tx] = h;
        Tl[(size_t)c * KP + k0 + tx] = l;
    }
}

// ---------------------------------------------------------------------------
// fp32 [N][F] -> bf16 [N][KP] (zero-padded) streaming convert
// ---------------------------------------------------------------------------
template<int F, int KP>
__global__ __launch_bounds__(256) void tobf16_kernel(unsigned short* __restrict__ t,
                                                     const float* __restrict__ x, int N) {
    int node = blockIdx.x * blockDim.y + threadIdx.y;
    int f = threadIdx.x;
    if (node >= N) return;
    t[(size_t)node * KP + f] = (f < F) ? f2bf(x[(size_t)node * F + f]) : (unsigned short)0;
}

// ---------------------------------------------------------------------------
// device bodies for the fused pipeline stages
// ---------------------------------------------------------------------------

// gather-aggregate: one wave per node, 16B vector loads, 2 rows in flight.
template<int KP, int CH, int GR>
static __device__ __forceinline__ void gather_dev(int nb, unsigned short* __restrict__ t,
                                                  const unsigned short* __restrict__ x,
                                                  const int* __restrict__ rowptr,
                                                  const int* __restrict__ col, int N) {
    int wave = threadIdx.x >> 6, lane = threadIdx.x & 63;
    int node = nb * 4 + wave;
    if (node >= N) return;
    int g = lane / CH;
    int c = lane - g * CH;
    bool act = (g < GR);
    int s = rowptr[node], e = rowptr[node + 1];
    float acc[8] = {0.f, 0.f, 0.f, 0.f, 0.f, 0.f, 0.f, 0.f};
    int j = act ? (s - 1 + g) : e;
    int src0 = node;
    if (j >= s && j < e) src0 = col[j];
    while (j < e) {
        int jb = j + GR;
        int jc = jb + GR;
        int srcb = (jb < e) ? col[jb] : 0;
        int srcc = (jc < e) ? col[jc] : 0;
        short8 v0 = *(const short8*)(x + (size_t)src0 * KP + c * 8);
#pragma unroll
        for (int i = 0; i < 8; ++i) acc[i] += bf2f((unsigned short)v0[i]);
        if (jb < e) {
            short8 v1 = *(const short8*)(x + (size_t)srcb * KP + c * 8);
#pragma unroll
            for (int i = 0; i < 8; ++i) acc[i] += bf2f((unsigned short)v1[i]);
        }
        j = jc; src0 = srcc;
    }
    if (GR == 8) {
#pragma unroll
        for (int i = 0; i < 8; ++i) {
            float v = acc[i];
            v += __shfl_xor(v, 8);
            v += __shfl_xor(v, 16);
            v += __shfl_xor(v, 32);
            acc[i] = v;
        }
    } else {
#pragma unroll
        for (int i = 0; i < 8; ++i) {
            float v = acc[i];
            float v1 = __shfl(v, lane + CH);
            float v2 = __shfl(v, lane + 2 * CH);
            float v3 = __shfl(v, lane + 3 * CH);
            float v4 = __shfl(v, lane + 4 * CH);
            acc[i] = v + v1 + v2 + v3 + v4;
        }
    }
    if (lane < CH) {
        short8 o;
#pragma unroll
        for (int i = 0; i < 8; ++i) o[i] = (short)f2bf(acc[i]);
        *(short8*)(t + (size_t)node * KP + lane * 8) = o;
    }
}

// conv1 via MFMA: y = relu(t @ W + b), bf16 [N][KP]
template<int KP, int KS, int NT>
static __device__ __forceinline__ void conv1_dev(int nb, const unsigned short* __restrict__ t,
                                                 const unsigned short* __restrict__ Wt,
                                                 const float* __restrict__ bias,
                                                 unsigned short* __restrict__ y,
                                                 int NC, int N) {
    int wave = threadIdx.x >> 6, lane = threadIdx.x & 63;
    int quad = lane >> 4, l15 = lane & 15;
    int r0 = (nb * 4 + wave) * 16;
    const short8 z8 = {0, 0, 0, 0, 0, 0, 0, 0};
    short8 a[KS];
    int arow = r0 + l15;
#pragma unroll
    for (int ks = 0; ks < KS; ++ks)
        a[ks] = (arow < N) ? *(const short8*)(t + (size_t)arow * KP + ks * 32 + quad * 8) : z8;
#pragma unroll
    for (int nt = 0; nt < NT; ++nt) {
        int colb = nt * 16 + l15;
        floatx4 c = {0.f, 0.f, 0.f, 0.f};
#pragma unroll
        for (int ks = 0; ks < KS; ++ks) {
            short8 b = *(const short8*)(Wt + (size_t)colb * KP + ks * 32 + quad * 8);
            c = __builtin_amdgcn_mfma_f32_16x16x32_bf16(a[ks], b, c, 0, 0, 0);
        }
        float bc = (colb < NC) ? bias[colb] : 0.f;
#pragma unroll
        for (int r = 0; r < 4; ++r) {
            int row = r0 + quad * 4 + r;
            if (row < N) {
                float o = fmaxf(c[r] + bc, 0.f);
                y[(size_t)row * KP + colb] = f2bf(o);
            }
        }
    }
}

// conv2 + relu + mean/max pool, epilogue emits hi/lo bf16 pooled rows
template<int KP, int KS>
static __device__ __forceinline__ void conv2_pool_dev(int cb, int g,
                                                      const unsigned short* __restrict__ t,
                                                      const unsigned short* __restrict__ Wt,
                                                      const float* __restrict__ bias,
                                                      const int* __restrict__ starts,
                                                      unsigned short* __restrict__ ph,
                                                      unsigned short* __restrict__ pl,
                                                      int OC, int KPad) {
    int wave = threadIdx.x >> 6, lane = threadIdx.x & 63;
    int quad = lane >> 4, l15 = lane & 15;
    int cw0 = cb * 256 + wave * 64;
    short8 bfr[4][KS];
    float bs[4];
#pragma unroll
    for (int ti = 0; ti < 4; ++ti) {
        int colb = cw0 + ti * 16 + l15;
#pragma unroll
        for (int ks = 0; ks < KS; ++ks)
            bfr[ti][ks] = *(const short8*)(Wt + (size_t)colb * KP + ks * 32 + quad * 8);
        bs[ti] = (colb < OC) ? bias[colb] : 0.f;
    }
    int s = starts[g], e = starts[g + 1];
    float sum[4] = {0.f, 0.f, 0.f, 0.f};
    float mx[4]  = {0.f, 0.f, 0.f, 0.f};
    const short8 z8 = {0, 0, 0, 0, 0, 0, 0, 0};
    for (int ns = s; ns < e; ns += 16) {
        short8 a[KS];
        int arow = ns + l15;
        bool av = arow < e;
#pragma unroll
        for (int ks = 0; ks < KS; ++ks)
            a[ks] = av ? *(const short8*)(t + (size_t)arow * KP + ks * 32 + quad * 8) : z8;
        int rbase = ns + quad * 4;
#pragma unroll
        for (int ti = 0; ti < 4; ++ti) {
            floatx4 c = {0.f, 0.f, 0.f, 0.f};
#pragma unroll
            for (int ks = 0; ks < KS; ++ks)
                c = __builtin_amdgcn_mfma_f32_16x16x32_bf16(a[ks], bfr[ti][ks], c, 0, 0, 0);
#pragma unroll
            for (int r = 0; r < 4; ++r) {
                float o = fmaxf(c[r] + bs[ti], 0.f);
                if (rbase + r < e) {
                    sum[ti] += o;
                    mx[ti] = fmaxf(mx[ti], o);
                }
            }
        }
    }
    int cnt = e - s;
    float rc = 1.f / (float)(cnt > 0 ? cnt : 1);
#pragma unroll
    for (int ti = 0; ti < 4; ++ti) {
        float sv = sum[ti], mv = mx[ti];
        sv += __shfl_down(sv, 32);
        mv = fmaxf(mv, __shfl_down(mv, 32));
        sv += __shfl_down(sv, 16);
        mv = fmaxf(mv, __shfl_down(mv, 16));
        if (lane < 16) {
            int colb = cw0 + ti * 16 + l15;
            if (colb < OC) {
                size_t base = (size_t)g * (size_t)KPad;
                unsigned short h, l;
                split_bf(sv * rc, h, l);
                ph[base + colb] = h; pl[base + colb] = l;
                split_bf(mv, h, l);
                ph[base + OC + colb] = h; pl[base + OC + colb] = l;
            }
        }
    }
}

// split-bf16 ("bf16x3") MFMA GEMM tile: C = A @ B^T(+bias), fp32-equivalent.
// MODE 0: relu, write hi/lo bf16.  MODE 1: fp32.  MODE 2: relu, fp32.
template<int MODE>
static __device__ __forceinline__ void gemm3x_dev(int bx, int by, int NBX,
                                                  const unsigned short* __restrict__ Ah,
                                                  const unsigned short* __restrict__ Al,
                                                  const unsigned short* __restrict__ Bh,
                                                  const unsigned short* __restrict__ Bl,
                                                  const float* __restrict__ bias,
                                                  float* __restrict__ Cf,
                                                  unsigned short* __restrict__ Ch,
                                                  unsigned short* __restrict__ Cl,
                                                  int KP) {
    int wave = threadIdx.x >> 6, lane = threadIdx.x & 63;
    int quad = lane >> 4, l15 = lane & 15;
    int r0 = by * 32 + (wave & 1) * 16;
    int c0 = bx * 64 + (wave >> 1) * 32;
    int Ncols = NBX * 64;
    floatx4 acc0 = {0.f, 0.f, 0.f, 0.f};
    floatx4 acc1 = {0.f, 0.f, 0.f, 0.f};
    const unsigned short* arh = Ah + (size_t)(r0 + l15) * KP;
    const unsigned short* arl = Al + (size_t)(r0 + l15) * KP;
    const unsigned short* b0h = Bh + (size_t)(c0 + l15) * KP;
    const unsigned short* b0l = Bl + (size_t)(c0 + l15) * KP;
    const unsigned short* b1h = Bh + (size_t)(c0 + 16 + l15) * KP;
    const unsigned short* b1l = Bl + (size_t)(c0 + 16 + l15) * KP;
    for (int k0 = 0; k0 < KP; k0 += 128) {
        short8 ah[4], al[4];
#pragma unroll
        for (int q = 0; q < 4; ++q) {
            ah[q] = *(const short8*)(arh + k0 + q * 32 + quad * 8);
            al[q] = *(const short8*)(arl + k0 + q * 32 + quad * 8);
        }
#pragma unroll
        for (int q = 0; q < 4; ++q) {
            short8 bh = *(const short8*)(b0h + k0 + q * 32 + quad * 8);
            short8 bl = *(const short8*)(b0l + k0 + q * 32 + quad * 8);
            acc0 = __builtin_amdgcn_mfma_f32_16x16x32_bf16(ah[q], bh, acc0, 0, 0, 0);
            acc0 = __builtin_amdgcn_mfma_f32_16x16x32_bf16(al[q], bh, acc0, 0, 0, 0);
            acc0 = __builtin_amdgcn_mfma_f32_16x16x32_bf16(ah[q], bl, acc0, 0, 0, 0);
            bh = *(const short8*)(b1h + k0 + q * 32 + quad * 8);
            bl = *(const short8*)(b1l + k0 + q * 32 + quad * 8);
            acc1 = __builtin_amdgcn_mfma_f32_16x16x32_bf16(ah[q], bh, acc1, 0, 0, 0);
            acc1 = __builtin_amdgcn_mfma_f32_16x16x32_bf16(al[q], bh, acc1, 0, 0, 0);
            acc1 = __builtin_amdgcn_mfma_f32_16x16x32_bf16(ah[q], bl, acc1, 0, 0, 0);
        }
    }
    int col0 = c0 + l15, col1 = c0 + 16 + l15;
    float bc0 = bias[col0], bc1 = bias[col1];
#pragma unroll
    for (int r = 0; r < 4; ++r) {
        int row = r0 + quad * 4 + r;
        float v0 = acc0[r] + bc0;
        float v1 = acc1[r] + bc1;
        if (MODE != 1) { v0 = fmaxf(v0, 0.f); v1 = fmaxf(v1, 0.f); }
        if (MODE == 0) {
            unsigned short h, l;
            split_bf(v0, h, l);
            Ch[(size_t)row * Ncols + col0] = h; Cl[(size_t)row * Ncols + col0] = l;
            split_bf(v1, h, l);
            Ch[(size_t)row * Ncols + col1] = h; Cl[(size_t)row * Ncols + col1] = l;
        } else {
            Cf[(size_t)row * Ncols + col0] = v0;
            Cf[(size_t)row * Ncols + col1] = v1;
        }
    }
}

// fused batchnorm (stats + apply, one block per column; 512 rows, 512 cols)
static __device__ __forceinline__ void bn_dev(int c, const float* __restrict__ p,
                                              const float* __restrict__ gamma,
                                              const float* __restrict__ beta,
                                              float* __restrict__ outp,
                                              unsigned short* __restrict__ oh,
                                              unsigned short* __restrict__ ol) {
    __shared__ float ls[256], ls2[256];
    int t = threadIdx.x;
    float v0 = p[(size_t)t * 512 + c];
    float v1 = p[(size_t)(t + 256) * 512 + c];
    ls[t] = v0 + v1;
    ls2[t] = v0 * v0 + v1 * v1;
    __syncthreads();
    for (int st = 128; st > 0; st >>= 1) {
        if (t < st) { ls[t] += ls[t + st]; ls2[t] += ls2[t + st]; }
        __syncthreads();
    }
    if (t == 0) {
        float m = ls[0] / 512.f;
        float var = ls2[0] / 512.f - m * m;
        ls[0] = m;
        ls2[0] = 1.f / sqrtf(var + BN_EPS);
    }
    __syncthreads();
    float m = ls[0], iv = ls2[0];
    float g = gamma[c], b = beta[c];
    float w0 = g * (v0 - m) * iv + b;
    float w1 = g * (v1 - m) * iv + b;
    outp[(size_t)t * 512 + c] = w0;
    outp[(size_t)(t + 256) * 512 + c] = w1;
    unsigned short h, l;
    split_bf(w0, h, l);
    oh[(size_t)t * 512 + c] = h; ol[(size_t)t * 512 + c] = l;
    split_bf(w1, h, l);
    oh[(size_t)(t + 256) * 512 + c] = h; ol[(size_t)(t + 256) * 512 + c] = l;
}

// head2: z[row][0..1] = h[row][0..255] @ w2[256][2] + b2. Wave per row.
static __device__ __forceinline__ void head2_dev(int nb, const float* __restrict__ h,
                                                 const float* __restrict__ w2,
                                                 const float* __restrict__ b2,
                                                 float* __restrict__ z, int M) {
    int wave = threadIdx.x >> 6, lane = threadIdx.x & 63;
    int row = nb * 4 + wave;
    if (row >= M) return;
    float4 hv = *(const float4*)(h + (size_t)row * 256 + lane * 4);
    const float* wp = w2 + lane * 8;
    float s0 = hv.x * wp[0] + hv.y * wp[2] + hv.z * wp[4] + hv.w * wp[6];
    float s1 = hv.x * wp[1] + hv.y * wp[3] + hv.z * wp[5] + hv.w * wp[7];
#pragma unroll
    for (int offd = 32; offd >= 1; offd >>= 1) {
        s0 += __shfl_down(s0, offd);
        s1 += __shfl_down(s1, offd);
    }
    if (lane == 0) {
        z[(size_t)row * 2 + 0] = s0 + b2[0];
        z[(size_t)row * 2 + 1] = s1 + b2[1];
    }
}

// ---------------------------------------------------------------------------
// standalone wrappers
// ---------------------------------------------------------------------------
template<int KP, int CH, int GR>
__global__ __launch_bounds__(256) void gather_wave_kernel(unsigned short* __restrict__ t,
                                                          const unsigned short* __restrict__ x,
                                                          const int* __restrict__ rowptr,
                                                          const int* __restrict__ col, int N) {
    gather_dev<KP, CH, GR>(blockIdx.x, t, x, rowptr, col, N);
}

__global__ __launch_bounds__(256) void head2_kernel(const float* __restrict__ h,
                                                    const float* __restrict__ w2,
                                                    const float* __restrict__ b2,
                                                    float* __restrict__ z, int M) {
    head2_dev(blockIdx.x, h, w2, b2, z, M);
}

// ---------------------------------------------------------------------------
// fused cross-branch stage kernels (block-range dispatch: memory-bound gather
// blocks co-scheduled with MFMA-bound conv/gemm blocks on the same CUs)
// ---------------------------------------------------------------------------
__global__ __launch_bounds__(256) void f2_kernel(   // conv1(b0) + gather-x(b1)
        const unsigned short* tb, const unsigned short* wt_a0, const float* b_c1,
        unsigned short* yb,
        unsigned short* t1, const unsigned short* xb1,
        const int* rowptr1, const int* col1) {
    int bid = blockIdx.x;
    if (bid < 1563)
        conv1_dev<96, 3, 6>(bid, tb, wt_a0, b_c1, yb, 93, N0);
    else
        gather_dev<64, 8, 8>(bid - 1563, t1, xb1, rowptr1, col1, N1);
}

__global__ __launch_bounds__(256) void f3_kernel(   // gather-y(b0) + conv1(b1)
        unsigned short* tb, const unsigned short* yb,
        const int* rowptr0, const int* col0,
        const unsigned short* t1, const unsigned short* wt_a1, const float* b_c3,
        unsigned short* y1) {
    int bid = blockIdx.x;
    if (bid < 25000)
        gather_dev<96, 12, 5>(bid, tb, yb, rowptr0, col0, N0);
    else
        conv1_dev<64, 2, 3>(bid - 25000, t1, wt_a1, b_c3, y1, 43, N1);
}

__global__ __launch_bounds__(256) void f4_kernel(   // conv2_pool(b0) + gather-y(b1)
        const unsigned short* tb, const unsigned short* wt_b0, const float* b_c2,
        const int* starts0, unsigned short* p0h, unsigned short* p0l,
        unsigned short* t1, const unsigned short* y1,
        const int* rowptr1, const int* col1) {
    int bid = blockIdx.x;
    if (bid < 2048)
        conv2_pool_dev<96, 3>(bid & 3, bid >> 2, tb, wt_b0, b_c2, starts0, p0h, p0l, OC0, 1920);
    else
        gather_dev<64, 8, 8>(bid - 2048, t1, y1, rowptr1, col1, N1);
}

__global__ __launch_bounds__(256) void f5_kernel(   // gemm1(b0) + conv2_pool(b1)
        const unsigned short* p0h, const unsigned short* p0l,
        const unsigned short* bt1h0, const unsigned short* bt1l0, const float* g0_b1,
        unsigned short* m1h0, unsigned short* m1l0,
        const unsigned short* t1, const unsigned short* wt_b1, const float* b_c4,
        const int* starts1, unsigned short* p1h, unsigned short* p1l) {
    int bid = blockIdx.x;
    if (bid < 256)
        gemm3x_dev<0>(bid & 15, bid >> 4, 16, p0h, p0l, bt1h0, bt1l0, g0_b1,
                      nullptr, m1h0, m1l0, 1920);
    else {
        int b = bid - 256;
        conv2_pool_dev<64, 2>(b & 1, b >> 1, t1, wt_b1, b_c4, starts1, p1h, p1l, OC1, 896);
    }
}

__global__ __launch_bounds__(256) void f6_kernel(   // gemm2(b0) + gemm1(b1)
        const unsigned short* m1h0, const unsigned short* m1l0,
        const unsigned short* bt2h0, const unsigned short* bt2l0, const float* g0_b2,
        float* pbn0,
        const unsigned short* p1h, const unsigned short* p1l,
        const unsigned short* bt1h1, const unsigned short* bt1l1, const float* g1_b1,
        unsigned short* m1h1, unsigned short* m1l1) {
    int bid = blockIdx.x;
    if (bid < 128)
        gemm3x_dev<1>(bid & 7, bid >> 3, 8, m1h0, m1l0, bt2h0, bt2l0, g0_b2,
                      pbn0, nullptr, nullptr, 1024);
    else {
        int b = bid - 128;
        gemm3x_dev<0>(b & 15, b >> 4, 16, p1h, p1l, bt1h1, bt1l1, g1_b1,
                      nullptr, m1h1, m1l1, 896);
    }
}

__global__ __launch_bounds__(256) void f7_kernel(   // bn(b0) + gemm2(b1)
        const float* pbn0, const float* g0_bn_g, const float* g0_bn_b,
        float* out_xg0, unsigned short* xgh0, unsigned short* xgl0,
        const unsigned short* m1h1, const unsigned short* m1l1,
        const unsigned short* bt2h1, const unsigned short* bt2l1, const float* g1_b2,
        float* pbn1) {
    int bid = blockIdx.x;
    if (bid < 512)
        bn_dev(bid, pbn0, g0_bn_g, g0_bn_b, out_xg0, xgh0, xgl0);
    else {
        int b = bid - 512;
        gemm3x_dev<1>(b & 7, b >> 3, 8, m1h1, m1l1, bt2h1, bt2l1, g1_b2,
                      pbn1, nullptr, nullptr, 1024);
    }
}

__global__ __launch_bounds__(256) void f8_kernel(   // gemmH(b0) + bn(b1)
        const unsigned short* xgh0, const unsigned short* xgl0,
        const unsigned short* bt3h0, const unsigned short* bt3l0, const float* f0_b1,
        float* hbuf0,
        const float* pbn1, const float* g1_bn_g, const float* g1_bn_b,
        float* out_xg1, unsigned short* xgh1, unsigned short* xgl1) {
    int bid = blockIdx.x;
    if (bid < 64)
        gemm3x_dev<2>(bid & 3, bid >> 2, 4, xgh0, xgl0, bt3h0, bt3l0, f0_b1,
                      hbuf0, nullptr, nullptr, 512);
    else
        bn_dev(bid - 64, pbn1, g1_bn_g, g1_bn_b, out_xg1, xgh1, xgl1);
}

__global__ __launch_bounds__(256) void f9_kernel(   // head2(b0) + gemmH(b1)
        const float* hbuf0, const float* f0_w2, const float* f0_b2, float* out_z,
        const unsigned short* xgh1, const unsigned short* xgl1,
        const unsigned short* bt3h1, const unsigned short* bt3l1, const float* f1_b1,
        float* hbuf1) {
    int bid = blockIdx.x;
    if (bid < 128)
        head2_dev(bid, hbuf0, f0_w2, f0_b2, out_z, GCONST);
    else {
        int b = bid - 128;
        gemm3x_dev<2>(b & 3, b >> 2, 4, xgh1, xgl1, bt3h1, bt3l1, f1_b1,
                      hbuf1, nullptr, nullptr, 512);
    }
}

// ---------------------------------------------------------------------------
// launch
// ---------------------------------------------------------------------------
static inline int ceildiv(int a, int b) { return (a + b - 1) / b; }

extern "C" void kernel_launch(void* const* d_in, const int* in_sizes, int n_in,
                              void* d_out, int out_size, void* d_ws, size_t ws_size,
                              hipStream_t stream) {
    const float* x0   = (const float*)d_in[0];
    const float* x1   = (const float*)d_in[1];
    const int*   ei0  = (const int*)d_in[2];
    const int*   ei1  = (const int*)d_in[3];
    const int*   bat0 = (const int*)d_in[4];
    const int*   bat1 = (const int*)d_in[5];
    const float* w_c1 = (const float*)d_in[6];
    const float* b_c1 = (const float*)d_in[7];
    const float* w_c2 = (const float*)d_in[8];
    const float* b_c2 = (const float*)d_in[9];
    const float* w_c3 = (const float*)d_in[10];
    const float* b_c3 = (const float*)d_in[11];
    const float* w_c4 = (const float*)d_in[12];
    const float* b_c4 = (const float*)d_in[13];
    const float* g0_w1 = (const float*)d_in[14];
    const float* g0_b1 = (const float*)d_in[15];
    const float* g0_w2 = (const float*)d_in[16];
    const float* g0_b2 = (const float*)d_in[17];
    const float* g0_bn_g = (const float*)d_in[18];
    const float* g0_bn_b = (const float*)d_in[19];
    const float* g1_w1 = (const float*)d_in[20];
    const float* g1_b1 = (const float*)d_in[21];
    const float* g1_w2 = (const float*)d_in[22];
    const float* g1_b2 = (const float*)d_in[23];
    const float* g1_bn_g = (const float*)d_in[24];
    const float* g1_bn_b = (const float*)d_in[25];
    const float* f0_w1 = (const float*)d_in[26];
    const float* f0_b1 = (const float*)d_in[27];
    const float* f0_w2 = (const float*)d_in[28];
    const float* f0_b2 = (const float*)d_in[29];
    const float* f1_w1 = (const float*)d_in[30];
    const float* f1_b1 = (const float*)d_in[31];
    const float* f1_w2 = (const float*)d_in[32];
    const float* f1_b2 = (const float*)d_in[33];

    float* out = (float*)d_out;
    float* out_z   = out;
    float* out_xg0 = out + 1024;
    float* out_xg1 = out + 1024 + 262144;
    float* out_z1  = out + 1024 + 262144 + 262144;

    // workspace carve (floats; all offsets multiples of 4 -> 16B aligned)
    float* ws = (float*)d_ws;
    size_t off = 0;
    auto alloc = [&](size_t n) { float* p = ws + off; off += n; return p; };
    unsigned short* xb0 = (unsigned short*)alloc((size_t)N0 * 96 / 2); // x0 bf16; later t1 (b1 gather out)
    unsigned short* xb1 = (unsigned short*)alloc((size_t)N1 * 64 / 2); // x1 bf16; later y1 (b1 conv1 out)
    unsigned short* tb  = (unsigned short*)alloc((size_t)N0 * 96 / 2); // staging0 overlay; b0 gather out
    unsigned short* yb  = (unsigned short*)alloc((size_t)N0 * 96 / 2); // staging1 overlay; b0 conv1 out
    unsigned short* wt_a0 = (unsigned short*)alloc(96 * 96 / 2);
    unsigned short* wt_b0 = (unsigned short*)alloc(1024 * 96 / 2);
    unsigned short* wt_a1 = (unsigned short*)alloc(48 * 64 / 2);
    unsigned short* wt_b1 = (unsigned short*)alloc(512 * 64 / 2);
    // MLP hi/lo weights, per branch
    unsigned short* bt1h0 = (unsigned short*)alloc((size_t)1024 * 1920 / 2);
    unsigned short* bt1l0 = (unsigned short*)alloc((size_t)1024 * 1920 / 2);
    unsigned short* bt2h0 = (unsigned short*)alloc((size_t)512 * 1024 / 2);
    unsigned short* bt2l0 = (unsigned short*)alloc((size_t)512 * 1024 / 2);
    unsigned short* bt3h0 = (unsigned short*)alloc((size_t)256 * 512 / 2);
    unsigned short* bt3l0 = (unsigned short*)alloc((size_t)256 * 512 / 2);
    unsigned short* bt1h1 = (unsigned short*)alloc((size_t)1024 * 896 / 2);
    unsigned short* bt1l1 = (unsigned short*)alloc((size_t)1024 * 896 / 2);
    unsigned short* bt2h1 = (unsigned short*)alloc((size_t)512 * 1024 / 2);
    unsigned short* bt2l1 = (unsigned short*)alloc((size_t)512 * 1024 / 2);
    unsigned short* bt3h1 = (unsigned short*)alloc((size_t)256 * 512 / 2);
    unsigned short* bt3l1 = (unsigned short*)alloc((size_t)256 * 512 / 2);
    // activations, per branch
    unsigned short* m1h0 = (unsigned short*)alloc((size_t)512 * 1024 / 2);
    unsigned short* m1l0 = (unsigned short*)alloc((size_t)512 * 1024 / 2);
    unsigned short* m1h1 = (unsigned short*)alloc((size_t)512 * 1024 / 2);
    unsigned short* m1l1 = (unsigned short*)alloc((size_t)512 * 1024 / 2);
    unsigned short* xgh0 = (unsigned short*)alloc((size_t)512 * 512 / 2);
    unsigned short* xgl0 = (unsigned short*)alloc((size_t)512 * 512 / 2);
    unsigned short* xgh1 = (unsigned short*)alloc((size_t)512 * 512 / 2);
    unsigned short* xgl1 = (unsigned short*)alloc((size_t)512 * 512 / 2);
    unsigned short* p0h = (unsigned short*)alloc((size_t)512 * 1920 / 2);
    unsigned short* p0l = (unsigned short*)alloc((size_t)512 * 1920 / 2);
    unsigned short* p1h = (unsigned short*)alloc((size_t)512 * 896 / 2);
    unsigned short* p1l = (unsigned short*)alloc((size_t)512 * 896 / 2);
    float* pbn0  = alloc((size_t)512 * 512);
    float* pbn1  = alloc((size_t)512 * 512);
    float* hbuf0 = alloc((size_t)512 * 256);
    float* hbuf1 = alloc((size_t)512 * 256);
    // CSR
    int* btot2  = (int*)alloc(1024);
    int* bbase2 = (int*)alloc(1024);
    int* bcur2  = (int*)alloc(1024);
    int* rowptr0 = (int*)alloc(100016);
    int* col0    = (int*)alloc(E0C);
    int* rowptr1 = (int*)alloc(100016);
    int* col1    = (int*)alloc(E1C);
    int* starts0 = (int*)alloc(520);
    int* starts1 = (int*)alloc(520);
    // staging overlays (dead after csr_build; tb/yb not yet written then)
    int2* staging0 = (int2*)tb;
    int2* staging1 = (int2*)yb;
    // branch1 intermediate overlays (xb0/xb1 dead after their gather-x reads)
    unsigned short* t1 = xb0;
    unsigned short* y1 = xb1;

    const int G = GCONST;
    const int EB = ceildiv(E0C, 2048);   // 782

    // ------------------------------ prologue ------------------------------
    find_starts2_kernel<<<dim3(3, 2), 256, 0, stream>>>(bat0, bat1, N0, G, starts0, starts1);
    wt_prep4_kernel<<<dim3(1024, 4), 128, 0, stream>>>(w_c1, w_c2, w_c3, w_c4,
                                                       wt_a0, wt_b0, wt_a1, wt_b1);
    {
        WsArgs a;
        a.W[0] = g0_w1; a.H[0] = bt1h0; a.L[0] = bt1l0; a.K[0] = 1860; a.N[0] = 1024; a.KP[0] = 1920;
        a.W[1] = g0_w2; a.H[1] = bt2h0; a.L[1] = bt2l0; a.K[1] = 1024; a.N[1] = 512;  a.KP[1] = 1024;
        a.W[2] = f0_w1; a.H[2] = bt3h0; a.L[2] = bt3l0; a.K[2] = 512;  a.N[2] = 256;  a.KP[2] = 512;
        a.W[3] = g1_w1; a.H[3] = bt1h1; a.L[3] = bt1l1; a.K[3] = 860;  a.N[3] = 1024; a.KP[3] = 896;
        a.W[4] = g1_w2; a.H[4] = bt2h1; a.L[4] = bt2l1; a.K[4] = 1024; a.N[4] = 512;  a.KP[4] = 1024;
        a.W[5] = f1_w1; a.H[5] = bt3h1; a.L[5] = bt3l1; a.K[5] = 512;  a.N[5] = 256;  a.KP[5] = 512;
        wsplit_all_kernel<<<dim3(60, 32, 6), 256, 0, stream>>>(a);
    }
    zero_pad_kernel<<<ceildiv(G * (1920 - 2 * OC0), 256), 256, 0, stream>>>(p0h, p0l, 1920, 2 * OC0);
    zero_pad_kernel<<<ceildiv(G * (896 - 2 * OC1), 256), 256, 0, stream>>>(p1h, p1l, 896, 2 * OC1);
    zero_int_kernel<<<4, 256, 0, stream>>>(btot2, 1024);
    bucket_count2_kernel<<<dim3(EB, 2), 256, 0, stream>>>(ei0, ei1, E0C, btot2);
    bucket_scan2_kernel<<<2, 512, 0, stream>>>(btot2, bbase2, bcur2);
    edge_bucket2_kernel<<<dim3(EB, 2), 256, 0, stream>>>(ei0, ei1, E0C, bcur2, staging0, staging1);
    csr_build2_kernel<<<dim3(NBKT, 2), 256, 0, stream>>>(staging0, staging1, bbase2, N0,
                                                         rowptr0, rowptr1, col0, col1);
    tobf16_kernel<93, 96><<<ceildiv(N0, 2), dim3(96, 2), 0, stream>>>(xb0, x0, N0);
    tobf16_kernel<43, 64><<<ceildiv(N1, 4), dim3(64, 4), 0, stream>>>(xb1, x1, N1);

    // ------------------- pipelined cross-branch schedule -------------------
    gather_wave_kernel<96, 12, 5><<<25000, 256, 0, stream>>>(tb, xb0, rowptr0, col0, N0);
    f2_kernel<<<1563 + 25000, 256, 0, stream>>>(tb, wt_a0, b_c1, yb,
                                                t1, xb1, rowptr1, col1);
    f3_kernel<<<25000 + 1563, 256, 0, stream>>>(tb, yb, rowptr0, col0,
                                                t1, wt_a1, b_c3, y1);
    f4_kernel<<<2048 + 25000, 256, 0, stream>>>(tb, wt_b0, b_c2, starts0, p0h, p0l,
                                                t1, y1, rowptr1, col1);
    f5_kernel<<<256 + 1024, 256, 0, stream>>>(p0h, p0l, bt1h0, bt1l0, g0_b1, m1h0, m1l0,
                                              t1, wt_b1, b_c4, starts1, p1h, p1l);
    f6_kernel<<<128 + 256, 256, 0, stream>>>(m1h0, m1l0, bt2h0, bt2l0, g0_b2, pbn0,
                                             p1h, p1l, bt1h1, bt1l1, g1_b1, m1h1, m1l1);
    f7_kernel<<<512 + 128, 256, 0, stream>>>(pbn0, g0_bn_g, g0_bn_b, out_xg0, xgh0, xgl0,
                                             m1h1, m1l1, bt2h1, bt2l1, g1_b2, pbn1);
    f8_kernel<<<64 + 512, 256, 0, stream>>>(xgh0, xgl0, bt3h0, bt3l0, f0_b1, hbuf0,
                                            pbn1, g1_bn_g, g1_bn_b, out_xg1, xgh1, xgl1);
    f9_kernel<<<128 + 64, 256, 0, stream>>>(hbuf0, f0_w2, f0_b2, out_z,
                                            xgh1, xgl1, bt3h1, bt3l1, f1_b1, hbuf1);
    head2_kernel<<<G / 4, 256, 0, stream>>>(hbuf1, f1_w2, f1_b2, out_z1, G);
}

// Round 5
// 730.716 us; speedup vs baseline: 1.4681x; 1.0108x over previous
//
#include <hip/hip_runtime.h>
#include <hip/hip_bf16.h>

// ---------------------------------------------------------------------------
// Problem constants
// ---------------------------------------------------------------------------
#define N0 100000
#define E0C 1600000
#define N1 100000
#define E1C 1600000
#define GCONST 512
#define F0C 93
#define F1C 43
#define OC0 (F0C * 10)   // 930
#define OC1 (F1C * 10)   // 430
#define BN_EPS 1e-5f
#define NBKT 391         // ceil(100000 / 256) buckets for CSR fill

typedef __attribute__((ext_vector_type(8))) short short8;
typedef __attribute__((ext_vector_type(4))) float floatx4;

static __device__ __forceinline__ unsigned short f2bf(float f) {
    unsigned u = __float_as_uint(f);
    unsigned r = (u + 0x7FFF + ((u >> 16) & 1)) >> 16;   // RNE
    return (unsigned short)r;
}
static __device__ __forceinline__ float bf2f(unsigned short u) {
    return __uint_as_float(((unsigned)u) << 16);
}
static __device__ __forceinline__ void split_bf(float v, unsigned short& h, unsigned short& l) {
    h = f2bf(v);
    l = f2bf(v - bf2f(h));
}

// ---------------------------------------------------------------------------
// CSR build kernels (both branches per launch via blockIdx.y)
// ---------------------------------------------------------------------------
__global__ __launch_bounds__(256) void bucket_count2_kernel(const int* __restrict__ ei0,
                                                            const int* __restrict__ ei1,
                                                            int E, int* __restrict__ btot2) {
    const int* ei = blockIdx.y ? ei1 : ei0;
    int* btot = btot2 + blockIdx.y * 512;
    __shared__ int h[NBKT];
    int t = threadIdx.x;
    for (int i = t; i < NBKT; i += 256) h[i] = 0;
    __syncthreads();
    int base = blockIdx.x * 2048;
#pragma unroll
    for (int i = 0; i < 8; ++i) {
        int e = base + i * 256 + t;
        if (e < E) atomicAdd(&h[ei[E + e] >> 8], 1);
    }
    __syncthreads();
    for (int i = t; i < NBKT; i += 256) {
        int c = h[i];
        if (c) atomicAdd(&btot[i], c);
    }
}

__global__ __launch_bounds__(512) void bucket_scan2_kernel(const int* __restrict__ btot2,
                                                           int* __restrict__ bbase2,
                                                           int* __restrict__ bcur2) {
    const int* btot = btot2 + blockIdx.x * 512;
    int* bbase = bbase2 + blockIdx.x * 512;
    int* bcur  = bcur2 + blockIdx.x * 512;
    __shared__ int sh[512];
    int t = threadIdx.x;
    int v = (t < NBKT) ? btot[t] : 0;
    sh[t] = v;
    __syncthreads();
    for (int o = 1; o < 512; o <<= 1) {
        int add = (t >= o) ? sh[t - o] : 0;
        __syncthreads();
        sh[t] += add;
        __syncthreads();
    }
    if (t < NBKT) {
        int ex = sh[t] - v;
        bbase[t] = ex;
        bcur[t] = ex;
    }
    if (t == NBKT) bbase[t] = sh[NBKT - 1];   // total == E
}

__global__ __launch_bounds__(256) void edge_bucket2_kernel(const int* __restrict__ ei0,
                                                           const int* __restrict__ ei1,
                                                           int E, int* __restrict__ bcur2,
                                                           int2* __restrict__ st0,
                                                           int2* __restrict__ st1) {
    const int* ei = blockIdx.y ? ei1 : ei0;
    int* bcur = bcur2 + blockIdx.y * 512;
    int2* staging = blockIdx.y ? st1 : st0;
    __shared__ int hist[NBKT];
    __shared__ int gbase[NBKT];
    int t = threadIdx.x;
    for (int i = t; i < NBKT; i += 256) hist[i] = 0;
    __syncthreads();
    int base = blockIdx.x * 2048;
    int srcv[8], dstv[8];
#pragma unroll
    for (int i = 0; i < 8; ++i) {
        int e = base + i * 256 + t;
        if (e < E) { srcv[i] = ei[e]; dstv[i] = ei[E + e]; }
        else dstv[i] = -1;
    }
#pragma unroll
    for (int i = 0; i < 8; ++i)
        if (dstv[i] >= 0) atomicAdd(&hist[dstv[i] >> 8], 1);
    __syncthreads();
    for (int i = t; i < NBKT; i += 256) {
        int c = hist[i];
        gbase[i] = c ? atomicAdd(&bcur[i], c) : 0;
        hist[i] = 0;   // reuse as local cursor
    }
    __syncthreads();
#pragma unroll
    for (int i = 0; i < 8; ++i) {
        if (dstv[i] >= 0) {
            int b = dstv[i] >> 8;
            int lofs = atomicAdd(&hist[b], 1);
            staging[gbase[b] + lofs] = make_int2(srcv[i], dstv[i]);
        }
    }
}

// per-bucket fused {LDS histogram -> scan -> rowptr -> col scatter}
static __device__ __forceinline__ void csr_build_dev(int b, const int2* __restrict__ staging,
                                                     const int* __restrict__ bbase, int N,
                                                     int* __restrict__ rowptr,
                                                     int* __restrict__ col) {
    __shared__ int h[256];
    __shared__ int sc[256];
    int t = threadIdx.x;
    int s = bbase[b], e = bbase[b + 1];
    h[t] = 0;
    __syncthreads();
    for (int i = s + t; i < e; i += 256)
        atomicAdd(&h[staging[i].y & 255], 1);
    __syncthreads();
    int v = h[t];
    sc[t] = v;
    __syncthreads();
    for (int o = 1; o < 256; o <<= 1) {
        int add = (t >= o) ? sc[t - o] : 0;
        __syncthreads();
        sc[t] += add;
        __syncthreads();
    }
    int ex = s + (sc[t] - v);
    int node = (b << 8) + t;
    if (node <= N) rowptr[node] = ex;
    __syncthreads();
    sc[t] = ex;                          // reuse as cursor
    __syncthreads();
    for (int i = s + t; i < e; i += 256) {
        int2 ed = staging[i];
        int pos = atomicAdd(&sc[ed.y & 255], 1);
        col[pos] = ed.x;
    }
}

// ---------------------------------------------------------------------------
// misc prologue kernel: find_starts + conv-weight preps + zeroing
//   [0,6)          find_starts (2 branches x 3 parts)
//   [6,2054)       wt_prep (4 cfgs x 512 blocks, 2 cols/block)
//   [2054,2058)    zero btot2 (1024 ints)
//   [2058,2178)    zero-pad p0 cols [1860,1920)
//   [2178,2250)    zero-pad p1 cols [860,896)
// ---------------------------------------------------------------------------
__global__ __launch_bounds__(256) void misc_kernel(const int* __restrict__ bat0,
                                                   const int* __restrict__ bat1,
                                                   int* __restrict__ st0,
                                                   int* __restrict__ st1,
                                                   const float* __restrict__ Wc1,
                                                   const float* __restrict__ Wc2,
                                                   const float* __restrict__ Wc3,
                                                   const float* __restrict__ Wc4,
                                                   unsigned short* __restrict__ Ta0,
                                                   unsigned short* __restrict__ Tb0,
                                                   unsigned short* __restrict__ Ta1,
                                                   unsigned short* __restrict__ Tb1,
                                                   int* __restrict__ btot2,
                                                   unsigned short* __restrict__ p0h,
                                                   unsigned short* __restrict__ p0l,
                                                   unsigned short* __restrict__ p1h,
                                                   unsigned short* __restrict__ p1l) {
    int bid = blockIdx.x;
    int t = threadIdx.x;
    if (bid < 6) {
        int branch = bid / 3;
        const int* batch = branch ? bat1 : bat0;
        int* starts = branch ? st1 : st0;
        int g = (bid % 3) * 256 + t;
        if (g > GCONST) return;
        if (g == GCONST) { starts[GCONST] = N0; return; }
        int lo = 0, hi = N0;
        while (lo < hi) {
            int mid = (lo + hi) >> 1;
            if (batch[mid] < g) lo = mid + 1; else hi = mid;
        }
        starts[g] = lo;
    } else if (bid < 2054) {
        int idx = bid - 6;
        int cfg = idx >> 9;
        int c = (idx & 511) * 2 + (t >> 7);
        int k = t & 127;
        const float* W; unsigned short* T; int OCr, Fr, KP, RB;
        switch (cfg) {
            case 0:  W = Wc1; T = Ta0; OCr = 93;  Fr = 93; KP = 96; RB = 96;   break;
            case 1:  W = Wc2; T = Tb0; OCr = 930; Fr = 93; KP = 96; RB = 1024; break;
            case 2:  W = Wc3; T = Ta1; OCr = 43;  Fr = 43; KP = 64; RB = 48;   break;
            default: W = Wc4; T = Tb1; OCr = 430; Fr = 43; KP = 64; RB = 512;  break;
        }
        if (c >= RB || k >= KP) return;
        unsigned short v = 0;
        if (c < OCr && k < Fr) v = f2bf(W[(size_t)k * OCr + c]);
        T[(size_t)c * KP + k] = v;
    } else if (bid < 2058) {
        int i = (bid - 2054) * 256 + t;
        if (i < 1024) btot2[i] = 0;
    } else if (bid < 2178) {
        int i = (bid - 2058) * 256 + t;
        if (i >= GCONST * 60) return;
        int g = i / 60, c = 1860 + (i - g * 60);
        p0h[(size_t)g * 1920 + c] = 0;
        p0l[(size_t)g * 1920 + c] = 0;
    } else {
        int i = (bid - 2178) * 256 + t;
        if (i >= GCONST * 36) return;
        int g = i / 36, c = 860 + (i - g * 36);
        p1h[(size_t)g * 896 + c] = 0;
        p1l[(size_t)g * 896 + c] = 0;
    }
}

// ---------------------------------------------------------------------------
// MLP weight transpose + hi/lo bf16 split (device body; fused into f1)
// ---------------------------------------------------------------------------
static __device__ __forceinline__ void wsplit_dev(int k0, int c0,
                                                  const float* __restrict__ W,
                                                  unsigned short* __restrict__ Th,
                                                  unsigned short* __restrict__ Tl,
                                                  int K, int N, int KP) {
    __shared__ float tile[32][33];
    int tx = threadIdx.x & 31, ty = threadIdx.x >> 5;
    for (int r = ty; r < 32; r += 8) {
        int k = k0 + r;
        tile[r][tx] = (k < K) ? W[(size_t)k * N + c0 + tx] : 0.f;
    }
    __syncthreads();
    for (int r = ty; r < 32; r += 8) {
        int c = c0 + r;
        float v = tile[tx][r];
        unsigned short h, l;
        split_bf(v, h, l);
        Th[(size_t)c * KP + k0 + tx] = h;
        Tl[(size_t)c * KP + k0 + tx] = l;
    }
}

// ---------------------------------------------------------------------------
// device bodies for the fused pipeline stages
// ---------------------------------------------------------------------------

// gather-aggregate: one wave per node, 16B vector loads, 2 rows in flight.
template<int KP, int CH, int GR>
static __device__ __forceinline__ void gather_dev(int nb, unsigned short* __restrict__ t,
                                                  const unsigned short* __restrict__ x,
                                                  const int* __restrict__ rowptr,
                                                  const int* __restrict__ col, int N) {
    int wave = threadIdx.x >> 6, lane = threadIdx.x & 63;
    int node = nb * 4 + wave;
    if (node >= N) return;
    int g = lane / CH;
    int c = lane - g * CH;
    bool act = (g < GR);
    int s = rowptr[node], e = rowptr[node + 1];
    float acc[8] = {0.f, 0.f, 0.f, 0.f, 0.f, 0.f, 0.f, 0.f};
    int j = act ? (s - 1 + g) : e;
    int src0 = node;
    if (j >= s && j < e) src0 = col[j];
    while (j < e) {
        int jb = j + GR;
        int jc = jb + GR;
        int srcb = (jb < e) ? col[jb] : 0;
        int srcc = (jc < e) ? col[jc] : 0;
        short8 v0 = *(const short8*)(x + (size_t)src0 * KP + c * 8);
#pragma unroll
        for (int i = 0; i < 8; ++i) acc[i] += bf2f((unsigned short)v0[i]);
        if (jb < e) {
            short8 v1 = *(const short8*)(x + (size_t)srcb * KP + c * 8);
#pragma unroll
            for (int i = 0; i < 8; ++i) acc[i] += bf2f((unsigned short)v1[i]);
        }
        j = jc; src0 = srcc;
    }
    if (GR == 8) {
#pragma unroll
        for (int i = 0; i < 8; ++i) {
            float v = acc[i];
            v += __shfl_xor(v, 8);
            v += __shfl_xor(v, 16);
            v += __shfl_xor(v, 32);
            acc[i] = v;
        }
    } else {
#pragma unroll
        for (int i = 0; i < 8; ++i) {
            float v = acc[i];
            float v1 = __shfl(v, lane + CH);
            float v2 = __shfl(v, lane + 2 * CH);
            float v3 = __shfl(v, lane + 3 * CH);
            float v4 = __shfl(v, lane + 4 * CH);
            acc[i] = v + v1 + v2 + v3 + v4;
        }
    }
    if (lane < CH) {
        short8 o;
#pragma unroll
        for (int i = 0; i < 8; ++i) o[i] = (short)f2bf(acc[i]);
        *(short8*)(t + (size_t)node * KP + lane * 8) = o;
    }
}

// conv1 via MFMA: y = relu(t @ W + b), bf16 [N][KP]
template<int KP, int KS, int NT>
static __device__ __forceinline__ void conv1_dev(int nb, const unsigned short* __restrict__ t,
                                                 const unsigned short* __restrict__ Wt,
                                                 const float* __restrict__ bias,
                                                 unsigned short* __restrict__ y,
                                                 int NC, int N) {
    int wave = threadIdx.x >> 6, lane = threadIdx.x & 63;
    int quad = lane >> 4, l15 = lane & 15;
    int r0 = (nb * 4 + wave) * 16;
    const short8 z8 = {0, 0, 0, 0, 0, 0, 0, 0};
    short8 a[KS];
    int arow = r0 + l15;
#pragma unroll
    for (int ks = 0; ks < KS; ++ks)
        a[ks] = (arow < N) ? *(const short8*)(t + (size_t)arow * KP + ks * 32 + quad * 8) : z8;
#pragma unroll
    for (int nt = 0; nt < NT; ++nt) {
        int colb = nt * 16 + l15;
        floatx4 c = {0.f, 0.f, 0.f, 0.f};
#pragma unroll
        for (int ks = 0; ks < KS; ++ks) {
            short8 b = *(const short8*)(Wt + (size_t)colb * KP + ks * 32 + quad * 8);
            c = __builtin_amdgcn_mfma_f32_16x16x32_bf16(a[ks], b, c, 0, 0, 0);
        }
        float bc = (colb < NC) ? bias[colb] : 0.f;
#pragma unroll
        for (int r = 0; r < 4; ++r) {
            int row = r0 + quad * 4 + r;
            if (row < N) {
                float o = fmaxf(c[r] + bc, 0.f);
                y[(size_t)row * KP + colb] = f2bf(o);
            }
        }
    }
}

// conv2 + relu + mean/max pool, epilogue emits hi/lo bf16 pooled rows
template<int KP, int KS>
static __device__ __forceinline__ void conv2_pool_dev(int cb, int g,
                                                      const unsigned short* __restrict__ t,
                                                      const unsigned short* __restrict__ Wt,
                                                      const float* __restrict__ bias,
                                                      const int* __restrict__ starts,
                                                      unsigned short* __restrict__ ph,
                                                      unsigned short* __restrict__ pl,
                                                      int OC, int KPad) {
    int wave = threadIdx.x >> 6, lane = threadIdx.x & 63;
    int quad = lane >> 4, l15 = lane & 15;
    int cw0 = cb * 256 + wave * 64;
    short8 bfr[4][KS];
    float bs[4];
#pragma unroll
    for (int ti = 0; ti < 4; ++ti) {
        int colb = cw0 + ti * 16 + l15;
#pragma unroll
        for (int ks = 0; ks < KS; ++ks)
            bfr[ti][ks] = *(const short8*)(Wt + (size_t)colb * KP + ks * 32 + quad * 8);
        bs[ti] = (colb < OC) ? bias[colb] : 0.f;
    }
    int s = starts[g], e = starts[g + 1];
    float sum[4] = {0.f, 0.f, 0.f, 0.f};
    float mx[4]  = {0.f, 0.f, 0.f, 0.f};
    const short8 z8 = {0, 0, 0, 0, 0, 0, 0, 0};
    for (int ns = s; ns < e; ns += 16) {
        short8 a[KS];
        int arow = ns + l15;
        bool av = arow < e;
#pragma unroll
        for (int ks = 0; ks < KS; ++ks)
            a[ks] = av ? *(const short8*)(t + (size_t)arow * KP + ks * 32 + quad * 8) : z8;
        int rbase = ns + quad * 4;
#pragma unroll
        for (int ti = 0; ti < 4; ++ti) {
            floatx4 c = {0.f, 0.f, 0.f, 0.f};
#pragma unroll
            for (int ks = 0; ks < KS; ++ks)
                c = __builtin_amdgcn_mfma_f32_16x16x32_bf16(a[ks], bfr[ti][ks], c, 0, 0, 0);
#pragma unroll
            for (int r = 0; r < 4; ++r) {
                float o = fmaxf(c[r] + bs[ti], 0.f);
                if (rbase + r < e) {
                    sum[ti] += o;
                    mx[ti] = fmaxf(mx[ti], o);
                }
            }
        }
    }
    int cnt = e - s;
    float rc = 1.f / (float)(cnt > 0 ? cnt : 1);
#pragma unroll
    for (int ti = 0; ti < 4; ++ti) {
        float sv = sum[ti], mv = mx[ti];
        sv += __shfl_down(sv, 32);
        mv = fmaxf(mv, __shfl_down(mv, 32));
        sv += __shfl_down(sv, 16);
        mv = fmaxf(mv, __shfl_down(mv, 16));
        if (lane < 16) {
            int colb = cw0 + ti * 16 + l15;
            if (colb < OC) {
                size_t base = (size_t)g * (size_t)KPad;
                unsigned short h, l;
                split_bf(sv * rc, h, l);
                ph[base + colb] = h; pl[base + colb] = l;
                split_bf(mv, h, l);
                ph[base + OC + colb] = h; pl[base + OC + colb] = l;
            }
        }
    }
}

// split-bf16 ("bf16x3") MFMA GEMM tile: C = A @ B^T(+bias), fp32-equivalent.
// MODE 0: relu, write hi/lo bf16.  MODE 1: fp32.  MODE 2: relu, fp32.
template<int MODE>
static __device__ __forceinline__ void gemm3x_dev(int bx, int by, int NBX,
                                                  const unsigned short* __restrict__ Ah,
                                                  const unsigned short* __restrict__ Al,
                                                  const unsigned short* __restrict__ Bh,
                                                  const unsigned short* __restrict__ Bl,
                                                  const float* __restrict__ bias,
                                                  float* __restrict__ Cf,
                                                  unsigned short* __restrict__ Ch,
                                                  unsigned short* __restrict__ Cl,
                                                  int KP) {
    int wave = threadIdx.x >> 6, lane = threadIdx.x & 63;
    int quad = lane >> 4, l15 = lane & 15;
    int r0 = by * 32 + (wave & 1) * 16;
    int c0 = bx * 64 + (wave >> 1) * 32;
    int Ncols = NBX * 64;
    floatx4 acc0 = {0.f, 0.f, 0.f, 0.f};
    floatx4 acc1 = {0.f, 0.f, 0.f, 0.f};
    const unsigned short* arh = Ah + (size_t)(r0 + l15) * KP;
    const unsigned short* arl = Al + (size_t)(r0 + l15) * KP;
    const unsigned short* b0h = Bh + (size_t)(c0 + l15) * KP;
    const unsigned short* b0l = Bl + (size_t)(c0 + l15) * KP;
    const unsigned short* b1h = Bh + (size_t)(c0 + 16 + l15) * KP;
    const unsigned short* b1l = Bl + (size_t)(c0 + 16 + l15) * KP;
    for (int k0 = 0; k0 < KP; k0 += 128) {
        short8 ah[4], al[4];
#pragma unroll
        for (int q = 0; q < 4; ++q) {
            ah[q] = *(const short8*)(arh + k0 + q * 32 + quad * 8);
            al[q] = *(const short8*)(arl + k0 + q * 32 + quad * 8);
        }
#pragma unroll
        for (int q = 0; q < 4; ++q) {
            short8 bh = *(const short8*)(b0h + k0 + q * 32 + quad * 8);
            short8 bl = *(const short8*)(b0l + k0 + q * 32 + quad * 8);
            acc0 = __builtin_amdgcn_mfma_f32_16x16x32_bf16(ah[q], bh, acc0, 0, 0, 0);
            acc0 = __builtin_amdgcn_mfma_f32_16x16x32_bf16(al[q], bh, acc0, 0, 0, 0);
            acc0 = __builtin_amdgcn_mfma_f32_16x16x32_bf16(ah[q], bl, acc0, 0, 0, 0);
            bh = *(const short8*)(b1h + k0 + q * 32 + quad * 8);
            bl = *(const short8*)(b1l + k0 + q * 32 + quad * 8);
            acc1 = __builtin_amdgcn_mfma_f32_16x16x32_bf16(ah[q], bh, acc1, 0, 0, 0);
            acc1 = __builtin_amdgcn_mfma_f32_16x16x32_bf16(al[q], bh, acc1, 0, 0, 0);
            acc1 = __builtin_amdgcn_mfma_f32_16x16x32_bf16(ah[q], bl, acc1, 0, 0, 0);
        }
    }
    int col0 = c0 + l15, col1 = c0 + 16 + l15;
    float bc0 = bias[col0], bc1 = bias[col1];
#pragma unroll
    for (int r = 0; r < 4; ++r) {
        int row = r0 + quad * 4 + r;
        float v0 = acc0[r] + bc0;
        float v1 = acc1[r] + bc1;
        if (MODE != 1) { v0 = fmaxf(v0, 0.f); v1 = fmaxf(v1, 0.f); }
        if (MODE == 0) {
            unsigned short h, l;
            split_bf(v0, h, l);
            Ch[(size_t)row * Ncols + col0] = h; Cl[(size_t)row * Ncols + col0] = l;
            split_bf(v1, h, l);
            Ch[(size_t)row * Ncols + col1] = h; Cl[(size_t)row * Ncols + col1] = l;
        } else {
            Cf[(size_t)row * Ncols + col0] = v0;
            Cf[(size_t)row * Ncols + col1] = v1;
        }
    }
}

// fused batchnorm (stats + apply, one block per column; 512 rows, 512 cols)
static __device__ __forceinline__ void bn_dev(int c, const float* __restrict__ p,
                                              const float* __restrict__ gamma,
                                              const float* __restrict__ beta,
                                              float* __restrict__ outp,
                                              unsigned short* __restrict__ oh,
                                              unsigned short* __restrict__ ol) {
    __shared__ float ls[256], ls2[256];
    int t = threadIdx.x;
    float v0 = p[(size_t)t * 512 + c];
    float v1 = p[(size_t)(t + 256) * 512 + c];
    ls[t] = v0 + v1;
    ls2[t] = v0 * v0 + v1 * v1;
    __syncthreads();
    for (int st = 128; st > 0; st >>= 1) {
        if (t < st) { ls[t] += ls[t + st]; ls2[t] += ls2[t + st]; }
        __syncthreads();
    }
    if (t == 0) {
        float m = ls[0] / 512.f;
        float var = ls2[0] / 512.f - m * m;
        ls[0] = m;
        ls2[0] = 1.f / sqrtf(var + BN_EPS);
    }
    __syncthreads();
    float m = ls[0], iv = ls2[0];
    float g = gamma[c], b = beta[c];
    float w0 = g * (v0 - m) * iv + b;
    float w1 = g * (v1 - m) * iv + b;
    outp[(size_t)t * 512 + c] = w0;
    outp[(size_t)(t + 256) * 512 + c] = w1;
    unsigned short h, l;
    split_bf(w0, h, l);
    oh[(size_t)t * 512 + c] = h; ol[(size_t)t * 512 + c] = l;
    split_bf(w1, h, l);
    oh[(size_t)(t + 256) * 512 + c] = h; ol[(size_t)(t + 256) * 512 + c] = l;
}

// head2: z[row][0..1] = h[row][0..255] @ w2[256][2] + b2. Wave per row.
static __device__ __forceinline__ void head2_dev(int nb, const float* __restrict__ h,
                                                 const float* __restrict__ w2,
                                                 const float* __restrict__ b2,
                                                 float* __restrict__ z, int M) {
    int wave = threadIdx.x >> 6, lane = threadIdx.x & 63;
    int row = nb * 4 + wave;
    if (row >= M) return;
    float4 hv = *(const float4*)(h + (size_t)row * 256 + lane * 4);
    const float* wp = w2 + lane * 8;
    float s0 = hv.x * wp[0] + hv.y * wp[2] + hv.z * wp[4] + hv.w * wp[6];
    float s1 = hv.x * wp[1] + hv.y * wp[3] + hv.z * wp[5] + hv.w * wp[7];
#pragma unroll
    for (int offd = 32; offd >= 1; offd >>= 1) {
        s0 += __shfl_down(s0, offd);
        s1 += __shfl_down(s1, offd);
    }
    if (lane == 0) {
        z[(size_t)row * 2 + 0] = s0 + b2[0];
        z[(size_t)row * 2 + 1] = s1 + b2[1];
    }
}

// ---------------------------------------------------------------------------
// fused stage kernels. RULE: memory-bound partition gets blockIdx 0..K so its
// loads are in flight first; compute blocks backfill (f4 lesson: compute-first
// ordering cost 96us vs ~70 expected).
// ---------------------------------------------------------------------------

// f0: csr_build(both) + tobf16(both)
__global__ __launch_bounds__(256) void f0_kernel(const int2* __restrict__ st0,
                                                 const int2* __restrict__ st1,
                                                 const int* __restrict__ bbase2,
                                                 int* __restrict__ rp0, int* __restrict__ rp1,
                                                 int* __restrict__ c0, int* __restrict__ c1,
                                                 unsigned short* __restrict__ xb0,
                                                 const float* __restrict__ x0,
                                                 unsigned short* __restrict__ xb1,
                                                 const float* __restrict__ x1) {
    int bid = blockIdx.x;
    if (bid < 2 * NBKT) {
        int branch = bid >= NBKT;
        csr_build_dev(branch ? bid - NBKT : bid,
                      branch ? st1 : st0, bbase2 + branch * 512, N0,
                      branch ? rp1 : rp0, branch ? c1 : c0);
    } else if (bid < 2 * NBKT + 50000) {
        int b = bid - 2 * NBKT;
        int node = b * 2 + (threadIdx.x >> 7);
        int f = threadIdx.x & 127;
        if (node < N0 && f < 96)
            xb0[(size_t)node * 96 + f] = (f < 93) ? f2bf(x0[(size_t)node * 93 + f]) : (unsigned short)0;
    } else {
        int b = bid - 2 * NBKT - 50000;
        int node = b * 4 + (threadIdx.x >> 6);
        int f = threadIdx.x & 63;
        if (node < N1)
            xb1[(size_t)node * 64 + f] = (f < 43) ? f2bf(x1[(size_t)node * 43 + f]) : (unsigned short)0;
    }
}

// f1: gather-x(b0) [25000] + wsplit of all 6 MLP weights [4096]
__global__ __launch_bounds__(256) void f1_kernel(unsigned short* __restrict__ tb,
                                                 const unsigned short* __restrict__ xb0,
                                                 const int* __restrict__ rowptr0,
                                                 const int* __restrict__ col0,
                                                 const float* g0_w1, const float* g0_w2,
                                                 const float* f0_w1,
                                                 const float* g1_w1, const float* g1_w2,
                                                 const float* f1_w1,
                                                 unsigned short* bt1h0, unsigned short* bt1l0,
                                                 unsigned short* bt2h0, unsigned short* bt2l0,
                                                 unsigned short* bt3h0, unsigned short* bt3l0,
                                                 unsigned short* bt1h1, unsigned short* bt1l1,
                                                 unsigned short* bt2h1, unsigned short* bt2l1,
                                                 unsigned short* bt3h1, unsigned short* bt3l1) {
    int bid = blockIdx.x;
    if (bid < 25000) {
        gather_dev<96, 12, 5>(bid, tb, xb0, rowptr0, col0, N0);
        return;
    }
    int w = bid - 25000;
    if (w < 1920)      wsplit_dev((w % 60) * 32, (w / 60) * 32, g0_w1, bt1h0, bt1l0, 1860, 1024, 1920);
    else if (w < 2432) { w -= 1920; wsplit_dev((w % 32) * 32, (w / 32) * 32, g0_w2, bt2h0, bt2l0, 1024, 512, 1024); }
    else if (w < 2560) { w -= 2432; wsplit_dev((w % 16) * 32, (w / 16) * 32, f0_w1, bt3h0, bt3l0, 512, 256, 512); }
    else if (w < 3456) { w -= 2560; wsplit_dev((w % 28) * 32, (w / 28) * 32, g1_w1, bt1h1, bt1l1, 860, 1024, 896); }
    else if (w < 3968) { w -= 3456; wsplit_dev((w % 32) * 32, (w / 32) * 32, g1_w2, bt2h1, bt2l1, 1024, 512, 1024); }
    else               { w -= 3968; wsplit_dev((w % 16) * 32, (w / 16) * 32, f1_w1, bt3h1, bt3l1, 512, 256, 512); }
}

// f2: gather-x(b1) [25000 first] + conv1(b0) [1563]
__global__ __launch_bounds__(256) void f2_kernel(unsigned short* __restrict__ t1,
                                                 const unsigned short* __restrict__ xb1,
                                                 const int* __restrict__ rowptr1,
                                                 const int* __restrict__ col1,
                                                 const unsigned short* __restrict__ tb,
                                                 const unsigned short* __restrict__ wt_a0,
                                                 const float* __restrict__ b_c1,
                                                 unsigned short* __restrict__ yb) {
    int bid = blockIdx.x;
    if (bid < 25000)
        gather_dev<64, 8, 8>(bid, t1, xb1, rowptr1, col1, N1);
    else
        conv1_dev<96, 3, 6>(bid - 25000, tb, wt_a0, b_c1, yb, 93, N0);
}

// f3: gather-y(b0) [25000 first] + conv1(b1) [1563]
__global__ __launch_bounds__(256) void f3_kernel(unsigned short* __restrict__ tb,
                                                 const unsigned short* __restrict__ yb,
                                                 const int* __restrict__ rowptr0,
                                                 const int* __restrict__ col0,
                                                 const unsigned short* __restrict__ t1,
                                                 const unsigned short* __restrict__ wt_a1,
                                                 const float* __restrict__ b_c3,
                                                 unsigned short* __restrict__ y1) {
    int bid = blockIdx.x;
    if (bid < 25000)
        gather_dev<96, 12, 5>(bid, tb, yb, rowptr0, col0, N0);
    else
        conv1_dev<64, 2, 3>(bid - 25000, t1, wt_a1, b_c3, y1, 43, N1);
}

// f4: gather-y(b1) [25000 first] + conv2_pool(b0) [2048]
__global__ __launch_bounds__(256) void f4_kernel(unsigned short* __restrict__ t1,
                                                 const unsigned short* __restrict__ y1,
                                                 const int* __restrict__ rowptr1,
                                                 const int* __restrict__ col1,
                                                 const unsigned short* __restrict__ tb,
                                                 const unsigned short* __restrict__ wt_b0,
                                                 const float* __restrict__ b_c2,
                                                 const int* __restrict__ starts0,
                                                 unsigned short* __restrict__ p0h,
                                                 unsigned short* __restrict__ p0l) {
    int bid = blockIdx.x;
    if (bid < 25000)
        gather_dev<64, 8, 8>(bid, t1, y1, rowptr1, col1, N1);
    else {
        int b = bid - 25000;
        conv2_pool_dev<96, 3>(b & 3, b >> 2, tb, wt_b0, b_c2, starts0, p0h, p0l, OC0, 1920);
    }
}

// f5: conv2_pool(b1) [1024 first] + gemm1(b0) [256]
__global__ __launch_bounds__(256) void f5_kernel(const unsigned short* __restrict__ t1,
                                                 const unsigned short* __restrict__ wt_b1,
                                                 const float* __restrict__ b_c4,
                                                 const int* __restrict__ starts1,
                                                 unsigned short* __restrict__ p1h,
                                                 unsigned short* __restrict__ p1l,
                                                 const unsigned short* __restrict__ p0h,
                                                 const unsigned short* __restrict__ p0l,
                                                 const unsigned short* __restrict__ bt1h0,
                                                 const unsigned short* __restrict__ bt1l0,
                                                 const float* __restrict__ g0_b1,
                                                 unsigned short* __restrict__ m1h0,
                                                 unsigned short* __restrict__ m1l0) {
    int bid = blockIdx.x;
    if (bid < 1024)
        conv2_pool_dev<64, 2>(bid & 1, bid >> 1, t1, wt_b1, b_c4, starts1, p1h, p1l, OC1, 896);
    else {
        int b = bid - 1024;
        gemm3x_dev<0>(b & 15, b >> 4, 16, p0h, p0l, bt1h0, bt1l0, g0_b1,
                      nullptr, m1h0, m1l0, 1920);
    }
}

// f6: gemm1(b1) [256 first] + gemm2(b0) [128]
__global__ __launch_bounds__(256) void f6_kernel(const unsigned short* __restrict__ p1h,
                                                 const unsigned short* __restrict__ p1l,
                                                 const unsigned short* __restrict__ bt1h1,
                                                 const unsigned short* __restrict__ bt1l1,
                                                 const float* __restrict__ g1_b1,
                                                 unsigned short* __restrict__ m1h1,
                                                 unsigned short* __restrict__ m1l1,
                                                 const unsigned short* __restrict__ m1h0,
                                                 const unsigned short* __restrict__ m1l0,
                                                 const unsigned short* __restrict__ bt2h0,
                                                 const unsigned short* __restrict__ bt2l0,
                                                 const float* __restrict__ g0_b2,
                                                 float* __restrict__ pbn0) {
    int bid = blockIdx.x;
    if (bid < 256)
        gemm3x_dev<0>(bid & 15, bid >> 4, 16, p1h, p1l, bt1h1, bt1l1, g1_b1,
                      nullptr, m1h1, m1l1, 896);
    else {
        int b = bid - 256;
        gemm3x_dev<1>(b & 7, b >> 3, 8, m1h0, m1l0, bt2h0, bt2l0, g0_b2,
                      pbn0, nullptr, nullptr, 1024);
    }
}

// f7: gemm2(b1) [128 first] + bn(b0) [512]
__global__ __launch_bounds__(256) void f7_kernel(const unsigned short* __restrict__ m1h1,
                                                 const unsigned short* __restrict__ m1l1,
                                                 const unsigned short* __restrict__ bt2h1,
                                                 const unsigned short* __restrict__ bt2l1,
                                                 const float* __restrict__ g1_b2,
                                                 float* __restrict__ pbn1,
                                                 const float* __restrict__ pbn0,
                                                 const float* __restrict__ g0_bn_g,
                                                 const float* __restrict__ g0_bn_b,
                                                 float* __restrict__ out_xg0,
                                                 unsigned short* __restrict__ xgh0,
                                                 unsigned short* __restrict__ xgl0) {
    int bid = blockIdx.x;
    if (bid < 128)
        gemm3x_dev<1>(bid & 7, bid >> 3, 8, m1h1, m1l1, bt2h1, bt2l1, g1_b2,
                      pbn1, nullptr, nullptr, 1024);
    else
        bn_dev(bid - 128, pbn0, g0_bn_g, g0_bn_b, out_xg0, xgh0, xgl0);
}

// f8: bn(b1) [512 first] + gemmH(b0) [64]
__global__ __launch_bounds__(256) void f8_kernel(const float* __restrict__ pbn1,
                                                 const float* __restrict__ g1_bn_g,
                                                 const float* __restrict__ g1_bn_b,
                                                 float* __restrict__ out_xg1,
                                                 unsigned short* __restrict__ xgh1,
                                                 unsigned short* __restrict__ xgl1,
                                                 const unsigned short* __restrict__ xgh0,
                                                 const unsigned short* __restrict__ xgl0,
                                                 const unsigned short* __restrict__ bt3h0,
                                                 const unsigned short* __restrict__ bt3l0,
                                                 const float* __restrict__ f0_b1,
                                                 float* __restrict__ hbuf0) {
    int bid = blockIdx.x;
    if (bid < 512)
        bn_dev(bid, pbn1, g1_bn_g, g1_bn_b, out_xg1, xgh1, xgl1);
    else {
        int b = bid - 512;
        gemm3x_dev<2>(b & 3, b >> 2, 4, xgh0, xgl0, bt3h0, bt3l0, f0_b1,
                      hbuf0, nullptr, nullptr, 512);
    }
}

// f9: gemmH(b1) [64 first] + head2(b0) [128]
__global__ __launch_bounds__(256) void f9_kernel(const unsigned short* __restrict__ xgh1,
                                                 const unsigned short* __restrict__ xgl1,
                                                 const unsigned short* __restrict__ bt3h1,
                                                 const unsigned short* __restrict__ bt3l1,
                                                 const float* __restrict__ f1_b1,
                                                 float* __restrict__ hbuf1,
                                                 const float* __restrict__ hbuf0,
                                                 const float* __restrict__ f0_w2,
                                                 const float* __restrict__ f0_b2,
                                                 float* __restrict__ out_z) {
    int bid = blockIdx.x;
    if (bid < 64)
        gemm3x_dev<2>(bid & 3, bid >> 2, 4, xgh1, xgl1, bt3h1, bt3l1, f1_b1,
                      hbuf1, nullptr, nullptr, 512);
    else
        head2_dev(bid - 64, hbuf0, f0_w2, f0_b2, out_z, GCONST);
}

__global__ __launch_bounds__(256) void head2_kernel(const float* __restrict__ h,
                                                    const float* __restrict__ w2,
                                                    const float* __restrict__ b2,
                                                    float* __restrict__ z, int M) {
    head2_dev(blockIdx.x, h, w2, b2, z, M);
}

// ---------------------------------------------------------------------------
// launch
// ---------------------------------------------------------------------------
static inline int ceildiv(int a, int b) { return (a + b - 1) / b; }

extern "C" void kernel_launch(void* const* d_in, const int* in_sizes, int n_in,
                              void* d_out, int out_size, void* d_ws, size_t ws_size,
                              hipStream_t stream) {
    const float* x0   = (const float*)d_in[0];
    const float* x1   = (const float*)d_in[1];
    const int*   ei0  = (const int*)d_in[2];
    const int*   ei1  = (const int*)d_in[3];
    const int*   bat0 = (const int*)d_in[4];
    const int*   bat1 = (const int*)d_in[5];
    const float* w_c1 = (const float*)d_in[6];
    const float* b_c1 = (const float*)d_in[7];
    const float* w_c2 = (const float*)d_in[8];
    const float* b_c2 = (const float*)d_in[9];
    const float* w_c3 = (const float*)d_in[10];
    const float* b_c3 = (const float*)d_in[11];
    const float* w_c4 = (const float*)d_in[12];
    const float* b_c4 = (const float*)d_in[13];
    const float* g0_w1 = (const float*)d_in[14];
    const float* g0_b1 = (const float*)d_in[15];
    const float* g0_w2 = (const float*)d_in[16];
    const float* g0_b2 = (const float*)d_in[17];
    const float* g0_bn_g = (const float*)d_in[18];
    const float* g0_bn_b = (const float*)d_in[19];
    const float* g1_w1 = (const float*)d_in[20];
    const float* g1_b1 = (const float*)d_in[21];
    const float* g1_w2 = (const float*)d_in[22];
    const float* g1_b2 = (const float*)d_in[23];
    const float* g1_bn_g = (const float*)d_in[24];
    const float* g1_bn_b = (const float*)d_in[25];
    const float* f0_w1 = (const float*)d_in[26];
    const float* f0_b1 = (const float*)d_in[27];
    const float* f0_w2 = (const float*)d_in[28];
    const float* f0_b2 = (const float*)d_in[29];
    const float* f1_w1 = (const float*)d_in[30];
    const float* f1_b1 = (const float*)d_in[31];
    const float* f1_w2 = (const float*)d_in[32];
    const float* f1_b2 = (const float*)d_in[33];

    float* out = (float*)d_out;
    float* out_z   = out;
    float* out_xg0 = out + 1024;
    float* out_xg1 = out + 1024 + 262144;
    float* out_z1  = out + 1024 + 262144 + 262144;

    // workspace carve (floats; all offsets multiples of 4 -> 16B aligned)
    float* ws = (float*)d_ws;
    size_t off = 0;
    auto alloc = [&](size_t n) { float* p = ws + off; off += n; return p; };
    unsigned short* xb0 = (unsigned short*)alloc((size_t)N0 * 96 / 2); // x0 bf16; later t1 (b1 feat buf)
    unsigned short* xb1 = (unsigned short*)alloc((size_t)N1 * 64 / 2); // x1 bf16; later y1 (b1 conv1 out)
    unsigned short* tb  = (unsigned short*)alloc((size_t)N0 * 96 / 2); // staging0 overlay; b0 gather out
    unsigned short* yb  = (unsigned short*)alloc((size_t)N0 * 96 / 2); // staging1 overlay; b0 conv1 out
    unsigned short* wt_a0 = (unsigned short*)alloc(96 * 96 / 2);
    unsigned short* wt_b0 = (unsigned short*)alloc(1024 * 96 / 2);
    unsigned short* wt_a1 = (unsigned short*)alloc(48 * 64 / 2);
    unsigned short* wt_b1 = (unsigned short*)alloc(512 * 64 / 2);
    // MLP hi/lo weights, per branch
    unsigned short* bt1h0 = (unsigned short*)alloc((size_t)1024 * 1920 / 2);
    unsigned short* bt1l0 = (unsigned short*)alloc((size_t)1024 * 1920 / 2);
    unsigned short* bt2h0 = (unsigned short*)alloc((size_t)512 * 1024 / 2);
    unsigned short* bt2l0 = (unsigned short*)alloc((size_t)512 * 1024 / 2);
    unsigned short* bt3h0 = (unsigned short*)alloc((size_t)256 * 512 / 2);
    unsigned short* bt3l0 = (unsigned short*)alloc((size_t)256 * 512 / 2);
    unsigned short* bt1h1 = (unsigned short*)alloc((size_t)1024 * 896 / 2);
    unsigned short* bt1l1 = (unsigned short*)alloc((size_t)1024 * 896 / 2);
    unsigned short* bt2h1 = (unsigned short*)alloc((size_t)512 * 1024 / 2);
    unsigned short* bt2l1 = (unsigned short*)alloc((size_t)512 * 1024 / 2);
    unsigned short* bt3h1 = (unsigned short*)alloc((size_t)256 * 512 / 2);
    unsigned short* bt3l1 = (unsigned short*)alloc((size_t)256 * 512 / 2);
    // activations, per branch
    unsigned short* m1h0 = (unsigned short*)alloc((size_t)512 * 1024 / 2);
    unsigned short* m1l0 = (unsigned short*)alloc((size_t)512 * 1024 / 2);
    unsigned short* m1h1 = (unsigned short*)alloc((size_t)512 * 1024 / 2);
    unsigned short* m1l1 = (unsigned short*)alloc((size_t)512 * 1024 / 2);
    unsigned short* xgh0 = (unsigned short*)alloc((size_t)512 * 512 / 2);
    unsigned short* xgl0 = (unsigned short*)alloc((size_t)512 * 512 / 2);
    unsigned short* xgh1 = (unsigned short*)alloc((size_t)512 * 512 / 2);
    unsigned short* xgl1 = (unsigned short*)alloc((size_t)512 * 512 / 2);
    unsigned short* p0h = (unsigned short*)alloc((size_t)512 * 1920 / 2);
    unsigned short* p0l = (unsigned short*)alloc((size_t)512 * 1920 / 2);
    unsigned short* p1h = (unsigned short*)alloc((size_t)512 * 896 / 2);
    unsigned short* p1l = (unsigned short*)alloc((size_t)512 * 896 / 2);
    float* pbn0  = alloc((size_t)512 * 512);
    float* pbn1  = alloc((size_t)512 * 512);
    float* hbuf0 = alloc((size_t)512 * 256);
    float* hbuf1 = alloc((size_t)512 * 256);
    // CSR
    int* btot2  = (int*)alloc(1024);
    int* bbase2 = (int*)alloc(1024);
    int* bcur2  = (int*)alloc(1024);
    int* rowptr0 = (int*)alloc(100016);
    int* col0    = (int*)alloc(E0C);
    int* rowptr1 = (int*)alloc(100016);
    int* col1    = (int*)alloc(E1C);
    int* starts0 = (int*)alloc(520);
    int* starts1 = (int*)alloc(520);
    // staging overlays (dead after f0; tb/yb first written in f1/f2)
    int2* staging0 = (int2*)tb;
    int2* staging1 = (int2*)yb;
    // branch1 overlays (xb0/xb1 dead after their last reads in f1/f2)
    unsigned short* t1 = xb0;
    unsigned short* y1 = xb1;

    const int EB = ceildiv(E0C, 2048);   // 782

    // ------------------------------ prologue ------------------------------
    misc_kernel<<<2250, 256, 0, stream>>>(bat0, bat1, starts0, starts1,
                                          w_c1, w_c2, w_c3, w_c4,
                                          wt_a0, wt_b0, wt_a1, wt_b1,
                                          btot2, p0h, p0l, p1h, p1l);
    bucket_count2_kernel<<<dim3(EB, 2), 256, 0, stream>>>(ei0, ei1, E0C, btot2);
    bucket_scan2_kernel<<<2, 512, 0, stream>>>(btot2, bbase2, bcur2);
    edge_bucket2_kernel<<<dim3(EB, 2), 256, 0, stream>>>(ei0, ei1, E0C, bcur2, staging0, staging1);
    f0_kernel<<<2 * NBKT + 50000 + 25000, 256, 0, stream>>>(
        staging0, staging1, bbase2, rowptr0, rowptr1, col0, col1,
        xb0, x0, xb1, x1);

    // ------------------- pipelined cross-branch schedule -------------------
    f1_kernel<<<25000 + 4096, 256, 0, stream>>>(
        tb, xb0, rowptr0, col0,
        g0_w1, g0_w2, f0_w1, g1_w1, g1_w2, f1_w1,
        bt1h0, bt1l0, bt2h0, bt2l0, bt3h0, bt3l0,
        bt1h1, bt1l1, bt2h1, bt2l1, bt3h1, bt3l1);
    f2_kernel<<<25000 + 1563, 256, 0, stream>>>(t1, xb1, rowptr1, col1,
                                                tb, wt_a0, b_c1, yb);
    f3_kernel<<<25000 + 1563, 256, 0, stream>>>(tb, yb, rowptr0, col0,
                                                t1, wt_a1, b_c3, y1);
    f4_kernel<<<25000 + 2048, 256, 0, stream>>>(t1, y1, rowptr1, col1,
                                                tb, wt_b0, b_c2, starts0, p0h, p0l);
    f5_kernel<<<1024 + 256, 256, 0, stream>>>(t1, wt_b1, b_c4, starts1, p1h, p1l,
                                              p0h, p0l, bt1h0, bt1l0, g0_b1, m1h0, m1l0);
    f6_kernel<<<256 + 128, 256, 0, stream>>>(p1h, p1l, bt1h1, bt1l1, g1_b1, m1h1, m1l1,
                                             m1h0, m1l0, bt2h0, bt2l0, g0_b2, pbn0);
    f7_kernel<<<128 + 512, 256, 0, stream>>>(m1h1, m1l1, bt2h1, bt2l1, g1_b2, pbn1,
                                             pbn0, g0_bn_g, g0_bn_b, out_xg0, xgh0, xgl0);
    f8_kernel<<<512 + 64, 256, 0, stream>>>(pbn1, g1_bn_g, g1_bn_b, out_xg1, xgh1, xgl1,
                                            xgh0, xgl0, bt3h0, bt3l0, f0_b1, hbuf0);
    f9_kernel<<<64 + 128, 256, 0, stream>>>(xgh1, xgl1, bt3h1, bt3l1, f1_b1, hbuf1,
                                            hbuf0, f0_w2, f0_b2, out_z);
    head2_kernel<<<GCONST / 4, 256, 0, stream>>>(hbuf1, f1_w2, f1_b2, out_z1, GCONST);
}

// Round 6
// 665.781 us; speedup vs baseline: 1.6113x; 1.0975x over previous
//
#include <hip/hip_runtime.h>
#include <hip/hip_bf16.h>

// ---------------------------------------------------------------------------
// Problem constants
// ---------------------------------------------------------------------------
#define N0 100000
#define E0C 1600000
#define N1 100000
#define E1C 1600000
#define GCONST 512
#define F0C 93
#define F1C 43
#define OC0 (F0C * 10)   // 930
#define OC1 (F1C * 10)   // 430
#define BN_EPS 1e-5f
#define NBKT 391         // ceil(100000 / 256) buckets for CSR fill
#define SLAB 6016        // staging slab per bucket (avg 4092, sigma~64 -> +30 sigma)

typedef __attribute__((ext_vector_type(8))) short short8;
typedef __attribute__((ext_vector_type(4))) float floatx4;

static __device__ __forceinline__ unsigned short f2bf(float f) {
    unsigned u = __float_as_uint(f);
    unsigned r = (u + 0x7FFF + ((u >> 16) & 1)) >> 16;   // RNE
    return (unsigned short)r;
}
static __device__ __forceinline__ float bf2f(unsigned short u) {
    return __uint_as_float(((unsigned)u) << 16);
}
static __device__ __forceinline__ void split_bf(float v, unsigned short& h, unsigned short& l) {
    h = f2bf(v);
    l = f2bf(v - bf2f(h));
}

// ---------------------------------------------------------------------------
// misc: find_starts [0,6) + slab cursor init [6]
// ---------------------------------------------------------------------------
__global__ __launch_bounds__(256) void misc_kernel(const int* __restrict__ bat0,
                                                   const int* __restrict__ bat1,
                                                   int* __restrict__ st0,
                                                   int* __restrict__ st1,
                                                   int* __restrict__ bcur2) {
    int bid = blockIdx.x;
    int t = threadIdx.x;
    if (bid < 6) {
        int branch = bid / 3;
        const int* batch = branch ? bat1 : bat0;
        int* starts = branch ? st1 : st0;
        int g = (bid % 3) * 256 + t;
        if (g > GCONST) return;
        if (g == GCONST) { starts[GCONST] = N0; return; }
        int lo = 0, hi = N0;
        while (lo < hi) {
            int mid = (lo + hi) >> 1;
            if (batch[mid] < g) lo = mid + 1; else hi = mid;
        }
        starts[g] = lo;
    } else {
        for (int i = t; i < 1024; i += 256) {
            if (i < NBKT) bcur2[i] = i * SLAB;
            else if (i >= 512 && i < 512 + NBKT) bcur2[i] = (i - 512) * SLAB;
        }
    }
}

// ---------------------------------------------------------------------------
// edge_bucket2: edges(b0) [0,782) | edges(b1) [782,1564) | wt_prep [1564,3612)
//               | p0 pad [3612,3732) | p1 pad [3732,3804)
// Edge blocks reserve contiguous runs off slab cursors (bcur starts at b*SLAB).
// wt_prep / pads are compute/stream backfill hidden under the edge phase.
// ---------------------------------------------------------------------------
__global__ __launch_bounds__(256) void edge_bucket2_kernel(const int* __restrict__ ei0,
                                                           const int* __restrict__ ei1,
                                                           int E, int* __restrict__ bcur2,
                                                           int2* __restrict__ st0,
                                                           int2* __restrict__ st1,
                                                           const float* __restrict__ Wc1,
                                                           const float* __restrict__ Wc2,
                                                           const float* __restrict__ Wc3,
                                                           const float* __restrict__ Wc4,
                                                           unsigned short* __restrict__ Ta0,
                                                           unsigned short* __restrict__ Tb0,
                                                           unsigned short* __restrict__ Ta1,
                                                           unsigned short* __restrict__ Tb1,
                                                           unsigned short* __restrict__ p0h,
                                                           unsigned short* __restrict__ p0l,
                                                           unsigned short* __restrict__ p1h,
                                                           unsigned short* __restrict__ p1l) {
    int bid = blockIdx.x;
    int t = threadIdx.x;
    if (bid < 1564) {
        int branch = bid >= 782;
        int blk = branch ? bid - 782 : bid;
        const int* ei = branch ? ei1 : ei0;
        int* bcur = bcur2 + branch * 512;
        int2* staging = branch ? st1 : st0;
        __shared__ int hist[NBKT];
        __shared__ int gbase[NBKT];
        for (int i = t; i < NBKT; i += 256) hist[i] = 0;
        __syncthreads();
        int base = blk * 2048;
        int srcv[8], dstv[8];
#pragma unroll
        for (int i = 0; i < 8; ++i) {
            int e = base + i * 256 + t;
            if (e < E) { srcv[i] = ei[e]; dstv[i] = ei[E + e]; }
            else dstv[i] = -1;
        }
#pragma unroll
        for (int i = 0; i < 8; ++i)
            if (dstv[i] >= 0) atomicAdd(&hist[dstv[i] >> 8], 1);
        __syncthreads();
        for (int i = t; i < NBKT; i += 256) {
            int c = hist[i];
            gbase[i] = c ? atomicAdd(&bcur[i], c) : 0;
            hist[i] = 0;   // reuse as local cursor
        }
        __syncthreads();
#pragma unroll
        for (int i = 0; i < 8; ++i) {
            if (dstv[i] >= 0) {
                int b = dstv[i] >> 8;
                int lofs = atomicAdd(&hist[b], 1);
                staging[gbase[b] + lofs] = make_int2(srcv[i], dstv[i]);
            }
        }
    } else if (bid < 3612) {
        int idx = bid - 1564;
        int cfg = idx >> 9;
        int c = (idx & 511) * 2 + (t >> 7);
        int k = t & 127;
        const float* W; unsigned short* T; int OCr, Fr, KP, RB;
        switch (cfg) {
            case 0:  W = Wc1; T = Ta0; OCr = 93;  Fr = 93; KP = 96; RB = 96;   break;
            case 1:  W = Wc2; T = Tb0; OCr = 930; Fr = 93; KP = 96; RB = 1024; break;
            case 2:  W = Wc3; T = Ta1; OCr = 43;  Fr = 43; KP = 64; RB = 48;   break;
            default: W = Wc4; T = Tb1; OCr = 430; Fr = 43; KP = 64; RB = 512;  break;
        }
        if (c >= RB || k >= KP) return;
        unsigned short v = 0;
        if (c < OCr && k < Fr) v = f2bf(W[(size_t)k * OCr + c]);
        T[(size_t)c * KP + k] = v;
    } else if (bid < 3732) {
        int i = (bid - 3612) * 256 + t;
        if (i >= GCONST * 60) return;
        int g = i / 60, c = 1860 + (i - g * 60);
        p0h[(size_t)g * 1920 + c] = 0;
        p0l[(size_t)g * 1920 + c] = 0;
    } else {
        int i = (bid - 3732) * 256 + t;
        if (i >= GCONST * 36) return;
        int g = i / 36, c = 860 + (i - g * 36);
        p1h[(size_t)g * 896 + c] = 0;
        p1l[(size_t)g * 896 + c] = 0;
    }
}

// ---------------------------------------------------------------------------
// bucket_scan2: recover bucket counts from slab cursors, exclusive scan ->
// global edge base offsets (bbase). Runs AFTER edge_bucket2.
// ---------------------------------------------------------------------------
__global__ __launch_bounds__(512) void bucket_scan2_kernel(const int* __restrict__ bcur2,
                                                           int* __restrict__ bbase2) {
    const int* bcur = bcur2 + blockIdx.x * 512;
    int* bbase = bbase2 + blockIdx.x * 512;
    __shared__ int sh[512];
    int t = threadIdx.x;
    int cnt = (t < NBKT) ? bcur[t] - t * SLAB : 0;
    sh[t] = cnt;
    __syncthreads();
    for (int o = 1; o < 512; o <<= 1) {
        int add = (t >= o) ? sh[t - o] : 0;
        __syncthreads();
        sh[t] += add;
        __syncthreads();
    }
    if (t <= NBKT) bbase[t] = sh[t] - cnt;   // exclusive; t==NBKT -> total==E
}

// per-bucket fused {LDS histogram -> scan -> rowptr -> col scatter} from slab
static __device__ __forceinline__ void csr_build_dev(int b, const int2* __restrict__ staging,
                                                     const int* __restrict__ bcur,
                                                     const int* __restrict__ bbase, int N,
                                                     int* __restrict__ rowptr,
                                                     int* __restrict__ col) {
    __shared__ int h[256];
    __shared__ int sc[256];
    int t = threadIdx.x;
    int sl = b * SLAB;
    int se = bcur[b];
    int go = bbase[b];
    h[t] = 0;
    __syncthreads();
    for (int i = sl + t; i < se; i += 256)
        atomicAdd(&h[staging[i].y & 255], 1);
    __syncthreads();
    int v = h[t];
    sc[t] = v;
    __syncthreads();
    for (int o = 1; o < 256; o <<= 1) {
        int add = (t >= o) ? sc[t - o] : 0;
        __syncthreads();
        sc[t] += add;
        __syncthreads();
    }
    int ex = go + (sc[t] - v);
    int node = (b << 8) + t;
    if (node <= N) rowptr[node] = ex;
    __syncthreads();
    sc[t] = ex;                          // reuse as cursor
    __syncthreads();
    for (int i = sl + t; i < se; i += 256) {
        int2 ed = staging[i];
        int pos = atomicAdd(&sc[ed.y & 255], 1);
        col[pos] = ed.x;
    }
}

// ---------------------------------------------------------------------------
// MLP weight transpose + hi/lo bf16 split (device body; fused into f1)
// ---------------------------------------------------------------------------
static __device__ __forceinline__ void wsplit_dev(int k0, int c0,
                                                  const float* __restrict__ W,
                                                  unsigned short* __restrict__ Th,
                                                  unsigned short* __restrict__ Tl,
                                                  int K, int N, int KP) {
    __shared__ float tile[32][33];
    int tx = threadIdx.x & 31, ty = threadIdx.x >> 5;
    for (int r = ty; r < 32; r += 8) {
        int k = k0 + r;
        tile[r][tx] = (k < K) ? W[(size_t)k * N + c0 + tx] : 0.f;
    }
    __syncthreads();
    for (int r = ty; r < 32; r += 8) {
        int c = c0 + r;
        float v = tile[tx][r];
        unsigned short h, l;
        split_bf(v, h, l);
        Th[(size_t)c * KP + k0 + tx] = h;
        Tl[(size_t)c * KP + k0 + tx] = l;
    }
}

// ---------------------------------------------------------------------------
// gather-aggregate: one wave per node, 16B vector loads, 2 rows in flight.
// ---------------------------------------------------------------------------
template<int KP, int CH, int GR>
static __device__ __forceinline__ void gather_dev(int nb, unsigned short* __restrict__ t,
                                                  const unsigned short* __restrict__ x,
                                                  const int* __restrict__ rowptr,
                                                  const int* __restrict__ col, int N) {
    int wave = threadIdx.x >> 6, lane = threadIdx.x & 63;
    int node = nb * 4 + wave;
    if (node >= N) return;
    int g = lane / CH;
    int c = lane - g * CH;
    bool act = (g < GR);
    int s = rowptr[node], e = rowptr[node + 1];
    float acc[8] = {0.f, 0.f, 0.f, 0.f, 0.f, 0.f, 0.f, 0.f};
    int j = act ? (s - 1 + g) : e;
    int src0 = node;
    if (j >= s && j < e) src0 = col[j];
    while (j < e) {
        int jb = j + GR;
        int jc = jb + GR;
        int srcb = (jb < e) ? col[jb] : 0;
        int srcc = (jc < e) ? col[jc] : 0;
        short8 v0 = *(const short8*)(x + (size_t)src0 * KP + c * 8);
#pragma unroll
        for (int i = 0; i < 8; ++i) acc[i] += bf2f((unsigned short)v0[i]);
        if (jb < e) {
            short8 v1 = *(const short8*)(x + (size_t)srcb * KP + c * 8);
#pragma unroll
            for (int i = 0; i < 8; ++i) acc[i] += bf2f((unsigned short)v1[i]);
        }
        j = jc; src0 = srcc;
    }
    if (GR == 8) {
#pragma unroll
        for (int i = 0; i < 8; ++i) {
            float v = acc[i];
            v += __shfl_xor(v, 8);
            v += __shfl_xor(v, 16);
            v += __shfl_xor(v, 32);
            acc[i] = v;
        }
    } else {
#pragma unroll
        for (int i = 0; i < 8; ++i) {
            float v = acc[i];
            float v1 = __shfl(v, lane + CH);
            float v2 = __shfl(v, lane + 2 * CH);
            float v3 = __shfl(v, lane + 3 * CH);
            float v4 = __shfl(v, lane + 4 * CH);
            acc[i] = v + v1 + v2 + v3 + v4;
        }
    }
    if (lane < CH) {
        short8 o;
#pragma unroll
        for (int i = 0; i < 8; ++i) o[i] = (short)f2bf(acc[i]);
        *(short8*)(t + (size_t)node * KP + lane * 8) = o;
    }
}

// conv1 via MFMA: y = relu(t @ W + b), bf16 [N][KP]
template<int KP, int KS, int NT>
static __device__ __forceinline__ void conv1_dev(int nb, const unsigned short* __restrict__ t,
                                                 const unsigned short* __restrict__ Wt,
                                                 const float* __restrict__ bias,
                                                 unsigned short* __restrict__ y,
                                                 int NC, int N) {
    int wave = threadIdx.x >> 6, lane = threadIdx.x & 63;
    int quad = lane >> 4, l15 = lane & 15;
    int r0 = (nb * 4 + wave) * 16;
    const short8 z8 = {0, 0, 0, 0, 0, 0, 0, 0};
    short8 a[KS];
    int arow = r0 + l15;
#pragma unroll
    for (int ks = 0; ks < KS; ++ks)
        a[ks] = (arow < N) ? *(const short8*)(t + (size_t)arow * KP + ks * 32 + quad * 8) : z8;
#pragma unroll
    for (int nt = 0; nt < NT; ++nt) {
        int colb = nt * 16 + l15;
        floatx4 c = {0.f, 0.f, 0.f, 0.f};
#pragma unroll
        for (int ks = 0; ks < KS; ++ks) {
            short8 b = *(const short8*)(Wt + (size_t)colb * KP + ks * 32 + quad * 8);
            c = __builtin_amdgcn_mfma_f32_16x16x32_bf16(a[ks], b, c, 0, 0, 0);
        }
        float bc = (colb < NC) ? bias[colb] : 0.f;
#pragma unroll
        for (int r = 0; r < 4; ++r) {
            int row = r0 + quad * 4 + r;
            if (row < N) {
                float o = fmaxf(c[r] + bc, 0.f);
                y[(size_t)row * KP + colb] = f2bf(o);
            }
        }
    }
}

// conv2 + relu + mean/max pool, epilogue emits hi/lo bf16 pooled rows
template<int KP, int KS>
static __device__ __forceinline__ void conv2_pool_dev(int cb, int g,
                                                      const unsigned short* __restrict__ t,
                                                      const unsigned short* __restrict__ Wt,
                                                      const float* __restrict__ bias,
                                                      const int* __restrict__ starts,
                                                      unsigned short* __restrict__ ph,
                                                      unsigned short* __restrict__ pl,
                                                      int OC, int KPad) {
    int wave = threadIdx.x >> 6, lane = threadIdx.x & 63;
    int quad = lane >> 4, l15 = lane & 15;
    int cw0 = cb * 256 + wave * 64;
    short8 bfr[4][KS];
    float bs[4];
#pragma unroll
    for (int ti = 0; ti < 4; ++ti) {
        int colb = cw0 + ti * 16 + l15;
#pragma unroll
        for (int ks = 0; ks < KS; ++ks)
            bfr[ti][ks] = *(const short8*)(Wt + (size_t)colb * KP + ks * 32 + quad * 8);
        bs[ti] = (colb < OC) ? bias[colb] : 0.f;
    }
    int s = starts[g], e = starts[g + 1];
    float sum[4] = {0.f, 0.f, 0.f, 0.f};
    float mx[4]  = {0.f, 0.f, 0.f, 0.f};
    const short8 z8 = {0, 0, 0, 0, 0, 0, 0, 0};
    for (int ns = s; ns < e; ns += 16) {
        short8 a[KS];
        int arow = ns + l15;
        bool av = arow < e;
#pragma unroll
        for (int ks = 0; ks < KS; ++ks)
            a[ks] = av ? *(const short8*)(t + (size_t)arow * KP + ks * 32 + quad * 8) : z8;
        int rbase = ns + quad * 4;
#pragma unroll
        for (int ti = 0; ti < 4; ++ti) {
            floatx4 c = {0.f, 0.f, 0.f, 0.f};
#pragma unroll
            for (int ks = 0; ks < KS; ++ks)
                c = __builtin_amdgcn_mfma_f32_16x16x32_bf16(a[ks], bfr[ti][ks], c, 0, 0, 0);
#pragma unroll
            for (int r = 0; r < 4; ++r) {
                float o = fmaxf(c[r] + bs[ti], 0.f);
                if (rbase + r < e) {
                    sum[ti] += o;
                    mx[ti] = fmaxf(mx[ti], o);
                }
            }
        }
    }
    int cnt = e - s;
    float rc = 1.f / (float)(cnt > 0 ? cnt : 1);
#pragma unroll
    for (int ti = 0; ti < 4; ++ti) {
        float sv = sum[ti], mv = mx[ti];
        sv += __shfl_down(sv, 32);
        mv = fmaxf(mv, __shfl_down(mv, 32));
        sv += __shfl_down(sv, 16);
        mv = fmaxf(mv, __shfl_down(mv, 16));
        if (lane < 16) {
            int colb = cw0 + ti * 16 + l15;
            if (colb < OC) {
                size_t base = (size_t)g * (size_t)KPad;
                unsigned short h, l;
                split_bf(sv * rc, h, l);
                ph[base + colb] = h; pl[base + colb] = l;
                split_bf(mv, h, l);
                ph[base + OC + colb] = h; pl[base + OC + colb] = l;
            }
        }
    }
}

// split-bf16 ("bf16x3") MFMA GEMM tile: C = A @ B^T(+bias), fp32-equivalent.
// MODE 0: relu, write hi/lo bf16.  MODE 1: fp32.  MODE 2: relu, fp32.
template<int MODE>
static __device__ __forceinline__ void gemm3x_dev(int bx, int by, int NBX,
                                                  const unsigned short* __restrict__ Ah,
                                                  const unsigned short* __restrict__ Al,
                                                  const unsigned short* __restrict__ Bh,
                                                  const unsigned short* __restrict__ Bl,
                                                  const float* __restrict__ bias,
                                                  float* __restrict__ Cf,
                                                  unsigned short* __restrict__ Ch,
                                                  unsigned short* __restrict__ Cl,
                                                  int KP) {
    int wave = threadIdx.x >> 6, lane = threadIdx.x & 63;
    int quad = lane >> 4, l15 = lane & 15;
    int r0 = by * 32 + (wave & 1) * 16;
    int c0 = bx * 64 + (wave >> 1) * 32;
    int Ncols = NBX * 64;
    floatx4 acc0 = {0.f, 0.f, 0.f, 0.f};
    floatx4 acc1 = {0.f, 0.f, 0.f, 0.f};
    const unsigned short* arh = Ah + (size_t)(r0 + l15) * KP;
    const unsigned short* arl = Al + (size_t)(r0 + l15) * KP;
    const unsigned short* b0h = Bh + (size_t)(c0 + l15) * KP;
    const unsigned short* b0l = Bl + (size_t)(c0 + l15) * KP;
    const unsigned short* b1h = Bh + (size_t)(c0 + 16 + l15) * KP;
    const unsigned short* b1l = Bl + (size_t)(c0 + 16 + l15) * KP;
    for (int k0 = 0; k0 < KP; k0 += 128) {
        short8 ah[4], al[4];
#pragma unroll
        for (int q = 0; q < 4; ++q) {
            ah[q] = *(const short8*)(arh + k0 + q * 32 + quad * 8);
            al[q] = *(const short8*)(arl + k0 + q * 32 + quad * 8);
        }
#pragma unroll
        for (int q = 0; q < 4; ++q) {
            short8 bh = *(const short8*)(b0h + k0 + q * 32 + quad * 8);
            short8 bl = *(const short8*)(b0l + k0 + q * 32 + quad * 8);
            acc0 = __builtin_amdgcn_mfma_f32_16x16x32_bf16(ah[q], bh, acc0, 0, 0, 0);
            acc0 = __builtin_amdgcn_mfma_f32_16x16x32_bf16(al[q], bh, acc0, 0, 0, 0);
            acc0 = __builtin_amdgcn_mfma_f32_16x16x32_bf16(ah[q], bl, acc0, 0, 0, 0);
            bh = *(const short8*)(b1h + k0 + q * 32 + quad * 8);
            bl = *(const short8*)(b1l + k0 + q * 32 + quad * 8);
            acc1 = __builtin_amdgcn_mfma_f32_16x16x32_bf16(ah[q], bh, acc1, 0, 0, 0);
            acc1 = __builtin_amdgcn_mfma_f32_16x16x32_bf16(al[q], bh, acc1, 0, 0, 0);
            acc1 = __builtin_amdgcn_mfma_f32_16x16x32_bf16(ah[q], bl, acc1, 0, 0, 0);
        }
    }
    int col0 = c0 + l15, col1 = c0 + 16 + l15;
    float bc0 = bias[col0], bc1 = bias[col1];
#pragma unroll
    for (int r = 0; r < 4; ++r) {
        int row = r0 + quad * 4 + r;
        float v0 = acc0[r] + bc0;
        float v1 = acc1[r] + bc1;
        if (MODE != 1) { v0 = fmaxf(v0, 0.f); v1 = fmaxf(v1, 0.f); }
        if (MODE == 0) {
            unsigned short h, l;
            split_bf(v0, h, l);
            Ch[(size_t)row * Ncols + col0] = h; Cl[(size_t)row * Ncols + col0] = l;
            split_bf(v1, h, l);
            Ch[(size_t)row * Ncols + col1] = h; Cl[(size_t)row * Ncols + col1] = l;
        } else {
            Cf[(size_t)row * Ncols + col0] = v0;
            Cf[(size_t)row * Ncols + col1] = v1;
        }
    }
}

// fused batchnorm (stats + apply, one block per column; 512 rows, 512 cols)
static __device__ __forceinline__ void bn_dev(int c, const float* __restrict__ p,
                                              const float* __restrict__ gamma,
                                              const float* __restrict__ beta,
                                              float* __restrict__ outp,
                                              unsigned short* __restrict__ oh,
                                              unsigned short* __restrict__ ol) {
    __shared__ float ls[256], ls2[256];
    int t = threadIdx.x;
    float v0 = p[(size_t)t * 512 + c];
    float v1 = p[(size_t)(t + 256) * 512 + c];
    ls[t] = v0 + v1;
    ls2[t] = v0 * v0 + v1 * v1;
    __syncthreads();
    for (int st = 128; st > 0; st >>= 1) {
        if (t < st) { ls[t] += ls[t + st]; ls2[t] += ls2[t + st]; }
        __syncthreads();
    }
    if (t == 0) {
        float m = ls[0] / 512.f;
        float var = ls2[0] / 512.f - m * m;
        ls[0] = m;
        ls2[0] = 1.f / sqrtf(var + BN_EPS);
    }
    __syncthreads();
    float m = ls[0], iv = ls2[0];
    float g = gamma[c], b = beta[c];
    float w0 = g * (v0 - m) * iv + b;
    float w1 = g * (v1 - m) * iv + b;
    outp[(size_t)t * 512 + c] = w0;
    outp[(size_t)(t + 256) * 512 + c] = w1;
    unsigned short h, l;
    split_bf(w0, h, l);
    oh[(size_t)t * 512 + c] = h; ol[(size_t)t * 512 + c] = l;
    split_bf(w1, h, l);
    oh[(size_t)(t + 256) * 512 + c] = h; ol[(size_t)(t + 256) * 512 + c] = l;
}

// head2: z[row][0..1] = h[row][0..255] @ w2[256][2] + b2. Wave per row.
static __device__ __forceinline__ void head2_dev(int nb, const float* __restrict__ h,
                                                 const float* __restrict__ w2,
                                                 const float* __restrict__ b2,
                                                 float* __restrict__ z, int M) {
    int wave = threadIdx.x >> 6, lane = threadIdx.x & 63;
    int row = nb * 4 + wave;
    if (row >= M) return;
    float4 hv = *(const float4*)(h + (size_t)row * 256 + lane * 4);
    const float* wp = w2 + lane * 8;
    float s0 = hv.x * wp[0] + hv.y * wp[2] + hv.z * wp[4] + hv.w * wp[6];
    float s1 = hv.x * wp[1] + hv.y * wp[3] + hv.z * wp[5] + hv.w * wp[7];
#pragma unroll
    for (int offd = 32; offd >= 1; offd >>= 1) {
        s0 += __shfl_down(s0, offd);
        s1 += __shfl_down(s1, offd);
    }
    if (lane == 0) {
        z[(size_t)row * 2 + 0] = s0 + b2[0];
        z[(size_t)row * 2 + 1] = s1 + b2[1];
    }
}

// ---------------------------------------------------------------------------
// fused stage kernels
// ---------------------------------------------------------------------------

// f0: csr_build(both) + tobf16(both)
__global__ __launch_bounds__(256) void f0_kernel(const int2* __restrict__ st0,
                                                 const int2* __restrict__ st1,
                                                 const int* __restrict__ bcur2,
                                                 const int* __restrict__ bbase2,
                                                 int* __restrict__ rp0, int* __restrict__ rp1,
                                                 int* __restrict__ c0, int* __restrict__ c1,
                                                 unsigned short* __restrict__ xb0,
                                                 const float* __restrict__ x0,
                                                 unsigned short* __restrict__ xb1,
                                                 const float* __restrict__ x1) {
    int bid = blockIdx.x;
    if (bid < 2 * NBKT) {
        int branch = bid >= NBKT;
        csr_build_dev(branch ? bid - NBKT : bid,
                      branch ? st1 : st0,
                      bcur2 + branch * 512, bbase2 + branch * 512, N0,
                      branch ? rp1 : rp0, branch ? c1 : c0);
    } else if (bid < 2 * NBKT + 50000) {
        int b = bid - 2 * NBKT;
        int node = b * 2 + (threadIdx.x >> 7);
        int f = threadIdx.x & 127;
        if (node < N0 && f < 96)
            xb0[(size_t)node * 96 + f] = (f < 93) ? f2bf(x0[(size_t)node * 93 + f]) : (unsigned short)0;
    } else {
        int b = bid - 2 * NBKT - 50000;
        int node = b * 4 + (threadIdx.x >> 6);
        int f = threadIdx.x & 63;
        if (node < N1)
            xb1[(size_t)node * 64 + f] = (f < 43) ? f2bf(x1[(size_t)node * 43 + f]) : (unsigned short)0;
    }
}

// f1: gather-x(b0) [25000] + wsplit of all 6 MLP weights [4096]
__global__ __launch_bounds__(256) void f1_kernel(unsigned short* __restrict__ tb,
                                                 const unsigned short* __restrict__ xb0,
                                                 const int* __restrict__ rowptr0,
                                                 const int* __restrict__ col0,
                                                 const float* g0_w1, const float* g0_w2,
                                                 const float* f0_w1,
                                                 const float* g1_w1, const float* g1_w2,
                                                 const float* f1_w1,
                                                 unsigned short* bt1h0, unsigned short* bt1l0,
                                                 unsigned short* bt2h0, unsigned short* bt2l0,
                                                 unsigned short* bt3h0, unsigned short* bt3l0,
                                                 unsigned short* bt1h1, unsigned short* bt1l1,
                                                 unsigned short* bt2h1, unsigned short* bt2l1,
                                                 unsigned short* bt3h1, unsigned short* bt3l1) {
    int bid = blockIdx.x;
    if (bid < 25000) {
        gather_dev<96, 12, 5>(bid, tb, xb0, rowptr0, col0, N0);
        return;
    }
    int w = bid - 25000;
    if (w < 1920)      wsplit_dev((w % 60) * 32, (w / 60) * 32, g0_w1, bt1h0, bt1l0, 1860, 1024, 1920);
    else if (w < 2432) { w -= 1920; wsplit_dev((w % 32) * 32, (w / 32) * 32, g0_w2, bt2h0, bt2l0, 1024, 512, 1024); }
    else if (w < 2560) { w -= 2432; wsplit_dev((w % 16) * 32, (w / 16) * 32, f0_w1, bt3h0, bt3l0, 512, 256, 512); }
    else if (w < 3456) { w -= 2560; wsplit_dev((w % 28) * 32, (w / 28) * 32, g1_w1, bt1h1, bt1l1, 860, 1024, 896); }
    else if (w < 3968) { w -= 3456; wsplit_dev((w % 32) * 32, (w / 32) * 32, g1_w2, bt2h1, bt2l1, 1024, 512, 1024); }
    else               { w -= 3968; wsplit_dev((w % 16) * 32, (w / 16) * 32, f1_w1, bt3h1, bt3l1, 512, 256, 512); }
}

// f2: gather-x(b1) [25000 first] + conv1(b0) [1563]
__global__ __launch_bounds__(256) void f2_kernel(unsigned short* __restrict__ t1,
                                                 const unsigned short* __restrict__ xb1,
                                                 const int* __restrict__ rowptr1,
                                                 const int* __restrict__ col1,
                                                 const unsigned short* __restrict__ tb,
                                                 const unsigned short* __restrict__ wt_a0,
                                                 const float* __restrict__ b_c1,
                                                 unsigned short* __restrict__ yb) {
    int bid = blockIdx.x;
    if (bid < 25000)
        gather_dev<64, 8, 8>(bid, t1, xb1, rowptr1, col1, N1);
    else
        conv1_dev<96, 3, 6>(bid - 25000, tb, wt_a0, b_c1, yb, 93, N0);
}

// f3: gather-y(b0) [25000 first] + conv1(b1) [1563]
__global__ __launch_bounds__(256) void f3_kernel(unsigned short* __restrict__ tb,
                                                 const unsigned short* __restrict__ yb,
                                                 const int* __restrict__ rowptr0,
                                                 const int* __restrict__ col0,
                                                 const unsigned short* __restrict__ t1,
                                                 const unsigned short* __restrict__ wt_a1,
                                                 const float* __restrict__ b_c3,
                                                 unsigned short* __restrict__ y1) {
    int bid = blockIdx.x;
    if (bid < 25000)
        gather_dev<96, 12, 5>(bid, tb, yb, rowptr0, col0, N0);
    else
        conv1_dev<64, 2, 3>(bid - 25000, t1, wt_a1, b_c3, y1, 43, N1);
}

// f4: gather-y(b1) standalone (fusing it with conv2_pool cost +30us: L2 thrash)
__global__ __launch_bounds__(256) void f4_kernel(unsigned short* __restrict__ t1,
                                                 const unsigned short* __restrict__ y1,
                                                 const int* __restrict__ rowptr1,
                                                 const int* __restrict__ col1) {
    gather_dev<64, 8, 8>(blockIdx.x, t1, y1, rowptr1, col1, N1);
}

// f5: conv2_pool(b0) [2048] + conv2_pool(b1) [1024].
// XCD-coherent mapping: the cb-quadrant blocks of one graph get blockIdx
// congruent mod 8 (same XCD under round-robin) and within 32 bids -> the
// 2nd..4th reads of the graph's rows hit that XCD's L2 (was 4x HBM re-fetch).
__global__ __launch_bounds__(256) void f5_kernel(const unsigned short* __restrict__ tb,
                                                 const unsigned short* __restrict__ wt_b0,
                                                 const float* __restrict__ b_c2,
                                                 const int* __restrict__ starts0,
                                                 unsigned short* __restrict__ p0h,
                                                 unsigned short* __restrict__ p0l,
                                                 const unsigned short* __restrict__ t1,
                                                 const unsigned short* __restrict__ wt_b1,
                                                 const float* __restrict__ b_c4,
                                                 const int* __restrict__ starts1,
                                                 unsigned short* __restrict__ p1h,
                                                 unsigned short* __restrict__ p1l) {
    int bid = blockIdx.x;
    if (bid < 2048) {
        int b = bid;
        int g = (b & 7) | ((b >> 5) << 3);
        int cb = (b >> 3) & 3;
        conv2_pool_dev<96, 3>(cb, g, tb, wt_b0, b_c2, starts0, p0h, p0l, OC0, 1920);
    } else {
        int b = bid - 2048;   // 2048 % 8 == 0 -> b mod 8 preserved
        int g = (b & 7) | ((b >> 4) << 3);
        int cb = (b >> 3) & 1;
        conv2_pool_dev<64, 2>(cb, g, t1, wt_b1, b_c4, starts1, p1h, p1l, OC1, 896);
    }
}

// f6: gemm1(b0) [256] + gemm1(b1) [256]
__global__ __launch_bounds__(256) void f6_kernel(const unsigned short* __restrict__ p0h,
                                                 const unsigned short* __restrict__ p0l,
                                                 const unsigned short* __restrict__ bt1h0,
                                                 const unsigned short* __restrict__ bt1l0,
                                                 const float* __restrict__ g0_b1,
                                                 unsigned short* __restrict__ m1h0,
                                                 unsigned short* __restrict__ m1l0,
                                                 const unsigned short* __restrict__ p1h,
                                                 const unsigned short* __restrict__ p1l,
                                                 const unsigned short* __restrict__ bt1h1,
                                                 const unsigned short* __restrict__ bt1l1,
                                                 const float* __restrict__ g1_b1,
                                                 unsigned short* __restrict__ m1h1,
                                                 unsigned short* __restrict__ m1l1) {
    int bid = blockIdx.x;
    if (bid < 256)
        gemm3x_dev<0>(bid & 15, bid >> 4, 16, p0h, p0l, bt1h0, bt1l0, g0_b1,
                      nullptr, m1h0, m1l0, 1920);
    else {
        int b = bid - 256;
        gemm3x_dev<0>(b & 15, b >> 4, 16, p1h, p1l, bt1h1, bt1l1, g1_b1,
                      nullptr, m1h1, m1l1, 896);
    }
}

// f7: gemm2(b0) [128] + gemm2(b1) [128]
__global__ __launch_bounds__(256) void f7_kernel(const unsigned short* __restrict__ m1h0,
                                                 const unsigned short* __restrict__ m1l0,
                                                 const unsigned short* __restrict__ bt2h0,
                                                 const unsigned short* __restrict__ bt2l0,
                                                 const float* __restrict__ g0_b2,
                                                 float* __restrict__ pbn0,
                                                 const unsigned short* __restrict__ m1h1,
                                                 const unsigned short* __restrict__ m1l1,
                                                 const unsigned short* __restrict__ bt2h1,
                                                 const unsigned short* __restrict__ bt2l1,
                                                 const float* __restrict__ g1_b2,
                                                 float* __restrict__ pbn1) {
    int bid = blockIdx.x;
    if (bid < 128)
        gemm3x_dev<1>(bid & 7, bid >> 3, 8, m1h0, m1l0, bt2h0, bt2l0, g0_b2,
                      pbn0, nullptr, nullptr, 1024);
    else {
        int b = bid - 128;
        gemm3x_dev<1>(b & 7, b >> 3, 8, m1h1, m1l1, bt2h1, bt2l1, g1_b2,
                      pbn1, nullptr, nullptr, 1024);
    }
}

// f8: bn(b0) [512] + bn(b1) [512]
__global__ __launch_bounds__(256) void f8_kernel(const float* __restrict__ pbn0,
                                                 const float* __restrict__ g0_bn_g,
                                                 const float* __restrict__ g0_bn_b,
                                                 float* __restrict__ out_xg0,
                                                 unsigned short* __restrict__ xgh0,
                                                 unsigned short* __restrict__ xgl0,
                                                 const float* __restrict__ pbn1,
                                                 const float* __restrict__ g1_bn_g,
                                                 const float* __restrict__ g1_bn_b,
                                                 float* __restrict__ out_xg1,
                                                 unsigned short* __restrict__ xgh1,
                                                 unsigned short* __restrict__ xgl1) {
    int bid = blockIdx.x;
    if (bid < 512)
        bn_dev(bid, pbn0, g0_bn_g, g0_bn_b, out_xg0, xgh0, xgl0);
    else
        bn_dev(bid - 512, pbn1, g1_bn_g, g1_bn_b, out_xg1, xgh1, xgl1);
}

// f9: gemmH(b0) [64] + gemmH(b1) [64]
__global__ __launch_bounds__(256) void f9_kernel(const unsigned short* __restrict__ xgh0,
                                                 const unsigned short* __restrict__ xgl0,
                                                 const unsigned short* __restrict__ bt3h0,
                                                 const unsigned short* __restrict__ bt3l0,
                                                 const float* __restrict__ f0_b1,
                                                 float* __restrict__ hbuf0,
                                                 const unsigned short* __restrict__ xgh1,
                                                 const unsigned short* __restrict__ xgl1,
                                                 const unsigned short* __restrict__ bt3h1,
                                                 const unsigned short* __restrict__ bt3l1,
                                                 const float* __restrict__ f1_b1,
                                                 float* __restrict__ hbuf1) {
    int bid = blockIdx.x;
    if (bid < 64)
        gemm3x_dev<2>(bid & 3, bid >> 2, 4, xgh0, xgl0, bt3h0, bt3l0, f0_b1,
                      hbuf0, nullptr, nullptr, 512);
    else {
        int b = bid - 64;
        gemm3x_dev<2>(b & 3, b >> 2, 4, xgh1, xgl1, bt3h1, bt3l1, f1_b1,
                      hbuf1, nullptr, nullptr, 512);
    }
}

// f10: head2(b0) [128] + head2(b1) [128]
__global__ __launch_bounds__(256) void f10_kernel(const float* __restrict__ hbuf0,
                                                  const float* __restrict__ f0_w2,
                                                  const float* __restrict__ f0_b2,
                                                  float* __restrict__ out_z,
                                                  const float* __restrict__ hbuf1,
                                                  const float* __restrict__ f1_w2,
                                                  const float* __restrict__ f1_b2,
                                                  float* __restrict__ out_z1) {
    int bid = blockIdx.x;
    if (bid < 128)
        head2_dev(bid, hbuf0, f0_w2, f0_b2, out_z, GCONST);
    else
        head2_dev(bid - 128, hbuf1, f1_w2, f1_b2, out_z1, GCONST);
}

// ---------------------------------------------------------------------------
// launch
// ---------------------------------------------------------------------------
static inline int ceildiv(int a, int b) { return (a + b - 1) / b; }

extern "C" void kernel_launch(void* const* d_in, const int* in_sizes, int n_in,
                              void* d_out, int out_size, void* d_ws, size_t ws_size,
                              hipStream_t stream) {
    const float* x0   = (const float*)d_in[0];
    const float* x1   = (const float*)d_in[1];
    const int*   ei0  = (const int*)d_in[2];
    const int*   ei1  = (const int*)d_in[3];
    const int*   bat0 = (const int*)d_in[4];
    const int*   bat1 = (const int*)d_in[5];
    const float* w_c1 = (const float*)d_in[6];
    const float* b_c1 = (const float*)d_in[7];
    const float* w_c2 = (const float*)d_in[8];
    const float* b_c2 = (const float*)d_in[9];
    const float* w_c3 = (const float*)d_in[10];
    const float* b_c3 = (const float*)d_in[11];
    const float* w_c4 = (const float*)d_in[12];
    const float* b_c4 = (const float*)d_in[13];
    const float* g0_w1 = (const float*)d_in[14];
    const float* g0_b1 = (const float*)d_in[15];
    const float* g0_w2 = (const float*)d_in[16];
    const float* g0_b2 = (const float*)d_in[17];
    const float* g0_bn_g = (const float*)d_in[18];
    const float* g0_bn_b = (const float*)d_in[19];
    const float* g1_w1 = (const float*)d_in[20];
    const float* g1_b1 = (const float*)d_in[21];
    const float* g1_w2 = (const float*)d_in[22];
    const float* g1_b2 = (const float*)d_in[23];
    const float* g1_bn_g = (const float*)d_in[24];
    const float* g1_bn_b = (const float*)d_in[25];
    const float* f0_w1 = (const float*)d_in[26];
    const float* f0_b1 = (const float*)d_in[27];
    const float* f0_w2 = (const float*)d_in[28];
    const float* f0_b2 = (const float*)d_in[29];
    const float* f1_w1 = (const float*)d_in[30];
    const float* f1_b1 = (const float*)d_in[31];
    const float* f1_w2 = (const float*)d_in[32];
    const float* f1_b2 = (const float*)d_in[33];

    float* out = (float*)d_out;
    float* out_z   = out;
    float* out_xg0 = out + 1024;
    float* out_xg1 = out + 1024 + 262144;
    float* out_z1  = out + 1024 + 262144 + 262144;

    // workspace carve (floats; all offsets multiples of 4 -> 16B aligned)
    float* ws = (float*)d_ws;
    size_t off = 0;
    auto alloc = [&](size_t n) { float* p = ws + off; off += n; return p; };
    unsigned short* xb0 = (unsigned short*)alloc((size_t)N0 * 96 / 2); // x0 bf16; later t1 (b1 feat buf)
    unsigned short* xb1 = (unsigned short*)alloc((size_t)N1 * 64 / 2); // x1 bf16; later y1 (b1 conv1 out)
    unsigned short* tb  = (unsigned short*)alloc((size_t)N0 * 96 / 2); // staging0 overlay; b0 gather out
    unsigned short* yb  = (unsigned short*)alloc((size_t)N0 * 96 / 2); // staging1 overlay; b0 conv1 out
    unsigned short* wt_a0 = (unsigned short*)alloc(96 * 96 / 2);
    unsigned short* wt_b0 = (unsigned short*)alloc(1024 * 96 / 2);
    unsigned short* wt_a1 = (unsigned short*)alloc(48 * 64 / 2);
    unsigned short* wt_b1 = (unsigned short*)alloc(512 * 64 / 2);
    // MLP hi/lo weights, per branch
    unsigned short* bt1h0 = (unsigned short*)alloc((size_t)1024 * 1920 / 2);
    unsigned short* bt1l0 = (unsigned short*)alloc((size_t)1024 * 1920 / 2);
    unsigned short* bt2h0 = (unsigned short*)alloc((size_t)512 * 1024 / 2);
    unsigned short* bt2l0 = (unsigned short*)alloc((size_t)512 * 1024 / 2);
    unsigned short* bt3h0 = (unsigned short*)alloc((size_t)256 * 512 / 2);
    unsigned short* bt3l0 = (unsigned short*)alloc((size_t)256 * 512 / 2);
    unsigned short* bt1h1 = (unsigned short*)alloc((size_t)1024 * 896 / 2);
    unsigned short* bt1l1 = (unsigned short*)alloc((size_t)1024 * 896 / 2);
    unsigned short* bt2h1 = (unsigned short*)alloc((size_t)512 * 1024 / 2);
    unsigned short* bt2l1 = (unsigned short*)alloc((size_t)512 * 1024 / 2);
    unsigned short* bt3h1 = (unsigned short*)alloc((size_t)256 * 512 / 2);
    unsigned short* bt3l1 = (unsigned short*)alloc((size_t)256 * 512 / 2);
    // activations, per branch
    unsigned short* m1h0 = (unsigned short*)alloc((size_t)512 * 1024 / 2);
    unsigned short* m1l0 = (unsigned short*)alloc((size_t)512 * 1024 / 2);
    unsigned short* m1h1 = (unsigned short*)alloc((size_t)512 * 1024 / 2);
    unsigned short* m1l1 = (unsigned short*)alloc((size_t)512 * 1024 / 2);
    unsigned short* xgh0 = (unsigned short*)alloc((size_t)512 * 512 / 2);
    unsigned short* xgl0 = (unsigned short*)alloc((size_t)512 * 512 / 2);
    unsigned short* xgh1 = (unsigned short*)alloc((size_t)512 * 512 / 2);
    unsigned short* xgl1 = (unsigned short*)alloc((size_t)512 * 512 / 2);
    unsigned short* p0h = (unsigned short*)alloc((size_t)512 * 1920 / 2);
    unsigned short* p0l = (unsigned short*)alloc((size_t)512 * 1920 / 2);
    unsigned short* p1h = (unsigned short*)alloc((size_t)512 * 896 / 2);
    unsigned short* p1l = (unsigned short*)alloc((size_t)512 * 896 / 2);
    float* pbn0  = alloc((size_t)512 * 512);
    float* pbn1  = alloc((size_t)512 * 512);
    float* hbuf0 = alloc((size_t)512 * 256);
    float* hbuf1 = alloc((size_t)512 * 256);
    // CSR
    int* bbase2 = (int*)alloc(1024);
    int* bcur2  = (int*)alloc(1024);
    int* rowptr0 = (int*)alloc(100016);
    int* col0    = (int*)alloc(E0C);
    int* rowptr1 = (int*)alloc(100016);
    int* col1    = (int*)alloc(E1C);
    int* starts0 = (int*)alloc(520);
    int* starts1 = (int*)alloc(520);
    // staging slab overlays (NBKT*SLAB int2 = 18.8MB <= 19.2MB tb/yb regions;
    // dead after f0; tb/yb first written in f1/f2)
    int2* staging0 = (int2*)tb;
    int2* staging1 = (int2*)yb;
    // branch1 overlays (xb0/xb1 dead after their last reads in f1/f2)
    unsigned short* t1 = xb0;
    unsigned short* y1 = xb1;

    // ------------------------------ prologue ------------------------------
    misc_kernel<<<7, 256, 0, stream>>>(bat0, bat1, starts0, starts1, bcur2);
    edge_bucket2_kernel<<<3804, 256, 0, stream>>>(ei0, ei1, E0C, bcur2,
                                                  staging0, staging1,
                                                  w_c1, w_c2, w_c3, w_c4,
                                                  wt_a0, wt_b0, wt_a1, wt_b1,
                                                  p0h, p0l, p1h, p1l);
    bucket_scan2_kernel<<<2, 512, 0, stream>>>(bcur2, bbase2);
    f0_kernel<<<2 * NBKT + 50000 + 25000, 256, 0, stream>>>(
        staging0, staging1, bcur2, bbase2, rowptr0, rowptr1, col0, col1,
        xb0, x0, xb1, x1);

    // ------------------- pipelined cross-branch schedule -------------------
    f1_kernel<<<25000 + 4096, 256, 0, stream>>>(
        tb, xb0, rowptr0, col0,
        g0_w1, g0_w2, f0_w1, g1_w1, g1_w2, f1_w1,
        bt1h0, bt1l0, bt2h0, bt2l0, bt3h0, bt3l0,
        bt1h1, bt1l1, bt2h1, bt2l1, bt3h1, bt3l1);
    f2_kernel<<<25000 + 1563, 256, 0, stream>>>(t1, xb1, rowptr1, col1,
                                                tb, wt_a0, b_c1, yb);
    f3_kernel<<<25000 + 1563, 256, 0, stream>>>(tb, yb, rowptr0, col0,
                                                t1, wt_a1, b_c3, y1);
    f4_kernel<<<25000, 256, 0, stream>>>(t1, y1, rowptr1, col1);
    f5_kernel<<<2048 + 1024, 256, 0, stream>>>(tb, wt_b0, b_c2, starts0, p0h, p0l,
                                               t1, wt_b1, b_c4, starts1, p1h, p1l);
    f6_kernel<<<256 + 256, 256, 0, stream>>>(p0h, p0l, bt1h0, bt1l0, g0_b1, m1h0, m1l0,
                                             p1h, p1l, bt1h1, bt1l1, g1_b1, m1h1, m1l1);
    f7_kernel<<<128 + 128, 256, 0, stream>>>(m1h0, m1l0, bt2h0, bt2l0, g0_b2, pbn0,
                                             m1h1, m1l1, bt2h1, bt2l1, g1_b2, pbn1);
    f8_kernel<<<512 + 512, 256, 0, stream>>>(pbn0, g0_bn_g, g0_bn_b, out_xg0, xgh0, xgl0,
                                             pbn1, g1_bn_g, g1_bn_b, out_xg1, xgh1, xgl1);
    f9_kernel<<<64 + 64, 256, 0, stream>>>(xgh0, xgl0, bt3h0, bt3l0, f0_b1, hbuf0,
                                           xgh1, xgl1, bt3h1, bt3l1, f1_b1, hbuf1);
    f10_kernel<<<128 + 128, 256, 0, stream>>>(hbuf0, f0_w2, f0_b2, out_z,
                                              hbuf1, f1_w2, f1_b2, out_z1);
}